// Round 6
// baseline (868.319 us; speedup 1.0000x reference)
//
#include <hip/hip_runtime.h>
#include <hip/hip_bf16.h>
#include <math.h>

#define NB 131072

typedef __attribute__((ext_vector_type(4))) float f32x4;
typedef __attribute__((ext_vector_type(8))) short bf16x8;

// Wave-local ordering fence for wave-private LDS: memory clobber stops IR
// reordering; sched_barrier(0x7F) pins DS ops only so the backend scheduler
// can still move VALU/MFMA/VMEM across (keeps register pressure down).
#define SYNC() do { asm volatile("" ::: "memory"); __builtin_amdgcn_sched_barrier(0x7F); } while (0)

// ---- workspace layout (float offsets) ----
#define WS_A_EEG 0          // [64][32]
#define WS_A_EOG 2048       // [64][32]
#define WS_B0    4096       // [64]
#define WS_WATT  4160       // [2][64][64] f32 (fallback)
#define WS_BATT  12352      // [2][64]
#define WS_WVT   12480      // [62][62]  (fallback)
#define WS_M     16324      // [62][62]
#define WS_OBB   20168      // [62]
#define WS_CWT   20232      // [62][32][5]
#define WS_CWOG  30152      // [33][32]
#define WS_W2T   31208      // [2][256][64] f32 (fallback)
#define WB_WA_F  64000      // bf16 [2][64][64]
#define WB_W1_F  68096      // bf16 [2][256][64]
#define WB_W2_F  84480      // bf16 [2][64][256]
// interleaved per-lane-contiguous data layouts:
#define WS_EEGX4 100864                     // [62][B][4]  x0..x3 (16B/lane)
#define WS_EEGX1 (WS_EEGX4 + 4 * 62 * NB)   // [62][B]     x4
#define WS_POOLI (WS_EEGX1 + 62 * NB)       // [B][64]     pooled (62 used)
#define WS_FEATI WS_POOLI                   // [B][64] feat overlays poolI:
                                            // thread b reads poolI[b] fully
                                            // before writing featI[b].
#define WS_TOTALF (WS_POOLI + 64 * NB)

// per-wave LDS for trans: 64 rows x 208B (13 granules; odd -> <=2-way banks)
#define ROWB 208
#define WAVE_LDS (64 * ROWB)

__device__ __forceinline__ short f2bf(float x) {
    union { __hip_bfloat16 h; short s; } u;
    u.h = __float2bfloat16(x);
    return u.s;
}

__global__ __launch_bounds__(256) void mcaf_pre(
    const float* __restrict__ eeg_inw, const float* __restrict__ eeg_inb,
    const float* __restrict__ eeg_ow,  const float* __restrict__ eeg_ob,
    const float* __restrict__ eeg_cw,
    const float* __restrict__ eeg_fw,  const float* __restrict__ eeg_fb,
    const float* __restrict__ eog_cw,  const float* __restrict__ eog_fw,
    const float* __restrict__ eog_fb,
    const float* __restrict__ fus_w,   const float* __restrict__ fus_b,
    const float* __restrict__ tl_inw,  const float* __restrict__ tl_inb,
    const float* __restrict__ tl_ow,   const float* __restrict__ tl_ob,
    const float* __restrict__ tl_w1,   const float* __restrict__ tl_w2,
    float* __restrict__ ws)
{
    const int tid  = blockIdx.x * blockDim.x + threadIdx.x;
    const int nthr = gridDim.x * blockDim.x;
    short* wa_b = (short*)(ws + WB_WA_F);
    short* w1_b = (short*)(ws + WB_W1_F);
    short* w2_b = (short*)(ws + WB_W2_F);

    for (int idx = tid; idx < 2048; idx += nthr) {
        int f = idx >> 5, o = idx & 31;
        float a = 0.f, a2 = 0.f;
        for (int k = 0; k < 64; ++k) {
            a  = fmaf(fus_w[f * 128 + k],      eeg_fw[k * 32 + o], a);
            a2 = fmaf(fus_w[f * 128 + 64 + k], eog_fw[k * 32 + o], a2);
        }
        ws[WS_A_EEG + idx] = a;
        ws[WS_A_EOG + idx] = a2;
    }
    for (int f = tid; f < 64; f += nthr) {
        float a = fus_b[f] + (float)(f & 1);
        for (int k = 0; k < 64; ++k) {
            a = fmaf(fus_w[f * 128 + k],      eeg_fb[k], a);
            a = fmaf(fus_w[f * 128 + 64 + k], eog_fb[k], a);
        }
        ws[WS_B0 + f] = a;
    }
    for (int idx = tid; idx < 8192; idx += nthr) {
        int i = idx >> 12, c = (idx >> 6) & 63, d = idx & 63;
        float a = 0.f;
        for (int e = 0; e < 64; ++e)
            a = fmaf(tl_ow[i * 4096 + c * 64 + e],
                     tl_inw[i * 12288 + (128 + e) * 64 + d], a);
        ws[WS_WATT + idx] = a;
        wa_b[idx] = f2bf(a);
    }
    for (int idx = tid; idx < 128; idx += nthr) {
        int i = idx >> 6, c = idx & 63;
        float a = tl_ob[i * 64 + c];
        for (int e = 0; e < 64; ++e)
            a = fmaf(tl_ow[i * 4096 + c * 64 + e], tl_inb[i * 192 + 128 + e], a);
        ws[WS_BATT + idx] = a;
    }
    for (int idx = tid; idx < 32768; idx += nthr) w1_b[idx] = f2bf(tl_w1[idx]);
    for (int idx = tid; idx < 32768; idx += nthr) w2_b[idx] = f2bf(tl_w2[idx]);

    for (int idx = tid; idx < 3844; idx += nthr) {
        int e = idx / 62, d = idx - e * 62;
        ws[WS_WVT + idx] = eeg_inw[(124 + d) * 62 + e];
    }
    for (int idx = tid; idx < 3844; idx += nthr) {
        int c = idx / 62, e = idx - c * 62;
        float a = 0.f;
        for (int d = 0; d < 62; ++d)
            a = fmaf(eeg_ow[c * 62 + d], eeg_inw[(124 + d) * 62 + e], a);
        ws[WS_M + idx] = a;
    }
    for (int c = tid; c < 62; c += nthr) {
        float a = eeg_ob[c];
        for (int d = 0; d < 62; ++d)
            a = fmaf(eeg_ow[c * 62 + d], eeg_inb[124 + d], a);
        ws[WS_OBB + c] = a;
    }
    for (int idx = tid; idx < 9920; idx += nthr) {
        int c = idx / 160, r = idx - c * 160;
        int o = r / 5, l = r - o * 5;
        ws[WS_CWT + idx] = eeg_cw[o * 310 + c * 5 + l];
    }
    for (int idx = tid; idx < 1056; idx += nthr) {
        int l = idx >> 5, o = idx & 31;
        ws[WS_CWOG + idx] = eog_cw[o * 33 + l];
    }
    for (int idx = tid; idx < 32768; idx += nthr) {
        int i = idx >> 14, r = idx & 16383;
        int j = r >> 6, c = r & 63;
        ws[WS_W2T + idx] = tl_w2[i * 16384 + c * 256 + j];
    }
}

// ---- eeg re-layout + fused pooling (wave-private LDS, no barriers) ----
// One block per 256 batch rows; each wave owns 64 rows and loops 8 col-chunks.
// Emits eegX4/eegX1 (per-lane contiguous) and poolI[B][64] (vector stores).
__global__ __launch_bounds__(256) void eeg_tr(const float* __restrict__ eeg,
                                              float* __restrict__ ws)
{
    __shared__ float smem[4 * 64 * 41];
    const int lane = threadIdx.x & 63;
    const int wid  = threadIdx.x >> 6;
    const int bw   = blockIdx.x * 256 + wid * 64;
    const int b    = bw + lane;
    float* sw = smem + wid * (64 * 41);

    float pooled[64];
    #pragma unroll
    for (int e = 0; e < 64; ++e) pooled[e] = 0.f;

    #pragma unroll
    for (int chunk = 0; chunk < 8; ++chunk) {
        const int ch0 = chunk * 40;
        for (int j = 0; j < 40; ++j) {
            int idx = j * 64 + lane;
            int r = idx / 40, cc = idx - r * 40;
            int gcol = ch0 + cc;
            float v = 0.f;
            if (gcol < 310) v = eeg[(bw + r) * 310 + gcol];
            sw[r * 41 + cc] = v;
        }
        SYNC();
        const int nch = (chunk == 7) ? 6 : 8;
        #pragma unroll
        for (int el = 0; el < 8; ++el) {
            if (el < nch) {
                int c = chunk * 8 + el;
                const float* xr = sw + lane * 41 + el * 5;
                float x0 = xr[0], x1 = xr[1], x2 = xr[2], x3 = xr[3], x4 = xr[4];
                pooled[c] = (x0 + x1 + x2 + x3 + x4) * 0.2f;
                *(f32x4*)(ws + WS_EEGX4 + (size_t)(c * NB + b) * 4) = (f32x4){x0, x1, x2, x3};
                ws[WS_EEGX1 + c * NB + b] = x4;
            }
        }
        SYNC();   // staged data consumed before next chunk overwrites
    }
    // coalesced per-lane-contiguous pooled row
    #pragma unroll
    for (int q = 0; q < 16; ++q) {
        f32x4 v = (f32x4){pooled[q * 4], pooled[q * 4 + 1], pooled[q * 4 + 2], pooled[q * 4 + 3]};
        *(f32x4*)(ws + WS_POOLI + (size_t)b * 64 + q * 4) = v;
    }
}

// ================= per-lane front-end: EEG + EOG -> featI[B][64] ===========
__global__ __launch_bounds__(256, 2) void mcaf_front(
    const float* __restrict__ eog,
    const float* __restrict__ eeg_cb,
    const float* __restrict__ eog_inw, const float* __restrict__ eog_inb,
    const float* __restrict__ eog_ow,  const float* __restrict__ eog_ob,
    const float* __restrict__ eog_cb,
    float* __restrict__ ws)
{
    const int b = blockIdx.x * 256 + threadIdx.x;

    float pooled[64];
    #pragma unroll
    for (int q = 0; q < 16; ++q) {
        f32x4 v = *(const f32x4*)(ws + WS_POOLI + (size_t)b * 64 + q * 4);
        pooled[q * 4] = v[0]; pooled[q * 4 + 1] = v[1];
        pooled[q * 4 + 2] = v[2]; pooled[q * 4 + 3] = v[3];
    }

    float h[32];
    #pragma unroll
    for (int o = 0; o < 32; ++o) h[o] = eeg_cb[o];

    for (int c = 0; c < 62; ++c) {
        const float* Mr = ws + WS_M + c * 62;
        float oc0 = ws[WS_OBB + c], oc1 = 0.f;
        #pragma unroll
        for (int e = 0; e < 62; e += 2) {
            oc0 = fmaf(Mr[e],     pooled[e],     oc0);
            oc1 = fmaf(Mr[e + 1], pooled[e + 1], oc1);
        }
        float oc = oc0 + oc1;
        f32x4 xv = *(const f32x4*)(ws + WS_EEGX4 + (size_t)(c * NB + b) * 4);
        float x4 = ws[WS_EEGX1 + c * NB + b];
        const float* cwr = ws + WS_CWT + c * 160;
        #pragma unroll
        for (int o = 0; o < 32; ++o) {
            float tt = xv[0] * cwr[o * 5 + 0];
            tt = fmaf(xv[1], cwr[o * 5 + 1], tt);
            tt = fmaf(xv[2], cwr[o * 5 + 2], tt);
            tt = fmaf(xv[3], cwr[o * 5 + 3], tt);
            tt = fmaf(x4,    cwr[o * 5 + 4], tt);
            h[o] = fmaf(oc, tt, h[o]);
        }
    }
    #pragma unroll
    for (int o = 0; o < 32; ++o) h[o] = h[o] > 0.f ? h[o] : expm1f(h[o]);

    float feat[64];
    #pragma unroll
    for (int f = 0; f < 64; ++f) {
        float acc = ws[WS_B0 + f];
        #pragma unroll
        for (int o = 0; o < 32; ++o)
            acc = fmaf(ws[WS_A_EEG + f * 32 + o], h[o], acc);
        feat[f] = acc;
    }

    // ---- EOG branch (direct row-major read; wave footprint 8.4KB, L2-hot) ----
    {
        float Tg[32];
        #pragma unroll
        for (int o = 0; o < 32; ++o) Tg[o] = 0.f;
        float pool = 0.f;
        const float* er = eog + (size_t)b * 33;
        for (int l2 = 0; l2 < 33; ++l2) {
            float x = er[l2];
            pool += x;
            const float* cr = ws + WS_CWOG + l2 * 32;
            #pragma unroll
            for (int o = 0; o < 32; ++o) Tg[o] = fmaf(x, cr[o], Tg[o]);
        }
        pool *= (1.f / 33.f);
        float vb2 = fmaf(pool, eog_inw[2], eog_inb[2]);
        float ob2 = fmaf(vb2, eog_ow[0], eog_ob[0]);
        #pragma unroll
        for (int o = 0; o < 32; ++o) {
            float hh = fmaf(ob2, Tg[o], eog_cb[o]);
            Tg[o] = hh > 0.f ? hh : expm1f(hh);
        }
        #pragma unroll
        for (int f = 0; f < 64; ++f) {
            float acc = feat[f];
            #pragma unroll
            for (int o = 0; o < 32; ++o)
                acc = fmaf(ws[WS_A_EOG + f * 32 + o], Tg[o], acc);
            feat[f] = acc;
        }
    }

    // store featI[b][64] (overlays poolI[b] — this thread has finished reading it)
    #pragma unroll
    for (int q = 0; q < 16; ++q) {
        f32x4 v = (f32x4){feat[q * 4], feat[q * 4 + 1], feat[q * 4 + 2], feat[q * 4 + 3]};
        *(f32x4*)(ws + WS_FEATI + (size_t)b * 64 + q * 4) = v;
    }
}

// ================= transformer + head (wave-coop MFMA, barrier-free) =======
__global__ __launch_bounds__(256, 2) void mcaf_trans(
    const float* __restrict__ tl_ln1_s, const float* __restrict__ tl_ln1_b,
    const float* __restrict__ tl_ln2_s, const float* __restrict__ tl_ln2_b,
    const float* __restrict__ tl_b1,   const float* __restrict__ tl_b2,
    const float* __restrict__ fn_s,    const float* __restrict__ fn_b,
    const float* __restrict__ cls_w,   const float* __restrict__ cls_b,
    const float* __restrict__ ws,      float* __restrict__ out)
{
    __shared__ char smem[4 * WAVE_LDS];
    const int tid  = threadIdx.x;
    const int lane = tid & 63;
    const int wid  = tid >> 6;
    const int b    = blockIdx.x * 256 + tid;
    char* Wv = smem + wid * WAVE_LDS;
    const int g4  = lane >> 4;
    const int r15 = lane & 15;

    float feat[64];
    #pragma unroll
    for (int q = 0; q < 16; ++q) {
        f32x4 v = *(const f32x4*)(ws + WS_FEATI + (size_t)b * 64 + q * 4);
        feat[q * 4] = v[0]; feat[q * 4 + 1] = v[1];
        feat[q * 4 + 2] = v[2]; feat[q * 4 + 3] = v[3];
    }

    const short* WAb = (const short*)(ws + WB_WA_F);
    const short* W1b = (const short*)(ws + WB_W1_F);
    const short* W2b = (const short*)(ws + WB_W2_F);

    for (int i2 = 0; i2 < 2; ++i2) {
        const float* ba  = ws + WS_BATT + i2 * 64;
        const float* s1  = tl_ln1_s + i2 * 64;
        const float* gb1 = tl_ln1_b + i2 * 64;
        const float* s2  = tl_ln2_s + i2 * 64;
        const float* gb2 = tl_ln2_b + i2 * 64;
        const float* bf1 = tl_b1 + i2 * 256;
        const float* bf2 = tl_b2 + i2 * 64;

        float hb[64];
        // LN1
        {
            float m = 0.f;
            #pragma unroll
            for (int d = 0; d < 64; ++d) m += feat[d];
            m *= 0.015625f;
            float vv = 0.f;
            #pragma unroll
            for (int d = 0; d < 64; ++d) { float u = feat[d] - m; vv = fmaf(u, u, vv); }
            vv *= 0.015625f;
            float inv = rsqrtf(vv + 1e-5f);
            #pragma unroll
            for (int d = 0; d < 64; ++d)
                hb[d] = fmaf((feat[d] - m) * inv, s1[d], gb1[d]);
        }
        #pragma unroll
        for (int jj = 0; jj < 8; ++jj) {
            bf16x8 v;
            #pragma unroll
            for (int e = 0; e < 8; ++e) v[e] = f2bf(hb[jj * 8 + e]);
            *(bf16x8*)(Wv + lane * ROWB + jj * 16) = v;
        }
        SYNC();
        bf16x8 Aat[4][2];
        #pragma unroll
        for (int rt = 0; rt < 4; ++rt)
            #pragma unroll
            for (int kt = 0; kt < 2; ++kt)
                Aat[rt][kt] = *(const bf16x8*)(Wv + (rt * 16 + r15) * ROWB + (kt * 4 + g4) * 16);
        SYNC();
        f32x4 acc[4][4];
        #pragma unroll
        for (int rt = 0; rt < 4; ++rt)
            #pragma unroll
            for (int ct = 0; ct < 4; ++ct) acc[rt][ct] = (f32x4){0.f, 0.f, 0.f, 0.f};
        #pragma unroll
        for (int kt = 0; kt < 2; ++kt) {
            bf16x8 bb[4];
            #pragma unroll
            for (int ct = 0; ct < 4; ++ct)
                bb[ct] = *(const bf16x8*)(WAb + i2 * 4096 + (ct * 16 + r15) * 64 + kt * 32 + g4 * 8);
            #pragma unroll
            for (int rt = 0; rt < 4; ++rt)
                #pragma unroll
                for (int ct = 0; ct < 4; ++ct)
                    acc[rt][ct] = __builtin_amdgcn_mfma_f32_16x16x32_bf16(Aat[rt][kt], bb[ct], acc[rt][ct], 0, 0, 0);
        }
        #pragma unroll
        for (int hf = 0; hf < 2; ++hf) {
            SYNC();
            #pragma unroll
            for (int ct2 = 0; ct2 < 2; ++ct2) {
                int ct = hf * 2 + ct2;
                #pragma unroll
                for (int rt = 0; rt < 4; ++rt)
                    #pragma unroll
                    for (int rg = 0; rg < 4; ++rg) {
                        int row = rt * 16 + g4 * 4 + rg;
                        int lc  = ct2 * 16 + r15;
                        *(float*)(Wv + row * ROWB + lc * 4) = acc[rt][ct][rg];
                    }
            }
            SYNC();
            #pragma unroll
            for (int j8 = 0; j8 < 8; ++j8) {
                f32x4 v = *(const f32x4*)(Wv + lane * ROWB + j8 * 16);
                #pragma unroll
                for (int e = 0; e < 4; ++e) {
                    int d = hf * 32 + j8 * 4 + e;
                    feat[d] += v[e] + ba[d];
                }
            }
        }
        // LN2
        {
            float m = 0.f;
            #pragma unroll
            for (int d = 0; d < 64; ++d) m += feat[d];
            m *= 0.015625f;
            float vv = 0.f;
            #pragma unroll
            for (int d = 0; d < 64; ++d) { float u = feat[d] - m; vv = fmaf(u, u, vv); }
            vv *= 0.015625f;
            float inv = rsqrtf(vv + 1e-5f);
            #pragma unroll
            for (int d = 0; d < 64; ++d)
                hb[d] = fmaf((feat[d] - m) * inv, s2[d], gb2[d]);
        }
        SYNC();
        #pragma unroll
        for (int jj = 0; jj < 8; ++jj) {
            bf16x8 v;
            #pragma unroll
            for (int e = 0; e < 8; ++e) v[e] = f2bf(hb[jj * 8 + e]);
            *(bf16x8*)(Wv + lane * ROWB + jj * 16) = v;
        }
        SYNC();
        f32x4 F[4][4];
        #pragma unroll
        for (int rt = 0; rt < 4; ++rt)
            #pragma unroll
            for (int ct = 0; ct < 4; ++ct) F[rt][ct] = (f32x4){0.f, 0.f, 0.f, 0.f};

        for (int ch = 0; ch < 8; ++ch) {
            f32x4 G[4][2];
            #pragma unroll
            for (int rt = 0; rt < 4; ++rt) {
                G[rt][0] = (f32x4){0.f, 0.f, 0.f, 0.f};
                G[rt][1] = (f32x4){0.f, 0.f, 0.f, 0.f};
            }
            #pragma unroll
            for (int kt = 0; kt < 2; ++kt) {
                bf16x8 a1[4];
                #pragma unroll
                for (int rt = 0; rt < 4; ++rt)
                    a1[rt] = *(const bf16x8*)(Wv + (rt * 16 + r15) * ROWB + (kt * 4 + g4) * 16);
                bf16x8 b1[2];
                #pragma unroll
                for (int cc = 0; cc < 2; ++cc)
                    b1[cc] = *(const bf16x8*)(W1b + i2 * 16384 + (ch * 32 + cc * 16 + r15) * 64 + kt * 32 + g4 * 8);
                #pragma unroll
                for (int rt = 0; rt < 4; ++rt)
                    #pragma unroll
                    for (int cc = 0; cc < 2; ++cc)
                        G[rt][cc] = __builtin_amdgcn_mfma_f32_16x16x32_bf16(a1[rt], b1[cc], G[rt][cc], 0, 0, 0);
            }
            SYNC();
            #pragma unroll
            for (int rt = 0; rt < 4; ++rt)
                #pragma unroll
                for (int cc = 0; cc < 2; ++cc) {
                    float bj = bf1[ch * 32 + cc * 16 + r15];
                    #pragma unroll
                    for (int rg = 0; rg < 4; ++rg) {
                        float v = G[rt][cc][rg] + bj;
                        v = 0.5f * v * (1.f + erff(v * 0.70710678118654752f));
                        int row = rt * 16 + g4 * 4 + rg;
                        int col = cc * 16 + r15;
                        *(short*)(Wv + row * ROWB + 128 + ((col >> 3) << 4) + ((col & 7) << 1)) = f2bf(v);
                    }
                }
            SYNC();
            bf16x8 a2[4], b2[4];
            #pragma unroll
            for (int rt = 0; rt < 4; ++rt)
                a2[rt] = *(const bf16x8*)(Wv + (rt * 16 + r15) * ROWB + 128 + g4 * 16);
            #pragma unroll
            for (int ct = 0; ct < 4; ++ct)
                b2[ct] = *(const bf16x8*)(W2b + i2 * 16384 + (ct * 16 + r15) * 256 + ch * 32 + g4 * 8);
            #pragma unroll
            for (int rt = 0; rt < 4; ++rt)
                #pragma unroll
                for (int ct = 0; ct < 4; ++ct)
                    F[rt][ct] = __builtin_amdgcn_mfma_f32_16x16x32_bf16(a2[rt], b2[ct], F[rt][ct], 0, 0, 0);
            SYNC();
        }
        #pragma unroll
        for (int hf = 0; hf < 2; ++hf) {
            SYNC();
            #pragma unroll
            for (int ct2 = 0; ct2 < 2; ++ct2) {
                int ct = hf * 2 + ct2;
                #pragma unroll
                for (int rt = 0; rt < 4; ++rt)
                    #pragma unroll
                    for (int rg = 0; rg < 4; ++rg) {
                        int row = rt * 16 + g4 * 4 + rg;
                        int lc  = ct2 * 16 + r15;
                        *(float*)(Wv + row * ROWB + lc * 4) = F[rt][ct][rg];
                    }
            }
            SYNC();
            #pragma unroll
            for (int j8 = 0; j8 < 8; ++j8) {
                f32x4 v = *(const f32x4*)(Wv + lane * ROWB + j8 * 16);
                #pragma unroll
                for (int e = 0; e < 4; ++e) {
                    int d = hf * 32 + j8 * 4 + e;
                    feat[d] += v[e] + bf2[d];
                }
            }
        }
        SYNC();
    }

    // ---- final LN + classifier ----
    {
        float m = 0.f;
        #pragma unroll
        for (int d = 0; d < 64; ++d) m += feat[d];
        m *= 0.015625f;
        float vv = 0.f;
        #pragma unroll
        for (int d = 0; d < 64; ++d) { float u = feat[d] - m; vv = fmaf(u, u, vv); }
        vv *= 0.015625f;
        float inv = rsqrtf(vv + 1e-5f);
        float o0 = cls_b[0], o1 = cls_b[1], o2 = cls_b[2];
        #pragma unroll
        for (int d = 0; d < 64; ++d) {
            float n = fmaf((feat[d] - m) * inv, fn_s[d], fn_b[d]);
            o0 = fmaf(n, cls_w[d], o0);
            o1 = fmaf(n, cls_w[64 + d], o1);
            o2 = fmaf(n, cls_w[128 + d], o2);
        }
        float* op = out + (size_t)b * 3;
        op[0] = o0; op[1] = o1; op[2] = o2;
    }
}

// ================= fallback main kernel (fp32, LDS staging) =================
__global__ __launch_bounds__(256, 2) void mcaf_main_fb(
    const float* __restrict__ eeg,     const float* __restrict__ eog,
    const float* __restrict__ eeg_inb,
    const float* __restrict__ eeg_ow,  const float* __restrict__ eeg_ob,
    const float* __restrict__ eog_inw, const float* __restrict__ eog_inb,
    const float* __restrict__ eog_ow,  const float* __restrict__ eog_ob,
    const float* __restrict__ eeg_cb,  const float* __restrict__ eog_cb,
    const float* __restrict__ tl_ln1_s, const float* __restrict__ tl_ln1_b,
    const float* __restrict__ tl_ln2_s, const float* __restrict__ tl_ln2_b,
    const float* __restrict__ tl_w1,   const float* __restrict__ tl_b1,
    const float* __restrict__ tl_b2,
    const float* __restrict__ fn_s,    const float* __restrict__ fn_b,
    const float* __restrict__ cls_w,   const float* __restrict__ cls_b,
    const float* __restrict__ ws,      float* __restrict__ out)
{
    __shared__ float smem[4 * 64 * 41];
    const int t    = threadIdx.x;
    const int lane = t & 63;
    const int wid  = t >> 6;
    const int bw   = blockIdx.x * 256 + wid * 64;
    const int b    = bw + lane;
    float* sw = smem + wid * (64 * 41);

    float vbar[62];
    #pragma unroll
    for (int d = 0; d < 62; ++d) vbar[d] = eeg_inb[124 + d];

    for (int chunk = 0; chunk < 8; ++chunk) {
        const int ch0 = chunk * 8;
        for (int j = 0; j < 40; ++j) {
            int idx = j * 64 + lane;
            int r = idx / 40, cc = idx - r * 40;
            int gcol = ch0 * 5 + cc;
            float v = 0.f;
            if (gcol < 310) v = eeg[(bw + r) * 310 + gcol];
            sw[r * 41 + cc] = v;
        }
        __syncthreads();
        const int nch = (62 - ch0 < 8) ? (62 - ch0) : 8;
        for (int el = 0; el < nch; ++el) {
            const int e = ch0 + el;
            const float* xr = sw + lane * 41 + el * 5;
            float p = (xr[0] + xr[1] + xr[2] + xr[3] + xr[4]) * 0.2f;
            const float* wr = ws + WS_WVT + e * 62;
            #pragma unroll
            for (int d = 0; d < 62; ++d) vbar[d] = fmaf(p, wr[d], vbar[d]);
        }
        __syncthreads();
    }

    float h[32];
    #pragma unroll
    for (int o = 0; o < 32; ++o) h[o] = eeg_cb[o];

    for (int chunk = 0; chunk < 8; ++chunk) {
        const int ch0 = chunk * 8;
        for (int j = 0; j < 40; ++j) {
            int idx = j * 64 + lane;
            int r = idx / 40, cc = idx - r * 40;
            int gcol = ch0 * 5 + cc;
            float v = 0.f;
            if (gcol < 310) v = eeg[(bw + r) * 310 + gcol];
            sw[r * 41 + cc] = v;
        }
        __syncthreads();
        const int nch = (62 - ch0 < 8) ? (62 - ch0) : 8;
        for (int el = 0; el < nch; ++el) {
            const int c = ch0 + el;
            const float* owr = eeg_ow + c * 62;
            float oc = eeg_ob[c];
            #pragma unroll
            for (int d = 0; d < 62; ++d) oc = fmaf(owr[d], vbar[d], oc);
            const float* xr = sw + lane * 41 + el * 5;
            float x0 = xr[0], x1 = xr[1], x2 = xr[2], x3 = xr[3], x4 = xr[4];
            const float* cwr = ws + WS_CWT + c * 160;
            #pragma unroll
            for (int o = 0; o < 32; ++o) {
                float tt = x0 * cwr[o * 5 + 0];
                tt = fmaf(x1, cwr[o * 5 + 1], tt);
                tt = fmaf(x2, cwr[o * 5 + 2], tt);
                tt = fmaf(x3, cwr[o * 5 + 3], tt);
                tt = fmaf(x4, cwr[o * 5 + 4], tt);
                h[o] = fmaf(oc, tt, h[o]);
            }
        }
        __syncthreads();
    }

    #pragma unroll
    for (int o = 0; o < 32; ++o) h[o] = h[o] > 0.f ? h[o] : expm1f(h[o]);

    float feat[64];
    #pragma unroll
    for (int f = 0; f < 64; ++f) {
        float acc = ws[WS_B0 + f];
        #pragma unroll
        for (int o = 0; o < 32; ++o)
            acc = fmaf(ws[WS_A_EEG + f * 32 + o], h[o], acc);
        feat[f] = acc;
    }

    for (int j = 0; j < 33; ++j) {
        int idx = j * 64 + lane;
        int r = idx / 33, cc = idx - r * 33;
        sw[r * 34 + cc] = eog[(bw + r) * 33 + cc];
    }
    __syncthreads();
    {
        float Tg[32];
        #pragma unroll
        for (int o = 0; o < 32; ++o) Tg[o] = 0.f;
        float pool = 0.f;
        for (int l2 = 0; l2 < 33; ++l2) {
            float x = sw[lane * 34 + l2];
            pool += x;
            const float* cr = ws + WS_CWOG + l2 * 32;
            #pragma unroll
            for (int o = 0; o < 32; ++o) Tg[o] = fmaf(x, cr[o], Tg[o]);
        }
        pool *= (1.f / 33.f);
        float vb2 = fmaf(pool, eog_inw[2], eog_inb[2]);
        float ob2 = fmaf(vb2, eog_ow[0], eog_ob[0]);
        #pragma unroll
        for (int o = 0; o < 32; ++o) {
            float hh = fmaf(ob2, Tg[o], eog_cb[o]);
            Tg[o] = hh > 0.f ? hh : expm1f(hh);
        }
        #pragma unroll
        for (int f = 0; f < 64; ++f) {
            float acc = feat[f];
            #pragma unroll
            for (int o = 0; o < 32; ++o)
                acc = fmaf(ws[WS_A_EOG + f * 32 + o], Tg[o], acc);
            feat[f] = acc;
        }
    }

    for (int i2 = 0; i2 < 2; ++i2) {
        const float* Wa  = ws + WS_WATT + i2 * 4096;
        const float* ba  = ws + WS_BATT + i2 * 64;
        const float* s1  = tl_ln1_s + i2 * 64;
        const float* g1  = tl_ln1_b + i2 * 64;
        const float* s2  = tl_ln2_s + i2 * 64;
        const float* g2  = tl_ln2_b + i2 * 64;
        const float* w1p = tl_w1 + i2 * 16384;
        const float* bf1 = tl_b1 + i2 * 256;
        const float* w2t = ws + WS_W2T + i2 * 16384;
        const float* bf2 = tl_b2 + i2 * 64;

        float hb[64];
        {
            float m = 0.f;
            #pragma unroll
            for (int d = 0; d < 64; ++d) m += feat[d];
            m *= 0.015625f;
            float vv = 0.f;
            #pragma unroll
            for (int d = 0; d < 64; ++d) { float u = feat[d] - m; vv = fmaf(u, u, vv); }
            vv *= 0.015625f;
            float inv = rsqrtf(vv + 1e-5f);
            #pragma unroll
            for (int d = 0; d < 64; ++d)
                hb[d] = fmaf((feat[d] - m) * inv, s1[d], g1[d]);
        }
        #pragma unroll
        for (int c = 0; c < 64; ++c) {
            float a = ba[c];
            #pragma unroll
            for (int d = 0; d < 64; ++d) a = fmaf(Wa[c * 64 + d], hb[d], a);
            feat[c] += a;
        }
        {
            float m = 0.f;
            #pragma unroll
            for (int d = 0; d < 64; ++d) m += feat[d];
            m *= 0.015625f;
            float vv = 0.f;
            #pragma unroll
            for (int d = 0; d < 64; ++d) { float u = feat[d] - m; vv = fmaf(u, u, vv); }
            vv *= 0.015625f;
            float inv = rsqrtf(vv + 1e-5f);
            #pragma unroll
            for (int d = 0; d < 64; ++d)
                hb[d] = fmaf((feat[d] - m) * inv, s2[d], g2[d]);
        }
        #pragma unroll
        for (int c = 0; c < 64; ++c) feat[c] += bf2[c];
        for (int j = 0; j < 256; ++j) {
            const float* wr = w1p + j * 64;
            float g = bf1[j];
            #pragma unroll
            for (int d = 0; d < 64; ++d) g = fmaf(wr[d], hb[d], g);
            g = 0.5f * g * (1.f + erff(g * 0.70710678118654752f));
            const float* w2r = w2t + j * 64;
            #pragma unroll
            for (int c = 0; c < 64; ++c) feat[c] = fmaf(g, w2r[c], feat[c]);
        }
    }

    {
        float m = 0.f;
        #pragma unroll
        for (int d = 0; d < 64; ++d) m += feat[d];
        m *= 0.015625f;
        float vv = 0.f;
        #pragma unroll
        for (int d = 0; d < 64; ++d) { float u = feat[d] - m; vv = fmaf(u, u, vv); }
        vv *= 0.015625f;
        float inv = rsqrtf(vv + 1e-5f);
        float o0 = cls_b[0], o1 = cls_b[1], o2 = cls_b[2];
        #pragma unroll
        for (int d = 0; d < 64; ++d) {
            float n = fmaf((feat[d] - m) * inv, fn_s[d], fn_b[d]);
            o0 = fmaf(n, cls_w[d], o0);
            o1 = fmaf(n, cls_w[64 + d], o1);
            o2 = fmaf(n, cls_w[128 + d], o2);
        }
        float* op = out + b * 3;
        op[0] = o0; op[1] = o1; op[2] = o2;
    }
}

extern "C" void kernel_launch(void* const* d_in, const int* in_sizes, int n_in,
                              void* d_out, int out_size, void* d_ws, size_t ws_size,
                              hipStream_t stream) {
    const float* eeg      = (const float*)d_in[0];
    const float* eog      = (const float*)d_in[1];
    const float* eeg_inw  = (const float*)d_in[2];
    const float* eeg_inb  = (const float*)d_in[3];
    const float* eeg_ow   = (const float*)d_in[4];
    const float* eeg_ob   = (const float*)d_in[5];
    const float* eog_inw  = (const float*)d_in[6];
    const float* eog_inb  = (const float*)d_in[7];
    const float* eog_ow   = (const float*)d_in[8];
    const float* eog_ob   = (const float*)d_in[9];
    const float* eeg_cw   = (const float*)d_in[10];
    const float* eeg_cb   = (const float*)d_in[11];
    const float* eeg_fw   = (const float*)d_in[12];
    const float* eeg_fb   = (const float*)d_in[13];
    const float* eog_cw   = (const float*)d_in[14];
    const float* eog_cb   = (const float*)d_in[15];
    const float* eog_fw   = (const float*)d_in[16];
    const float* eog_fb   = (const float*)d_in[17];
    const float* fus_w    = (const float*)d_in[18];
    const float* fus_b    = (const float*)d_in[19];
    const float* tl_ln1_s = (const float*)d_in[20];
    const float* tl_ln1_b = (const float*)d_in[21];
    const float* tl_inw   = (const float*)d_in[22];
    const float* tl_inb   = (const float*)d_in[23];
    const float* tl_ow    = (const float*)d_in[24];
    const float* tl_ob    = (const float*)d_in[25];
    const float* tl_ln2_s = (const float*)d_in[26];
    const float* tl_ln2_b = (const float*)d_in[27];
    const float* tl_w1    = (const float*)d_in[28];
    const float* tl_b1    = (const float*)d_in[29];
    const float* tl_w2    = (const float*)d_in[30];
    const float* tl_b2    = (const float*)d_in[31];
    const float* fn_s     = (const float*)d_in[32];
    const float* fn_b     = (const float*)d_in[33];
    const float* cls_w    = (const float*)d_in[34];
    const float* cls_b    = (const float*)d_in[35];
    float* ws  = (float*)d_ws;
    float* out = (float*)d_out;

    hipLaunchKernelGGL(mcaf_pre, dim3(8), dim3(256), 0, stream,
                       eeg_inw, eeg_inb, eeg_ow, eeg_ob, eeg_cw,
                       eeg_fw, eeg_fb, eog_cw, eog_fw, eog_fb,
                       fus_w, fus_b, tl_inw, tl_inb, tl_ow, tl_ob, tl_w1, tl_w2, ws);

    const size_t need = (size_t)WS_TOTALF * 4u;
    if (ws_size >= need) {
        hipLaunchKernelGGL(eeg_tr, dim3(NB / 256), dim3(256), 0, stream, eeg, ws);
        hipLaunchKernelGGL(mcaf_front, dim3(NB / 256), dim3(256), 0, stream,
                           eog, eeg_cb, eog_inw, eog_inb, eog_ow, eog_ob, eog_cb, ws);
        hipLaunchKernelGGL(mcaf_trans, dim3(NB / 256), dim3(256), 0, stream,
                           tl_ln1_s, tl_ln1_b, tl_ln2_s, tl_ln2_b,
                           tl_b1, tl_b2, fn_s, fn_b, cls_w, cls_b, ws, out);
    } else {
        hipLaunchKernelGGL(mcaf_main_fb, dim3(NB / 256), dim3(256), 0, stream,
                           eeg, eog, eeg_inb, eeg_ow, eeg_ob,
                           eog_inw, eog_inb, eog_ow, eog_ob,
                           eeg_cb, eog_cb,
                           tl_ln1_s, tl_ln1_b, tl_ln2_s, tl_ln2_b,
                           tl_w1, tl_b1, tl_b2,
                           fn_s, fn_b, cls_w, cls_b, ws, out);
    }
}

// Round 7
// 856.548 us; speedup vs baseline: 1.0137x; 1.0137x over previous
//
#include <hip/hip_runtime.h>
#include <hip/hip_bf16.h>
#include <math.h>

#define NB 131072

typedef __attribute__((ext_vector_type(4))) float f32x4;
typedef __attribute__((ext_vector_type(8))) short bf16x8;

// Wave-local ordering fence for wave-private LDS.
#define SYNC() do { asm volatile("" ::: "memory"); __builtin_amdgcn_sched_barrier(0x7F); } while (0)

// ---- workspace layout (float offsets) ----
#define WS_A_EEG 0          // [64][32]
#define WS_A_EOG 2048       // [64][32]
#define WS_B0    4096       // [64]
#define WS_WATT  4160       // [2][64][64] f32 (fallback)
#define WS_BATT  12352      // [2][64]
#define WS_WVT   12480      // [62][62]  (fallback)
#define WS_M     16324      // [62][62]
#define WS_OBB   20168      // [62]
#define WS_CWT   20232      // [62][32][5]
#define WS_CWOG  30152      // [33][32]
#define WS_W2T   31208      // [2][256][64] f32 (fallback)
#define WB_WA_F  64000      // bf16 [2][64][64]
#define WB_W1_F  68096      // bf16 [2][256][64]
#define WB_W2_F  84480      // bf16 [2][64][256]
// lane-coalesced vector layouts (lane stride 16B within each plane):
#define WS_EEGX4 100864                     // [62][B][4]  x0..x3
#define WS_EEGX1 (WS_EEGX4 + 4 * 62 * NB)   // [62][B]     x4
#define WS_POOLI (WS_EEGX1 + 62 * NB)       // [16][B][4]  pooled chunks (62 used)
#define WS_FEATI WS_POOLI                   // [16][B][4]  feat overlays poolI:
                                            // thread b reads all poolI[*][b]
                                            // before writing featI[*][b].
#define WS_TOTALF (WS_POOLI + 64 * NB)

// per-wave LDS for trans: 64 rows x 208B (13 granules; odd -> <=2-way banks)
#define ROWB 208
#define WAVE_LDS (64 * ROWB)

__device__ __forceinline__ short f2bf(float x) {
    union { __hip_bfloat16 h; short s; } u;
    u.h = __float2bfloat16(x);
    return u.s;
}

__global__ __launch_bounds__(256) void mcaf_pre(
    const float* __restrict__ eeg_inw, const float* __restrict__ eeg_inb,
    const float* __restrict__ eeg_ow,  const float* __restrict__ eeg_ob,
    const float* __restrict__ eeg_cw,
    const float* __restrict__ eeg_fw,  const float* __restrict__ eeg_fb,
    const float* __restrict__ eog_cw,  const float* __restrict__ eog_fw,
    const float* __restrict__ eog_fb,
    const float* __restrict__ fus_w,   const float* __restrict__ fus_b,
    const float* __restrict__ tl_inw,  const float* __restrict__ tl_inb,
    const float* __restrict__ tl_ow,   const float* __restrict__ tl_ob,
    const float* __restrict__ tl_w1,   const float* __restrict__ tl_w2,
    float* __restrict__ ws)
{
    const int tid  = blockIdx.x * blockDim.x + threadIdx.x;
    const int nthr = gridDim.x * blockDim.x;
    short* wa_b = (short*)(ws + WB_WA_F);
    short* w1_b = (short*)(ws + WB_W1_F);
    short* w2_b = (short*)(ws + WB_W2_F);

    for (int idx = tid; idx < 2048; idx += nthr) {
        int f = idx >> 5, o = idx & 31;
        float a = 0.f, a2 = 0.f;
        for (int k = 0; k < 64; ++k) {
            a  = fmaf(fus_w[f * 128 + k],      eeg_fw[k * 32 + o], a);
            a2 = fmaf(fus_w[f * 128 + 64 + k], eog_fw[k * 32 + o], a2);
        }
        ws[WS_A_EEG + idx] = a;
        ws[WS_A_EOG + idx] = a2;
    }
    for (int f = tid; f < 64; f += nthr) {
        float a = fus_b[f] + (float)(f & 1);
        for (int k = 0; k < 64; ++k) {
            a = fmaf(fus_w[f * 128 + k],      eeg_fb[k], a);
            a = fmaf(fus_w[f * 128 + 64 + k], eog_fb[k], a);
        }
        ws[WS_B0 + f] = a;
    }
    for (int idx = tid; idx < 8192; idx += nthr) {
        int i = idx >> 12, c = (idx >> 6) & 63, d = idx & 63;
        float a = 0.f;
        for (int e = 0; e < 64; ++e)
            a = fmaf(tl_ow[i * 4096 + c * 64 + e],
                     tl_inw[i * 12288 + (128 + e) * 64 + d], a);
        ws[WS_WATT + idx] = a;
        wa_b[idx] = f2bf(a);
    }
    for (int idx = tid; idx < 128; idx += nthr) {
        int i = idx >> 6, c = idx & 63;
        float a = tl_ob[i * 64 + c];
        for (int e = 0; e < 64; ++e)
            a = fmaf(tl_ow[i * 4096 + c * 64 + e], tl_inb[i * 192 + 128 + e], a);
        ws[WS_BATT + idx] = a;
    }
    for (int idx = tid; idx < 32768; idx += nthr) w1_b[idx] = f2bf(tl_w1[idx]);
    for (int idx = tid; idx < 32768; idx += nthr) w2_b[idx] = f2bf(tl_w2[idx]);

    for (int idx = tid; idx < 3844; idx += nthr) {
        int e = idx / 62, d = idx - e * 62;
        ws[WS_WVT + idx] = eeg_inw[(124 + d) * 62 + e];
    }
    for (int idx = tid; idx < 3844; idx += nthr) {
        int c = idx / 62, e = idx - c * 62;
        float a = 0.f;
        for (int d = 0; d < 62; ++d)
            a = fmaf(eeg_ow[c * 62 + d], eeg_inw[(124 + d) * 62 + e], a);
        ws[WS_M + idx] = a;
    }
    for (int c = tid; c < 62; c += nthr) {
        float a = eeg_ob[c];
        for (int d = 0; d < 62; ++d)
            a = fmaf(eeg_ow[c * 62 + d], eeg_inb[124 + d], a);
        ws[WS_OBB + c] = a;
    }
    for (int idx = tid; idx < 9920; idx += nthr) {
        int c = idx / 160, r = idx - c * 160;
        int o = r / 5, l = r - o * 5;
        ws[WS_CWT + idx] = eeg_cw[o * 310 + c * 5 + l];
    }
    for (int idx = tid; idx < 1056; idx += nthr) {
        int l = idx >> 5, o = idx & 31;
        ws[WS_CWOG + idx] = eog_cw[o * 33 + l];
    }
    for (int idx = tid; idx < 32768; idx += nthr) {
        int i = idx >> 14, r = idx & 16383;
        int j = r >> 6, c = r & 63;
        ws[WS_W2T + idx] = tl_w2[i * 16384 + c * 256 + j];
    }
}

// ---- eeg re-layout + fused pooling (wave-private LDS, no barriers) ----
__global__ __launch_bounds__(256) void eeg_tr(const float* __restrict__ eeg,
                                              float* __restrict__ ws)
{
    __shared__ float smem[4 * 64 * 41];
    const int lane = threadIdx.x & 63;
    const int wid  = threadIdx.x >> 6;
    const int bw   = blockIdx.x * 256 + wid * 64;
    const int b    = bw + lane;
    float* sw = smem + wid * (64 * 41);

    float pooled[64];
    #pragma unroll
    for (int e = 0; e < 64; ++e) pooled[e] = 0.f;

    #pragma unroll
    for (int chunk = 0; chunk < 8; ++chunk) {
        const int ch0 = chunk * 40;
        for (int j = 0; j < 40; ++j) {
            int idx = j * 64 + lane;
            int r = idx / 40, cc = idx - r * 40;
            int gcol = ch0 + cc;
            float v = 0.f;
            if (gcol < 310) v = eeg[(bw + r) * 310 + gcol];
            sw[r * 41 + cc] = v;
        }
        SYNC();
        const int nch = (chunk == 7) ? 6 : 8;
        #pragma unroll
        for (int el = 0; el < 8; ++el) {
            if (el < nch) {
                int c = chunk * 8 + el;
                const float* xr = sw + lane * 41 + el * 5;
                float x0 = xr[0], x1 = xr[1], x2 = xr[2], x3 = xr[3], x4 = xr[4];
                pooled[c] = (x0 + x1 + x2 + x3 + x4) * 0.2f;
                *(f32x4*)(ws + WS_EEGX4 + (size_t)(c * NB + b) * 4) = (f32x4){x0, x1, x2, x3};
                ws[WS_EEGX1 + c * NB + b] = x4;
            }
        }
        SYNC();
    }
    // coalesced pooled chunks: lane stride 16B within each q-plane
    #pragma unroll
    for (int q = 0; q < 16; ++q) {
        f32x4 v = (f32x4){pooled[q * 4], pooled[q * 4 + 1], pooled[q * 4 + 2], pooled[q * 4 + 3]};
        *(f32x4*)(ws + WS_POOLI + (size_t)(q * NB + b) * 4) = v;
    }
}

// ================= per-lane front-end: EEG + EOG -> featI ===========
__global__ __launch_bounds__(256, 2) void mcaf_front(
    const float* __restrict__ eog,
    const float* __restrict__ eeg_cb,
    const float* __restrict__ eog_inw, const float* __restrict__ eog_inb,
    const float* __restrict__ eog_ow,  const float* __restrict__ eog_ob,
    const float* __restrict__ eog_cb,
    float* __restrict__ ws)
{
    const int b = blockIdx.x * 256 + threadIdx.x;

    float pooled[64];
    #pragma unroll
    for (int q = 0; q < 16; ++q) {
        f32x4 v = *(const f32x4*)(ws + WS_POOLI + (size_t)(q * NB + b) * 4);
        pooled[q * 4] = v[0]; pooled[q * 4 + 1] = v[1];
        pooled[q * 4 + 2] = v[2]; pooled[q * 4 + 3] = v[3];
    }

    float h[32];
    #pragma unroll
    for (int o = 0; o < 32; ++o) h[o] = eeg_cb[o];

    for (int c = 0; c < 62; ++c) {
        const float* Mr = ws + WS_M + c * 62;
        float oc0 = ws[WS_OBB + c], oc1 = 0.f;
        #pragma unroll
        for (int e = 0; e < 62; e += 2) {
            oc0 = fmaf(Mr[e],     pooled[e],     oc0);
            oc1 = fmaf(Mr[e + 1], pooled[e + 1], oc1);
        }
        float oc = oc0 + oc1;
        f32x4 xv = *(const f32x4*)(ws + WS_EEGX4 + (size_t)(c * NB + b) * 4);
        float x4 = ws[WS_EEGX1 + c * NB + b];
        const float* cwr = ws + WS_CWT + c * 160;
        #pragma unroll
        for (int o = 0; o < 32; ++o) {
            float tt = xv[0] * cwr[o * 5 + 0];
            tt = fmaf(xv[1], cwr[o * 5 + 1], tt);
            tt = fmaf(xv[2], cwr[o * 5 + 2], tt);
            tt = fmaf(xv[3], cwr[o * 5 + 3], tt);
            tt = fmaf(x4,    cwr[o * 5 + 4], tt);
            h[o] = fmaf(oc, tt, h[o]);
        }
    }
    #pragma unroll
    for (int o = 0; o < 32; ++o) h[o] = h[o] > 0.f ? h[o] : expm1f(h[o]);

    float feat[64];
    #pragma unroll
    for (int f = 0; f < 64; ++f) {
        float acc = ws[WS_B0 + f];
        #pragma unroll
        for (int o = 0; o < 32; ++o)
            acc = fmaf(ws[WS_A_EEG + f * 32 + o], h[o], acc);
        feat[f] = acc;
    }

    // ---- EOG branch (direct row-major read; wave footprint 8.4KB, L1-hot) ----
    {
        float Tg[32];
        #pragma unroll
        for (int o = 0; o < 32; ++o) Tg[o] = 0.f;
        float pool = 0.f;
        const float* er = eog + (size_t)b * 33;
        for (int l2 = 0; l2 < 33; ++l2) {
            float x = er[l2];
            pool += x;
            const float* cr = ws + WS_CWOG + l2 * 32;
            #pragma unroll
            for (int o = 0; o < 32; ++o) Tg[o] = fmaf(x, cr[o], Tg[o]);
        }
        pool *= (1.f / 33.f);
        float vb2 = fmaf(pool, eog_inw[2], eog_inb[2]);
        float ob2 = fmaf(vb2, eog_ow[0], eog_ob[0]);
        #pragma unroll
        for (int o = 0; o < 32; ++o) {
            float hh = fmaf(ob2, Tg[o], eog_cb[o]);
            Tg[o] = hh > 0.f ? hh : expm1f(hh);
        }
        #pragma unroll
        for (int f = 0; f < 64; ++f) {
            float acc = feat[f];
            #pragma unroll
            for (int o = 0; o < 32; ++o)
                acc = fmaf(ws[WS_A_EOG + f * 32 + o], Tg[o], acc);
            feat[f] = acc;
        }
    }

    // store featI chunks (coalesced; overlays poolI which this thread is done with)
    #pragma unroll
    for (int q = 0; q < 16; ++q) {
        f32x4 v = (f32x4){feat[q * 4], feat[q * 4 + 1], feat[q * 4 + 2], feat[q * 4 + 3]};
        *(f32x4*)(ws + WS_FEATI + (size_t)(q * NB + b) * 4) = v;
    }
}

// ================= transformer + head (wave-coop MFMA, barrier-free) =======
__global__ __launch_bounds__(256, 2) void mcaf_trans(
    const float* __restrict__ tl_ln1_s, const float* __restrict__ tl_ln1_b,
    const float* __restrict__ tl_ln2_s, const float* __restrict__ tl_ln2_b,
    const float* __restrict__ tl_b1,   const float* __restrict__ tl_b2,
    const float* __restrict__ fn_s,    const float* __restrict__ fn_b,
    const float* __restrict__ cls_w,   const float* __restrict__ cls_b,
    const float* __restrict__ ws,      float* __restrict__ out)
{
    __shared__ char smem[4 * WAVE_LDS];
    const int tid  = threadIdx.x;
    const int lane = tid & 63;
    const int wid  = tid >> 6;
    const int b    = blockIdx.x * 256 + tid;
    char* Wv = smem + wid * WAVE_LDS;
    const int g4  = lane >> 4;
    const int r15 = lane & 15;

    float feat[64];
    #pragma unroll
    for (int q = 0; q < 16; ++q) {
        f32x4 v = *(const f32x4*)(ws + WS_FEATI + (size_t)(q * NB + b) * 4);
        feat[q * 4] = v[0]; feat[q * 4 + 1] = v[1];
        feat[q * 4 + 2] = v[2]; feat[q * 4 + 3] = v[3];
    }

    const short* WAb = (const short*)(ws + WB_WA_F);
    const short* W1b = (const short*)(ws + WB_W1_F);
    const short* W2b = (const short*)(ws + WB_W2_F);

    for (int i2 = 0; i2 < 2; ++i2) {
        const float* ba  = ws + WS_BATT + i2 * 64;
        const float* s1  = tl_ln1_s + i2 * 64;
        const float* gb1 = tl_ln1_b + i2 * 64;
        const float* s2  = tl_ln2_s + i2 * 64;
        const float* gb2 = tl_ln2_b + i2 * 64;
        const float* bf1 = tl_b1 + i2 * 256;
        const float* bf2 = tl_b2 + i2 * 64;

        float hb[64];
        // LN1
        {
            float m = 0.f;
            #pragma unroll
            for (int d = 0; d < 64; ++d) m += feat[d];
            m *= 0.015625f;
            float vv = 0.f;
            #pragma unroll
            for (int d = 0; d < 64; ++d) { float u = feat[d] - m; vv = fmaf(u, u, vv); }
            vv *= 0.015625f;
            float inv = rsqrtf(vv + 1e-5f);
            #pragma unroll
            for (int d = 0; d < 64; ++d)
                hb[d] = fmaf((feat[d] - m) * inv, s1[d], gb1[d]);
        }
        #pragma unroll
        for (int jj = 0; jj < 8; ++jj) {
            bf16x8 v;
            #pragma unroll
            for (int e = 0; e < 8; ++e) v[e] = f2bf(hb[jj * 8 + e]);
            *(bf16x8*)(Wv + lane * ROWB + jj * 16) = v;
        }
        SYNC();
        bf16x8 Aat[4][2];
        #pragma unroll
        for (int rt = 0; rt < 4; ++rt)
            #pragma unroll
            for (int kt = 0; kt < 2; ++kt)
                Aat[rt][kt] = *(const bf16x8*)(Wv + (rt * 16 + r15) * ROWB + (kt * 4 + g4) * 16);
        SYNC();
        f32x4 acc[4][4];
        #pragma unroll
        for (int rt = 0; rt < 4; ++rt)
            #pragma unroll
            for (int ct = 0; ct < 4; ++ct) acc[rt][ct] = (f32x4){0.f, 0.f, 0.f, 0.f};
        #pragma unroll
        for (int kt = 0; kt < 2; ++kt) {
            bf16x8 bb[4];
            #pragma unroll
            for (int ct = 0; ct < 4; ++ct)
                bb[ct] = *(const bf16x8*)(WAb + i2 * 4096 + (ct * 16 + r15) * 64 + kt * 32 + g4 * 8);
            #pragma unroll
            for (int rt = 0; rt < 4; ++rt)
                #pragma unroll
                for (int ct = 0; ct < 4; ++ct)
                    acc[rt][ct] = __builtin_amdgcn_mfma_f32_16x16x32_bf16(Aat[rt][kt], bb[ct], acc[rt][ct], 0, 0, 0);
        }
        #pragma unroll
        for (int hf = 0; hf < 2; ++hf) {
            SYNC();
            #pragma unroll
            for (int ct2 = 0; ct2 < 2; ++ct2) {
                int ct = hf * 2 + ct2;
                #pragma unroll
                for (int rt = 0; rt < 4; ++rt)
                    #pragma unroll
                    for (int rg = 0; rg < 4; ++rg) {
                        int row = rt * 16 + g4 * 4 + rg;
                        int lc  = ct2 * 16 + r15;
                        *(float*)(Wv + row * ROWB + lc * 4) = acc[rt][ct][rg];
                    }
            }
            SYNC();
            #pragma unroll
            for (int j8 = 0; j8 < 8; ++j8) {
                f32x4 v = *(const f32x4*)(Wv + lane * ROWB + j8 * 16);
                #pragma unroll
                for (int e = 0; e < 4; ++e) {
                    int d = hf * 32 + j8 * 4 + e;
                    feat[d] += v[e] + ba[d];
                }
            }
        }
        // LN2
        {
            float m = 0.f;
            #pragma unroll
            for (int d = 0; d < 64; ++d) m += feat[d];
            m *= 0.015625f;
            float vv = 0.f;
            #pragma unroll
            for (int d = 0; d < 64; ++d) { float u = feat[d] - m; vv = fmaf(u, u, vv); }
            vv *= 0.015625f;
            float inv = rsqrtf(vv + 1e-5f);
            #pragma unroll
            for (int d = 0; d < 64; ++d)
                hb[d] = fmaf((feat[d] - m) * inv, s2[d], gb2[d]);
        }
        SYNC();
        #pragma unroll
        for (int jj = 0; jj < 8; ++jj) {
            bf16x8 v;
            #pragma unroll
            for (int e = 0; e < 8; ++e) v[e] = f2bf(hb[jj * 8 + e]);
            *(bf16x8*)(Wv + lane * ROWB + jj * 16) = v;
        }
        SYNC();
        f32x4 F[4][4];
        #pragma unroll
        for (int rt = 0; rt < 4; ++rt)
            #pragma unroll
            for (int ct = 0; ct < 4; ++ct) F[rt][ct] = (f32x4){0.f, 0.f, 0.f, 0.f};

        for (int ch = 0; ch < 8; ++ch) {
            f32x4 G[4][2];
            #pragma unroll
            for (int rt = 0; rt < 4; ++rt) {
                G[rt][0] = (f32x4){0.f, 0.f, 0.f, 0.f};
                G[rt][1] = (f32x4){0.f, 0.f, 0.f, 0.f};
            }
            #pragma unroll
            for (int kt = 0; kt < 2; ++kt) {
                bf16x8 a1[4];
                #pragma unroll
                for (int rt = 0; rt < 4; ++rt)
                    a1[rt] = *(const bf16x8*)(Wv + (rt * 16 + r15) * ROWB + (kt * 4 + g4) * 16);
                bf16x8 b1[2];
                #pragma unroll
                for (int cc = 0; cc < 2; ++cc)
                    b1[cc] = *(const bf16x8*)(W1b + i2 * 16384 + (ch * 32 + cc * 16 + r15) * 64 + kt * 32 + g4 * 8);
                #pragma unroll
                for (int rt = 0; rt < 4; ++rt)
                    #pragma unroll
                    for (int cc = 0; cc < 2; ++cc)
                        G[rt][cc] = __builtin_amdgcn_mfma_f32_16x16x32_bf16(a1[rt], b1[cc], G[rt][cc], 0, 0, 0);
            }
            SYNC();
            #pragma unroll
            for (int rt = 0; rt < 4; ++rt)
                #pragma unroll
                for (int cc = 0; cc < 2; ++cc) {
                    float bj = bf1[ch * 32 + cc * 16 + r15];
                    #pragma unroll
                    for (int rg = 0; rg < 4; ++rg) {
                        float v = G[rt][cc][rg] + bj;
                        v = 0.5f * v * (1.f + erff(v * 0.70710678118654752f));
                        int row = rt * 16 + g4 * 4 + rg;
                        int col = cc * 16 + r15;
                        *(short*)(Wv + row * ROWB + 128 + ((col >> 3) << 4) + ((col & 7) << 1)) = f2bf(v);
                    }
                }
            SYNC();
            bf16x8 a2[4], b2[4];
            #pragma unroll
            for (int rt = 0; rt < 4; ++rt)
                a2[rt] = *(const bf16x8*)(Wv + (rt * 16 + r15) * ROWB + 128 + g4 * 16);
            #pragma unroll
            for (int ct = 0; ct < 4; ++ct)
                b2[ct] = *(const bf16x8*)(W2b + i2 * 16384 + (ct * 16 + r15) * 256 + ch * 32 + g4 * 8);
            #pragma unroll
            for (int rt = 0; rt < 4; ++rt)
                #pragma unroll
                for (int ct = 0; ct < 4; ++ct)
                    F[rt][ct] = __builtin_amdgcn_mfma_f32_16x16x32_bf16(a2[rt], b2[ct], F[rt][ct], 0, 0, 0);
            SYNC();
        }
        #pragma unroll
        for (int hf = 0; hf < 2; ++hf) {
            SYNC();
            #pragma unroll
            for (int ct2 = 0; ct2 < 2; ++ct2) {
                int ct = hf * 2 + ct2;
                #pragma unroll
                for (int rt = 0; rt < 4; ++rt)
                    #pragma unroll
                    for (int rg = 0; rg < 4; ++rg) {
                        int row = rt * 16 + g4 * 4 + rg;
                        int lc  = ct2 * 16 + r15;
                        *(float*)(Wv + row * ROWB + lc * 4) = F[rt][ct][rg];
                    }
            }
            SYNC();
            #pragma unroll
            for (int j8 = 0; j8 < 8; ++j8) {
                f32x4 v = *(const f32x4*)(Wv + lane * ROWB + j8 * 16);
                #pragma unroll
                for (int e = 0; e < 4; ++e) {
                    int d = hf * 32 + j8 * 4 + e;
                    feat[d] += v[e] + bf2[d];
                }
            }
        }
        SYNC();
    }

    // ---- final LN + classifier ----
    {
        float m = 0.f;
        #pragma unroll
        for (int d = 0; d < 64; ++d) m += feat[d];
        m *= 0.015625f;
        float vv = 0.f;
        #pragma unroll
        for (int d = 0; d < 64; ++d) { float u = feat[d] - m; vv = fmaf(u, u, vv); }
        vv *= 0.015625f;
        float inv = rsqrtf(vv + 1e-5f);
        float o0 = cls_b[0], o1 = cls_b[1], o2 = cls_b[2];
        #pragma unroll
        for (int d = 0; d < 64; ++d) {
            float n = fmaf((feat[d] - m) * inv, fn_s[d], fn_b[d]);
            o0 = fmaf(n, cls_w[d], o0);
            o1 = fmaf(n, cls_w[64 + d], o1);
            o2 = fmaf(n, cls_w[128 + d], o2);
        }
        float* op = out + (size_t)b * 3;
        op[0] = o0; op[1] = o1; op[2] = o2;
    }
}

// ================= fallback main kernel (fp32, LDS staging) =================
__global__ __launch_bounds__(256, 2) void mcaf_main_fb(
    const float* __restrict__ eeg,     const float* __restrict__ eog,
    const float* __restrict__ eeg_inb,
    const float* __restrict__ eeg_ow,  const float* __restrict__ eeg_ob,
    const float* __restrict__ eog_inw, const float* __restrict__ eog_inb,
    const float* __restrict__ eog_ow,  const float* __restrict__ eog_ob,
    const float* __restrict__ eeg_cb,  const float* __restrict__ eog_cb,
    const float* __restrict__ tl_ln1_s, const float* __restrict__ tl_ln1_b,
    const float* __restrict__ tl_ln2_s, const float* __restrict__ tl_ln2_b,
    const float* __restrict__ tl_w1,   const float* __restrict__ tl_b1,
    const float* __restrict__ tl_b2,
    const float* __restrict__ fn_s,    const float* __restrict__ fn_b,
    const float* __restrict__ cls_w,   const float* __restrict__ cls_b,
    const float* __restrict__ ws,      float* __restrict__ out)
{
    __shared__ float smem[4 * 64 * 41];
    const int t    = threadIdx.x;
    const int lane = t & 63;
    const int wid  = t >> 6;
    const int bw   = blockIdx.x * 256 + wid * 64;
    const int b    = bw + lane;
    float* sw = smem + wid * (64 * 41);

    float vbar[62];
    #pragma unroll
    for (int d = 0; d < 62; ++d) vbar[d] = eeg_inb[124 + d];

    for (int chunk = 0; chunk < 8; ++chunk) {
        const int ch0 = chunk * 8;
        for (int j = 0; j < 40; ++j) {
            int idx = j * 64 + lane;
            int r = idx / 40, cc = idx - r * 40;
            int gcol = ch0 * 5 + cc;
            float v = 0.f;
            if (gcol < 310) v = eeg[(bw + r) * 310 + gcol];
            sw[r * 41 + cc] = v;
        }
        __syncthreads();
        const int nch = (62 - ch0 < 8) ? (62 - ch0) : 8;
        for (int el = 0; el < nch; ++el) {
            const int e = ch0 + el;
            const float* xr = sw + lane * 41 + el * 5;
            float p = (xr[0] + xr[1] + xr[2] + xr[3] + xr[4]) * 0.2f;
            const float* wr = ws + WS_WVT + e * 62;
            #pragma unroll
            for (int d = 0; d < 62; ++d) vbar[d] = fmaf(p, wr[d], vbar[d]);
        }
        __syncthreads();
    }

    float h[32];
    #pragma unroll
    for (int o = 0; o < 32; ++o) h[o] = eeg_cb[o];

    for (int chunk = 0; chunk < 8; ++chunk) {
        const int ch0 = chunk * 8;
        for (int j = 0; j < 40; ++j) {
            int idx = j * 64 + lane;
            int r = idx / 40, cc = idx - r * 40;
            int gcol = ch0 * 5 + cc;
            float v = 0.f;
            if (gcol < 310) v = eeg[(bw + r) * 310 + gcol];
            sw[r * 41 + cc] = v;
        }
        __syncthreads();
        const int nch = (62 - ch0 < 8) ? (62 - ch0) : 8;
        for (int el = 0; el < nch; ++el) {
            const int c = ch0 + el;
            const float* owr = eeg_ow + c * 62;
            float oc = eeg_ob[c];
            #pragma unroll
            for (int d = 0; d < 62; ++d) oc = fmaf(owr[d], vbar[d], oc);
            const float* xr = sw + lane * 41 + el * 5;
            float x0 = xr[0], x1 = xr[1], x2 = xr[2], x3 = xr[3], x4 = xr[4];
            const float* cwr = ws + WS_CWT + c * 160;
            #pragma unroll
            for (int o = 0; o < 32; ++o) {
                float tt = x0 * cwr[o * 5 + 0];
                tt = fmaf(x1, cwr[o * 5 + 1], tt);
                tt = fmaf(x2, cwr[o * 5 + 2], tt);
                tt = fmaf(x3, cwr[o * 5 + 3], tt);
                tt = fmaf(x4, cwr[o * 5 + 4], tt);
                h[o] = fmaf(oc, tt, h[o]);
            }
        }
        __syncthreads();
    }

    #pragma unroll
    for (int o = 0; o < 32; ++o) h[o] = h[o] > 0.f ? h[o] : expm1f(h[o]);

    float feat[64];
    #pragma unroll
    for (int f = 0; f < 64; ++f) {
        float acc = ws[WS_B0 + f];
        #pragma unroll
        for (int o = 0; o < 32; ++o)
            acc = fmaf(ws[WS_A_EEG + f * 32 + o], h[o], acc);
        feat[f] = acc;
    }

    for (int j = 0; j < 33; ++j) {
        int idx = j * 64 + lane;
        int r = idx / 33, cc = idx - r * 33;
        sw[r * 34 + cc] = eog[(bw + r) * 33 + cc];
    }
    __syncthreads();
    {
        float Tg[32];
        #pragma unroll
        for (int o = 0; o < 32; ++o) Tg[o] = 0.f;
        float pool = 0.f;
        for (int l2 = 0; l2 < 33; ++l2) {
            float x = sw[lane * 34 + l2];
            pool += x;
            const float* cr = ws + WS_CWOG + l2 * 32;
            #pragma unroll
            for (int o = 0; o < 32; ++o) Tg[o] = fmaf(x, cr[o], Tg[o]);
        }
        pool *= (1.f / 33.f);
        float vb2 = fmaf(pool, eog_inw[2], eog_inb[2]);
        float ob2 = fmaf(vb2, eog_ow[0], eog_ob[0]);
        #pragma unroll
        for (int o = 0; o < 32; ++o) {
            float hh = fmaf(ob2, Tg[o], eog_cb[o]);
            Tg[o] = hh > 0.f ? hh : expm1f(hh);
        }
        #pragma unroll
        for (int f = 0; f < 64; ++f) {
            float acc = feat[f];
            #pragma unroll
            for (int o = 0; o < 32; ++o)
                acc = fmaf(ws[WS_A_EOG + f * 32 + o], Tg[o], acc);
            feat[f] = acc;
        }
    }

    for (int i2 = 0; i2 < 2; ++i2) {
        const float* Wa  = ws + WS_WATT + i2 * 4096;
        const float* ba  = ws + WS_BATT + i2 * 64;
        const float* s1  = tl_ln1_s + i2 * 64;
        const float* g1  = tl_ln1_b + i2 * 64;
        const float* s2  = tl_ln2_s + i2 * 64;
        const float* g2  = tl_ln2_b + i2 * 64;
        const float* w1p = tl_w1 + i2 * 16384;
        const float* bf1 = tl_b1 + i2 * 256;
        const float* w2t = ws + WS_W2T + i2 * 16384;
        const float* bf2 = tl_b2 + i2 * 64;

        float hb[64];
        {
            float m = 0.f;
            #pragma unroll
            for (int d = 0; d < 64; ++d) m += feat[d];
            m *= 0.015625f;
            float vv = 0.f;
            #pragma unroll
            for (int d = 0; d < 64; ++d) { float u = feat[d] - m; vv = fmaf(u, u, vv); }
            vv *= 0.015625f;
            float inv = rsqrtf(vv + 1e-5f);
            #pragma unroll
            for (int d = 0; d < 64; ++d)
                hb[d] = fmaf((feat[d] - m) * inv, s1[d], g1[d]);
        }
        #pragma unroll
        for (int c = 0; c < 64; ++c) {
            float a = ba[c];
            #pragma unroll
            for (int d = 0; d < 64; ++d) a = fmaf(Wa[c * 64 + d], hb[d], a);
            feat[c] += a;
        }
        {
            float m = 0.f;
            #pragma unroll
            for (int d = 0; d < 64; ++d) m += feat[d];
            m *= 0.015625f;
            float vv = 0.f;
            #pragma unroll
            for (int d = 0; d < 64; ++d) { float u = feat[d] - m; vv = fmaf(u, u, vv); }
            vv *= 0.015625f;
            float inv = rsqrtf(vv + 1e-5f);
            #pragma unroll
            for (int d = 0; d < 64; ++d)
                hb[d] = fmaf((feat[d] - m) * inv, s2[d], g2[d]);
        }
        #pragma unroll
        for (int c = 0; c < 64; ++c) feat[c] += bf2[c];
        for (int j = 0; j < 256; ++j) {
            const float* wr = w1p + j * 64;
            float g = bf1[j];
            #pragma unroll
            for (int d = 0; d < 64; ++d) g = fmaf(wr[d], hb[d], g);
            g = 0.5f * g * (1.f + erff(g * 0.70710678118654752f));
            const float* w2r = w2t + j * 64;
            #pragma unroll
            for (int c = 0; c < 64; ++c) feat[c] = fmaf(g, w2r[c], feat[c]);
        }
    }

    {
        float m = 0.f;
        #pragma unroll
        for (int d = 0; d < 64; ++d) m += feat[d];
        m *= 0.015625f;
        float vv = 0.f;
        #pragma unroll
        for (int d = 0; d < 64; ++d) { float u = feat[d] - m; vv = fmaf(u, u, vv); }
        vv *= 0.015625f;
        float inv = rsqrtf(vv + 1e-5f);
        float o0 = cls_b[0], o1 = cls_b[1], o2 = cls_b[2];
        #pragma unroll
        for (int d = 0; d < 64; ++d) {
            float n = fmaf((feat[d] - m) * inv, fn_s[d], fn_b[d]);
            o0 = fmaf(n, cls_w[d], o0);
            o1 = fmaf(n, cls_w[64 + d], o1);
            o2 = fmaf(n, cls_w[128 + d], o2);
        }
        float* op = out + b * 3;
        op[0] = o0; op[1] = o1; op[2] = o2;
    }
}

extern "C" void kernel_launch(void* const* d_in, const int* in_sizes, int n_in,
                              void* d_out, int out_size, void* d_ws, size_t ws_size,
                              hipStream_t stream) {
    const float* eeg      = (const float*)d_in[0];
    const float* eog      = (const float*)d_in[1];
    const float* eeg_inw  = (const float*)d_in[2];
    const float* eeg_inb  = (const float*)d_in[3];
    const float* eeg_ow   = (const float*)d_in[4];
    const float* eeg_ob   = (const float*)d_in[5];
    const float* eog_inw  = (const float*)d_in[6];
    const float* eog_inb  = (const float*)d_in[7];
    const float* eog_ow   = (const float*)d_in[8];
    const float* eog_ob   = (const float*)d_in[9];
    const float* eeg_cw   = (const float*)d_in[10];
    const float* eeg_cb   = (const float*)d_in[11];
    const float* eeg_fw   = (const float*)d_in[12];
    const float* eeg_fb   = (const float*)d_in[13];
    const float* eog_cw   = (const float*)d_in[14];
    const float* eog_cb   = (const float*)d_in[15];
    const float* eog_fw   = (const float*)d_in[16];
    const float* eog_fb   = (const float*)d_in[17];
    const float* fus_w    = (const float*)d_in[18];
    const float* fus_b    = (const float*)d_in[19];
    const float* tl_ln1_s = (const float*)d_in[20];
    const float* tl_ln1_b = (const float*)d_in[21];
    const float* tl_inw   = (const float*)d_in[22];
    const float* tl_inb   = (const float*)d_in[23];
    const float* tl_ow    = (const float*)d_in[24];
    const float* tl_ob    = (const float*)d_in[25];
    const float* tl_ln2_s = (const float*)d_in[26];
    const float* tl_ln2_b = (const float*)d_in[27];
    const float* tl_w1    = (const float*)d_in[28];
    const float* tl_b1    = (const float*)d_in[29];
    const float* tl_w2    = (const float*)d_in[30];
    const float* tl_b2    = (const float*)d_in[31];
    const float* fn_s     = (const float*)d_in[32];
    const float* fn_b     = (const float*)d_in[33];
    const float* cls_w    = (const float*)d_in[34];
    const float* cls_b    = (const float*)d_in[35];
    float* ws  = (float*)d_ws;
    float* out = (float*)d_out;

    hipLaunchKernelGGL(mcaf_pre, dim3(8), dim3(256), 0, stream,
                       eeg_inw, eeg_inb, eeg_ow, eeg_ob, eeg_cw,
                       eeg_fw, eeg_fb, eog_cw, eog_fw, eog_fb,
                       fus_w, fus_b, tl_inw, tl_inb, tl_ow, tl_ob, tl_w1, tl_w2, ws);

    const size_t need = (size_t)WS_TOTALF * 4u;
    if (ws_size >= need) {
        hipLaunchKernelGGL(eeg_tr, dim3(NB / 256), dim3(256), 0, stream, eeg, ws);
        hipLaunchKernelGGL(mcaf_front, dim3(NB / 256), dim3(256), 0, stream,
                           eog, eeg_cb, eog_inw, eog_inb, eog_ow, eog_ob, eog_cb, ws);
        hipLaunchKernelGGL(mcaf_trans, dim3(NB / 256), dim3(256), 0, stream,
                           tl_ln1_s, tl_ln1_b, tl_ln2_s, tl_ln2_b,
                           tl_b1, tl_b2, fn_s, fn_b, cls_w, cls_b, ws, out);
    } else {
        hipLaunchKernelGGL(mcaf_main_fb, dim3(NB / 256), dim3(256), 0, stream,
                           eeg, eog, eeg_inb, eeg_ow, eeg_ob,
                           eog_inw, eog_inb, eog_ow, eog_ob,
                           eeg_cb, eog_cb,
                           tl_ln1_s, tl_ln1_b, tl_ln2_s, tl_ln2_b,
                           tl_w1, tl_b1, tl_b2,
                           fn_s, fn_b, cls_w, cls_b, ws, out);
    }
}

// Round 8
// 394.947 us; speedup vs baseline: 2.1986x; 2.1688x over previous
//
#include <hip/hip_runtime.h>
#include <hip/hip_bf16.h>
#include <math.h>

#define NB 131072

typedef __attribute__((ext_vector_type(4))) float f32x4;
typedef __attribute__((ext_vector_type(8))) short bf16x8;

// Wave-local ordering fence for wave-private LDS (DS ops pinned, rest free).
#define SYNC() do { asm volatile("" ::: "memory"); __builtin_amdgcn_sched_barrier(0x7F); } while (0)

// ---- workspace layout (float offsets) ----
#define WS_A_EEG 0          // [64][32] f32 (fallback)
#define WS_A_EOG 2048
#define WS_B0    4096       // [64]
#define WS_WATT  4160       // [2][64][64] f32 (fallback)
#define WS_BATT  12352      // [2][64]
#define WS_WVT   12480      // [62][62] (fallback)
#define WS_M     16324      // [62][62] (fallback/aux)
#define WS_OBB   20168      // [62]
#define WS_CWT   20232      // [62][32][5] (fallback)
#define WS_CWOG  30152      // [33][32]
#define WS_W2T   31208      // [2][256][64] f32 (fallback)
#define WB_WA_F  64000      // bf16 [2][64][64]
#define WB_W1_F  68096      // bf16 [2][256][64]
#define WB_W2_F  84480      // bf16 [2][64][256]
#define WB_MB    100864     // bf16 [64][64]  Maug[c][e] (e=62 -> obb, pad 0)
#define WB_CWL   102912     // bf16 [32][320] CWL[o][l*64+c]
#define WB_ACAT  108032     // bf16 [64][64]  [A_EEG | A_EOG][f][j]
#define WS_EEGXL 110080                      // f32 [310][B]  plane (l*62+c)
#define WS_FEATI WS_EEGXL                    // f32 [16][B][4] overlays planes 0..63:
                                             // thread b reads all its eegXL column
                                             // before writing featI column b.
#define WB_POOLB (WS_EEGXL + 310 * NB)       // bf16 [8][B][8] pooled (e62=1.0,e63=0)
#define WS_EOGT  (WB_POOLB + 32 * NB)        // f32 [33][B]
#define WS_TOTALF (WS_EOGT + 33 * NB)

// per-wave LDS: 64 rows x 208B (13 x 16B granules; odd stride)
#define ROWB 208
#define WAVE_LDS (64 * ROWB)

__device__ __forceinline__ short f2bf(float x) {
    union { __hip_bfloat16 h; short s; } u;
    u.h = __float2bfloat16(x);
    return u.s;
}

__global__ __launch_bounds__(256) void mcaf_pre(
    const float* __restrict__ eeg_inw, const float* __restrict__ eeg_inb,
    const float* __restrict__ eeg_ow,  const float* __restrict__ eeg_ob,
    const float* __restrict__ eeg_cw,
    const float* __restrict__ eeg_fw,  const float* __restrict__ eeg_fb,
    const float* __restrict__ eog_cw,  const float* __restrict__ eog_fw,
    const float* __restrict__ eog_fb,
    const float* __restrict__ fus_w,   const float* __restrict__ fus_b,
    const float* __restrict__ tl_inw,  const float* __restrict__ tl_inb,
    const float* __restrict__ tl_ow,   const float* __restrict__ tl_ob,
    const float* __restrict__ tl_w1,   const float* __restrict__ tl_w2,
    float* __restrict__ ws)
{
    const int tid  = blockIdx.x * blockDim.x + threadIdx.x;
    const int nthr = gridDim.x * blockDim.x;
    short* wa_b   = (short*)(ws + WB_WA_F);
    short* w1_b   = (short*)(ws + WB_W1_F);
    short* w2_b   = (short*)(ws + WB_W2_F);
    short* mb_b   = (short*)(ws + WB_MB);
    short* cwl_b  = (short*)(ws + WB_CWL);
    short* acat_b = (short*)(ws + WB_ACAT);

    // A_EEG / A_EOG f32 (fallback) ; ACAT bf16 built separately below
    for (int idx = tid; idx < 2048; idx += nthr) {
        int f = idx >> 5, o = idx & 31;
        float a = 0.f, a2 = 0.f;
        for (int k = 0; k < 64; ++k) {
            a  = fmaf(fus_w[f * 128 + k],      eeg_fw[k * 32 + o], a);
            a2 = fmaf(fus_w[f * 128 + 64 + k], eog_fw[k * 32 + o], a2);
        }
        ws[WS_A_EEG + idx] = a;
        ws[WS_A_EOG + idx] = a2;
    }
    // ACAT bf16 [f][j]: j<32 -> A_EEG, j>=32 -> A_EOG  (recompute, no intra-kernel dep)
    for (int idx = tid; idx < 4096; idx += nthr) {
        int f = idx >> 6, j = idx & 63;
        float a = 0.f;
        if (j < 32) {
            for (int k = 0; k < 64; ++k)
                a = fmaf(fus_w[f * 128 + k], eeg_fw[k * 32 + j], a);
        } else {
            int o = j - 32;
            for (int k = 0; k < 64; ++k)
                a = fmaf(fus_w[f * 128 + 64 + k], eog_fw[k * 32 + o], a);
        }
        acat_b[idx] = f2bf(a);
    }
    for (int f = tid; f < 64; f += nthr) {
        float a = fus_b[f] + (float)(f & 1);
        for (int k = 0; k < 64; ++k) {
            a = fmaf(fus_w[f * 128 + k],      eeg_fb[k], a);
            a = fmaf(fus_w[f * 128 + 64 + k], eog_fb[k], a);
        }
        ws[WS_B0 + f] = a;
    }
    for (int idx = tid; idx < 8192; idx += nthr) {
        int i = idx >> 12, c = (idx >> 6) & 63, d = idx & 63;
        float a = 0.f;
        for (int e = 0; e < 64; ++e)
            a = fmaf(tl_ow[i * 4096 + c * 64 + e],
                     tl_inw[i * 12288 + (128 + e) * 64 + d], a);
        ws[WS_WATT + idx] = a;
        wa_b[idx] = f2bf(a);
    }
    for (int idx = tid; idx < 128; idx += nthr) {
        int i = idx >> 6, c = idx & 63;
        float a = tl_ob[i * 64 + c];
        for (int e = 0; e < 64; ++e)
            a = fmaf(tl_ow[i * 4096 + c * 64 + e], tl_inb[i * 192 + 128 + e], a);
        ws[WS_BATT + idx] = a;
    }
    for (int idx = tid; idx < 32768; idx += nthr) w1_b[idx] = f2bf(tl_w1[idx]);
    for (int idx = tid; idx < 32768; idx += nthr) w2_b[idx] = f2bf(tl_w2[idx]);

    for (int idx = tid; idx < 3844; idx += nthr) {
        int e = idx / 62, d = idx - e * 62;
        ws[WS_WVT + idx] = eeg_inw[(124 + d) * 62 + e];
    }
    for (int idx = tid; idx < 3844; idx += nthr) {
        int c = idx / 62, e = idx - c * 62;
        float a = 0.f;
        for (int d = 0; d < 62; ++d)
            a = fmaf(eeg_ow[c * 62 + d], eeg_inw[(124 + d) * 62 + e], a);
        ws[WS_M + idx] = a;
    }
    for (int c = tid; c < 62; c += nthr) {
        float a = eeg_ob[c];
        for (int d = 0; d < 62; ++d)
            a = fmaf(eeg_ow[c * 62 + d], eeg_inb[124 + d], a);
        ws[WS_OBB + c] = a;
    }
    // Maug bf16 [c][e]: e<62 -> M, e==62 -> obb, pad 0 (recompute directly)
    for (int idx = tid; idx < 4096; idx += nthr) {
        int c = idx >> 6, e = idx & 63;
        float a = 0.f;
        if (c < 62) {
            if (e < 62) {
                for (int d = 0; d < 62; ++d)
                    a = fmaf(eeg_ow[c * 62 + d], eeg_inw[(124 + d) * 62 + e], a);
            } else if (e == 62) {
                a = eeg_ob[c];
                for (int d = 0; d < 62; ++d)
                    a = fmaf(eeg_ow[c * 62 + d], eeg_inb[124 + d], a);
            }
        }
        mb_b[idx] = f2bf(a);
    }
    // CWL bf16 [o][l*64+c]
    for (int idx = tid; idx < 10240; idx += nthr) {
        int o = idx / 320, k = idx - o * 320;
        int l = k >> 6, c = k & 63;
        float a = (c < 62 && l < 5) ? eeg_cw[o * 310 + c * 5 + l] : 0.f;
        cwl_b[idx] = f2bf(a);
    }
    for (int idx = tid; idx < 9920; idx += nthr) {
        int c = idx / 160, r = idx - c * 160;
        int o = r / 5, l = r - o * 5;
        ws[WS_CWT + idx] = eeg_cw[o * 310 + c * 5 + l];
    }
    for (int idx = tid; idx < 1056; idx += nthr) {
        int l = idx >> 5, o = idx & 31;
        ws[WS_CWOG + idx] = eog_cw[o * 33 + l];
    }
    for (int idx = tid; idx < 32768; idx += nthr) {
        int i = idx >> 14, r = idx & 16383;
        int j = r >> 6, c = r & 63;
        ws[WS_W2T + idx] = tl_w2[i * 16384 + c * 256 + j];
    }
}

// ---- eeg re-layout (l-major planes) + pooled bf16 (chunk-parallel) ----
__global__ __launch_bounds__(256) void eeg_tr(const float* __restrict__ eeg,
                                              float* __restrict__ ws)
{
    __shared__ float smem[4 * 64 * 41];
    const int lane  = threadIdx.x & 63;
    const int wid   = threadIdx.x >> 6;
    const int chunk = blockIdx.x & 7;
    const int bw    = (blockIdx.x >> 3) * 256 + wid * 64;
    const int b     = bw + lane;
    float* sw = smem + wid * (64 * 41);

    const int ch0 = chunk * 40;
    for (int j = 0; j < 40; ++j) {
        int idx = j * 64 + lane;
        int r = idx / 40, cc = idx - r * 40;
        int gcol = ch0 + cc;
        float v = 0.f;
        if (gcol < 310) v = eeg[(size_t)(bw + r) * 310 + gcol];
        sw[r * 41 + cc] = v;
    }
    SYNC();
    float p[8];
    #pragma unroll
    for (int el = 0; el < 8; ++el) {
        int c = chunk * 8 + el;
        if (c < 62) {
            const float* xr = sw + lane * 41 + el * 5;
            float x0 = xr[0], x1 = xr[1], x2 = xr[2], x3 = xr[3], x4 = xr[4];
            p[el] = (x0 + x1 + x2 + x3 + x4) * 0.2f;
            ws[WS_EEGXL + (size_t)(0 * 62 + c) * NB + b] = x0;
            ws[WS_EEGXL + (size_t)(1 * 62 + c) * NB + b] = x1;
            ws[WS_EEGXL + (size_t)(2 * 62 + c) * NB + b] = x2;
            ws[WS_EEGXL + (size_t)(3 * 62 + c) * NB + b] = x3;
            ws[WS_EEGXL + (size_t)(4 * 62 + c) * NB + b] = x4;
        } else {
            p[el] = (c == 62) ? 1.0f : 0.f;   // augmented-pooled: e62 = 1 (obb col), e63 = 0
        }
    }
    bf16x8 pv;
    #pragma unroll
    for (int el = 0; el < 8; ++el) pv[el] = f2bf(p[el]);
    *(bf16x8*)((short*)(ws + WB_POOLB) + ((size_t)chunk * NB + b) * 8) = pv;
}

// ---- eog transpose ----
__global__ __launch_bounds__(256) void eog_tr(const float* __restrict__ eog,
                                              float* __restrict__ ws)
{
    __shared__ float smem[4 * 64 * 34];
    const int lane = threadIdx.x & 63;
    const int wid  = threadIdx.x >> 6;
    const int bw   = blockIdx.x * 256 + wid * 64;
    float* sw = smem + wid * (64 * 34);

    for (int j = 0; j < 33; ++j) {
        int idx = j * 64 + lane;
        int r = idx / 33, cc = idx - r * 33;
        sw[r * 34 + cc] = eog[(size_t)(bw + r) * 33 + cc];
    }
    SYNC();
    #pragma unroll
    for (int cc = 0; cc < 33; ++cc)
        ws[WS_EOGT + (size_t)cc * NB + bw + lane] = sw[lane * 34 + cc];
}

// ================= MFMA front-end: EEG + EOG -> featI ======================
__global__ __launch_bounds__(256, 2) void mcaf_front(
    const float* __restrict__ eeg_cb,
    const float* __restrict__ eog_inw, const float* __restrict__ eog_inb,
    const float* __restrict__ eog_ow,  const float* __restrict__ eog_ob,
    const float* __restrict__ eog_cb,
    float* __restrict__ ws)
{
    __shared__ char smem[4 * WAVE_LDS];
    const int tid  = threadIdx.x;
    const int lane = tid & 63;
    const int wid  = tid >> 6;
    const int b    = blockIdx.x * 256 + tid;
    char* Wv = smem + wid * WAVE_LDS;
    const int g4  = lane >> 4;
    const int r15 = lane & 15;

    const short* MB   = (const short*)(ws + WB_MB);
    const short* CWL  = (const short*)(ws + WB_CWL);
    const short* ACAT = (const short*)(ws + WB_ACAT);
    const short* PB   = (const short*)(ws + WB_POOLB);

    // ---- phase 1: oc[64] = [pooled,1] @ Maug^T  (32 MFMA) ----
    #pragma unroll
    for (int q = 0; q < 8; ++q) {
        bf16x8 v = *(const bf16x8*)(PB + ((size_t)q * NB + b) * 8);
        *(bf16x8*)(Wv + lane * ROWB + q * 16) = v;
    }
    SYNC();
    bf16x8 Ap[4][2];
    #pragma unroll
    for (int rt = 0; rt < 4; ++rt)
        #pragma unroll
        for (int kt = 0; kt < 2; ++kt)
            Ap[rt][kt] = *(const bf16x8*)(Wv + (rt * 16 + r15) * ROWB + (kt * 4 + g4) * 16);
    SYNC();
    f32x4 accO[4][4];
    #pragma unroll
    for (int rt = 0; rt < 4; ++rt)
        #pragma unroll
        for (int ct = 0; ct < 4; ++ct) accO[rt][ct] = (f32x4){0.f, 0.f, 0.f, 0.f};
    #pragma unroll
    for (int kt = 0; kt < 2; ++kt) {
        bf16x8 bb[4];
        #pragma unroll
        for (int ct = 0; ct < 4; ++ct)
            bb[ct] = *(const bf16x8*)(MB + (ct * 16 + r15) * 64 + kt * 32 + g4 * 8);
        #pragma unroll
        for (int rt = 0; rt < 4; ++rt)
            #pragma unroll
            for (int ct = 0; ct < 4; ++ct)
                accO[rt][ct] = __builtin_amdgcn_mfma_f32_16x16x32_bf16(Ap[rt][kt], bb[ct], accO[rt][ct], 0, 0, 0);
    }
    float oc[64];
    #pragma unroll
    for (int hf = 0; hf < 2; ++hf) {
        SYNC();
        #pragma unroll
        for (int ct2 = 0; ct2 < 2; ++ct2) {
            int ct = hf * 2 + ct2;
            #pragma unroll
            for (int rt = 0; rt < 4; ++rt)
                #pragma unroll
                for (int rg = 0; rg < 4; ++rg) {
                    int row = rt * 16 + g4 * 4 + rg;
                    *(float*)(Wv + row * ROWB + (ct2 * 16 + r15) * 4) = accO[rt][ct][rg];
                }
        }
        SYNC();
        #pragma unroll
        for (int j8 = 0; j8 < 8; ++j8) {
            f32x4 v = *(const f32x4*)(Wv + lane * ROWB + j8 * 16);
            #pragma unroll
            for (int e = 0; e < 4; ++e) oc[hf * 32 + j8 * 4 + e] = v[e];
        }
    }

    // ---- phase 2: h[32] = Y @ CWL^T, Y[l*64+c] = oc[c]*x[c][l]  (80 MFMA) ----
    f32x4 accH[4][2];
    #pragma unroll
    for (int rt = 0; rt < 4; ++rt) {
        accH[rt][0] = (f32x4){0.f, 0.f, 0.f, 0.f};
        accH[rt][1] = (f32x4){0.f, 0.f, 0.f, 0.f};
    }
    for (int l = 0; l < 5; ++l) {
        float y[64];
        #pragma unroll
        for (int c = 0; c < 62; ++c)
            y[c] = oc[c] * ws[WS_EEGXL + (size_t)(l * 62 + c) * NB + b];
        y[62] = 0.f; y[63] = 0.f;
        SYNC();
        #pragma unroll
        for (int jj = 0; jj < 8; ++jj) {
            bf16x8 v;
            #pragma unroll
            for (int e = 0; e < 8; ++e) v[e] = f2bf(y[jj * 8 + e]);
            *(bf16x8*)(Wv + lane * ROWB + jj * 16) = v;
        }
        SYNC();
        bf16x8 a[4][2];
        #pragma unroll
        for (int rt = 0; rt < 4; ++rt)
            #pragma unroll
            for (int kt = 0; kt < 2; ++kt)
                a[rt][kt] = *(const bf16x8*)(Wv + (rt * 16 + r15) * ROWB + (kt * 4 + g4) * 16);
        SYNC();
        #pragma unroll
        for (int kt = 0; kt < 2; ++kt) {
            bf16x8 bb[2];
            #pragma unroll
            for (int ct = 0; ct < 2; ++ct)
                bb[ct] = *(const bf16x8*)(CWL + (ct * 16 + r15) * 320 + l * 64 + kt * 32 + g4 * 8);
            #pragma unroll
            for (int rt = 0; rt < 4; ++rt)
                #pragma unroll
                for (int ct = 0; ct < 2; ++ct)
                    accH[rt][ct] = __builtin_amdgcn_mfma_f32_16x16x32_bf16(a[rt][kt], bb[ct], accH[rt][ct], 0, 0, 0);
        }
    }
    float h[32];
    SYNC();
    #pragma unroll
    for (int ct2 = 0; ct2 < 2; ++ct2)
        #pragma unroll
        for (int rt = 0; rt < 4; ++rt)
            #pragma unroll
            for (int rg = 0; rg < 4; ++rg) {
                int row = rt * 16 + g4 * 4 + rg;
                *(float*)(Wv + row * ROWB + (ct2 * 16 + r15) * 4) = accH[rt][ct2][rg];
            }
    SYNC();
    #pragma unroll
    for (int j8 = 0; j8 < 8; ++j8) {
        f32x4 v = *(const f32x4*)(Wv + lane * ROWB + j8 * 16);
        #pragma unroll
        for (int e = 0; e < 4; ++e) h[j8 * 4 + e] = v[e] + eeg_cb[j8 * 4 + e];
    }
    #pragma unroll
    for (int o = 0; o < 32; ++o) h[o] = h[o] > 0.f ? h[o] : expm1f(h[o]);

    // ---- phase 3: EOG per-lane (coalesced eogT) ----
    float Tg[32];
    {
        #pragma unroll
        for (int o = 0; o < 32; ++o) Tg[o] = 0.f;
        float pool = 0.f;
        for (int l2 = 0; l2 < 33; ++l2) {
            float x = ws[WS_EOGT + (size_t)l2 * NB + b];
            pool += x;
            const float* cr = ws + WS_CWOG + l2 * 32;
            #pragma unroll
            for (int o = 0; o < 32; ++o) Tg[o] = fmaf(x, cr[o], Tg[o]);
        }
        pool *= (1.f / 33.f);
        float vb2 = fmaf(pool, eog_inw[2], eog_inb[2]);
        float ob2 = fmaf(vb2, eog_ow[0], eog_ob[0]);
        #pragma unroll
        for (int o = 0; o < 32; ++o) {
            float hh = fmaf(ob2, Tg[o], eog_cb[o]);
            Tg[o] = hh > 0.f ? hh : expm1f(hh);
        }
    }

    // ---- phase 4: feat = [h|Tg] @ ACAT^T + B0  (32 MFMA) ----
    SYNC();
    #pragma unroll
    for (int jj = 0; jj < 8; ++jj) {
        bf16x8 v;
        #pragma unroll
        for (int e = 0; e < 8; ++e) {
            int j = jj * 8 + e;
            v[e] = f2bf(j < 32 ? h[j] : Tg[j - 32]);
        }
        *(bf16x8*)(Wv + lane * ROWB + jj * 16) = v;
    }
    SYNC();
    bf16x8 Ac[4][2];
    #pragma unroll
    for (int rt = 0; rt < 4; ++rt)
        #pragma unroll
        for (int kt = 0; kt < 2; ++kt)
            Ac[rt][kt] = *(const bf16x8*)(Wv + (rt * 16 + r15) * ROWB + (kt * 4 + g4) * 16);
    SYNC();
    f32x4 accF[4][4];
    #pragma unroll
    for (int rt = 0; rt < 4; ++rt)
        #pragma unroll
        for (int ct = 0; ct < 4; ++ct) accF[rt][ct] = (f32x4){0.f, 0.f, 0.f, 0.f};
    #pragma unroll
    for (int kt = 0; kt < 2; ++kt) {
        bf16x8 bb[4];
        #pragma unroll
        for (int ct = 0; ct < 4; ++ct)
            bb[ct] = *(const bf16x8*)(ACAT + (ct * 16 + r15) * 64 + kt * 32 + g4 * 8);
        #pragma unroll
        for (int rt = 0; rt < 4; ++rt)
            #pragma unroll
            for (int ct = 0; ct < 4; ++ct)
                accF[rt][ct] = __builtin_amdgcn_mfma_f32_16x16x32_bf16(Ac[rt][kt], bb[ct], accF[rt][ct], 0, 0, 0);
    }
    #pragma unroll
    for (int hf = 0; hf < 2; ++hf) {
        SYNC();
        #pragma unroll
        for (int ct2 = 0; ct2 < 2; ++ct2) {
            int ct = hf * 2 + ct2;
            #pragma unroll
            for (int rt = 0; rt < 4; ++rt)
                #pragma unroll
                for (int rg = 0; rg < 4; ++rg) {
                    int row = rt * 16 + g4 * 4 + rg;
                    *(float*)(Wv + row * ROWB + (ct2 * 16 + r15) * 4) = accF[rt][ct][rg];
                }
        }
        SYNC();
        #pragma unroll
        for (int j8 = 0; j8 < 8; ++j8) {
            f32x4 v = *(const f32x4*)(Wv + lane * ROWB + j8 * 16);
            f32x4 o;
            #pragma unroll
            for (int e = 0; e < 4; ++e) {
                int d = hf * 32 + j8 * 4 + e;
                o[e] = v[e] + ws[WS_B0 + d];
            }
            int q = hf * 8 + j8;
            *(f32x4*)(ws + WS_FEATI + (size_t)(q * NB + b) * 4) = o;
        }
    }
}

// ================= transformer + head (wave-coop MFMA, barrier-free) =======
__global__ __launch_bounds__(256, 2) void mcaf_trans(
    const float* __restrict__ tl_ln1_s, const float* __restrict__ tl_ln1_b,
    const float* __restrict__ tl_ln2_s, const float* __restrict__ tl_ln2_b,
    const float* __restrict__ tl_b1,   const float* __restrict__ tl_b2,
    const float* __restrict__ fn_s,    const float* __restrict__ fn_b,
    const float* __restrict__ cls_w,   const float* __restrict__ cls_b,
    const float* __restrict__ ws,      float* __restrict__ out)
{
    __shared__ char smem[4 * WAVE_LDS];
    const int tid  = threadIdx.x;
    const int lane = tid & 63;
    const int wid  = tid >> 6;
    const int b    = blockIdx.x * 256 + tid;
    char* Wv = smem + wid * WAVE_LDS;
    const int g4  = lane >> 4;
    const int r15 = lane & 15;

    float feat[64];
    #pragma unroll
    for (int q = 0; q < 16; ++q) {
        f32x4 v = *(const f32x4*)(ws + WS_FEATI + (size_t)(q * NB + b) * 4);
        feat[q * 4] = v[0]; feat[q * 4 + 1] = v[1];
        feat[q * 4 + 2] = v[2]; feat[q * 4 + 3] = v[3];
    }

    const short* WAb = (const short*)(ws + WB_WA_F);
    const short* W1b = (const short*)(ws + WB_W1_F);
    const short* W2b = (const short*)(ws + WB_W2_F);

    for (int i2 = 0; i2 < 2; ++i2) {
        const float* ba  = ws + WS_BATT + i2 * 64;
        const float* s1  = tl_ln1_s + i2 * 64;
        const float* gb1 = tl_ln1_b + i2 * 64;
        const float* s2  = tl_ln2_s + i2 * 64;
        const float* gb2 = tl_ln2_b + i2 * 64;
        const float* bf1 = tl_b1 + i2 * 256;
        const float* bf2 = tl_b2 + i2 * 64;

        float hb[64];
        {
            float m = 0.f;
            #pragma unroll
            for (int d = 0; d < 64; ++d) m += feat[d];
            m *= 0.015625f;
            float vv = 0.f;
            #pragma unroll
            for (int d = 0; d < 64; ++d) { float u = feat[d] - m; vv = fmaf(u, u, vv); }
            vv *= 0.015625f;
            float inv = rsqrtf(vv + 1e-5f);
            #pragma unroll
            for (int d = 0; d < 64; ++d)
                hb[d] = fmaf((feat[d] - m) * inv, s1[d], gb1[d]);
        }
        #pragma unroll
        for (int jj = 0; jj < 8; ++jj) {
            bf16x8 v;
            #pragma unroll
            for (int e = 0; e < 8; ++e) v[e] = f2bf(hb[jj * 8 + e]);
            *(bf16x8*)(Wv + lane * ROWB + jj * 16) = v;
        }
        SYNC();
        bf16x8 Aat[4][2];
        #pragma unroll
        for (int rt = 0; rt < 4; ++rt)
            #pragma unroll
            for (int kt = 0; kt < 2; ++kt)
                Aat[rt][kt] = *(const bf16x8*)(Wv + (rt * 16 + r15) * ROWB + (kt * 4 + g4) * 16);
        SYNC();
        f32x4 acc[4][4];
        #pragma unroll
        for (int rt = 0; rt < 4; ++rt)
            #pragma unroll
            for (int ct = 0; ct < 4; ++ct) acc[rt][ct] = (f32x4){0.f, 0.f, 0.f, 0.f};
        #pragma unroll
        for (int kt = 0; kt < 2; ++kt) {
            bf16x8 bb[4];
            #pragma unroll
            for (int ct = 0; ct < 4; ++ct)
                bb[ct] = *(const bf16x8*)(WAb + i2 * 4096 + (ct * 16 + r15) * 64 + kt * 32 + g4 * 8);
            #pragma unroll
            for (int rt = 0; rt < 4; ++rt)
                #pragma unroll
                for (int ct = 0; ct < 4; ++ct)
                    acc[rt][ct] = __builtin_amdgcn_mfma_f32_16x16x32_bf16(Aat[rt][kt], bb[ct], acc[rt][ct], 0, 0, 0);
        }
        #pragma unroll
        for (int hf = 0; hf < 2; ++hf) {
            SYNC();
            #pragma unroll
            for (int ct2 = 0; ct2 < 2; ++ct2) {
                int ct = hf * 2 + ct2;
                #pragma unroll
                for (int rt = 0; rt < 4; ++rt)
                    #pragma unroll
                    for (int rg = 0; rg < 4; ++rg) {
                        int row = rt * 16 + g4 * 4 + rg;
                        *(float*)(Wv + row * ROWB + (ct2 * 16 + r15) * 4) = acc[rt][ct][rg];
                    }
            }
            SYNC();
            #pragma unroll
            for (int j8 = 0; j8 < 8; ++j8) {
                f32x4 v = *(const f32x4*)(Wv + lane * ROWB + j8 * 16);
                #pragma unroll
                for (int e = 0; e < 4; ++e) {
                    int d = hf * 32 + j8 * 4 + e;
                    feat[d] += v[e] + ba[d];
                }
            }
        }
        {
            float m = 0.f;
            #pragma unroll
            for (int d = 0; d < 64; ++d) m += feat[d];
            m *= 0.015625f;
            float vv = 0.f;
            #pragma unroll
            for (int d = 0; d < 64; ++d) { float u = feat[d] - m; vv = fmaf(u, u, vv); }
            vv *= 0.015625f;
            float inv = rsqrtf(vv + 1e-5f);
            #pragma unroll
            for (int d = 0; d < 64; ++d)
                hb[d] = fmaf((feat[d] - m) * inv, s2[d], gb2[d]);
        }
        SYNC();
        #pragma unroll
        for (int jj = 0; jj < 8; ++jj) {
            bf16x8 v;
            #pragma unroll
            for (int e = 0; e < 8; ++e) v[e] = f2bf(hb[jj * 8 + e]);
            *(bf16x8*)(Wv + lane * ROWB + jj * 16) = v;
        }
        SYNC();
        f32x4 F[4][4];
        #pragma unroll
        for (int rt = 0; rt < 4; ++rt)
            #pragma unroll
            for (int ct = 0; ct < 4; ++ct) F[rt][ct] = (f32x4){0.f, 0.f, 0.f, 0.f};

        for (int ch = 0; ch < 8; ++ch) {
            f32x4 G[4][2];
            #pragma unroll
            for (int rt = 0; rt < 4; ++rt) {
                G[rt][0] = (f32x4){0.f, 0.f, 0.f, 0.f};
                G[rt][1] = (f32x4){0.f, 0.f, 0.f, 0.f};
            }
            #pragma unroll
            for (int kt = 0; kt < 2; ++kt) {
                bf16x8 a1[4];
                #pragma unroll
                for (int rt = 0; rt < 4; ++rt)
                    a1[rt] = *(const bf16x8*)(Wv + (rt * 16 + r15) * ROWB + (kt * 4 + g4) * 16);
                bf16x8 b1[2];
                #pragma unroll
                for (int cc = 0; cc < 2; ++cc)
                    b1[cc] = *(const bf16x8*)(W1b + i2 * 16384 + (ch * 32 + cc * 16 + r15) * 64 + kt * 32 + g4 * 8);
                #pragma unroll
                for (int rt = 0; rt < 4; ++rt)
                    #pragma unroll
                    for (int cc = 0; cc < 2; ++cc)
                        G[rt][cc] = __builtin_amdgcn_mfma_f32_16x16x32_bf16(a1[rt], b1[cc], G[rt][cc], 0, 0, 0);
            }
            SYNC();
            #pragma unroll
            for (int rt = 0; rt < 4; ++rt)
                #pragma unroll
                for (int cc = 0; cc < 2; ++cc) {
                    float bj = bf1[ch * 32 + cc * 16 + r15];
                    #pragma unroll
                    for (int rg = 0; rg < 4; ++rg) {
                        float v = G[rt][cc][rg] + bj;
                        v = 0.5f * v * (1.f + erff(v * 0.70710678118654752f));
                        int row = rt * 16 + g4 * 4 + rg;
                        int col = cc * 16 + r15;
                        *(short*)(Wv + row * ROWB + 128 + ((col >> 3) << 4) + ((col & 7) << 1)) = f2bf(v);
                    }
                }
            SYNC();
            bf16x8 a2[4], b2[4];
            #pragma unroll
            for (int rt = 0; rt < 4; ++rt)
                a2[rt] = *(const bf16x8*)(Wv + (rt * 16 + r15) * ROWB + 128 + g4 * 16);
            #pragma unroll
            for (int ct = 0; ct < 4; ++ct)
                b2[ct] = *(const bf16x8*)(W2b + i2 * 16384 + (ct * 16 + r15) * 256 + ch * 32 + g4 * 8);
            #pragma unroll
            for (int rt = 0; rt < 4; ++rt)
                #pragma unroll
                for (int ct = 0; ct < 4; ++ct)
                    F[rt][ct] = __builtin_amdgcn_mfma_f32_16x16x32_bf16(a2[rt], b2[ct], F[rt][ct], 0, 0, 0);
            SYNC();
        }
        #pragma unroll
        for (int hf = 0; hf < 2; ++hf) {
            SYNC();
            #pragma unroll
            for (int ct2 = 0; ct2 < 2; ++ct2) {
                int ct = hf * 2 + ct2;
                #pragma unroll
                for (int rt = 0; rt < 4; ++rt)
                    #pragma unroll
                    for (int rg = 0; rg < 4; ++rg) {
                        int row = rt * 16 + g4 * 4 + rg;
                        *(float*)(Wv + row * ROWB + (ct2 * 16 + r15) * 4) = F[rt][ct][rg];
                    }
            }
            SYNC();
            #pragma unroll
            for (int j8 = 0; j8 < 8; ++j8) {
                f32x4 v = *(const f32x4*)(Wv + lane * ROWB + j8 * 16);
                #pragma unroll
                for (int e = 0; e < 4; ++e) {
                    int d = hf * 32 + j8 * 4 + e;
                    feat[d] += v[e] + bf2[d];
                }
            }
        }
        SYNC();
    }

    {
        float m = 0.f;
        #pragma unroll
        for (int d = 0; d < 64; ++d) m += feat[d];
        m *= 0.015625f;
        float vv = 0.f;
        #pragma unroll
        for (int d = 0; d < 64; ++d) { float u = feat[d] - m; vv = fmaf(u, u, vv); }
        vv *= 0.015625f;
        float inv = rsqrtf(vv + 1e-5f);
        float o0 = cls_b[0], o1 = cls_b[1], o2 = cls_b[2];
        #pragma unroll
        for (int d = 0; d < 64; ++d) {
            float n = fmaf((feat[d] - m) * inv, fn_s[d], fn_b[d]);
            o0 = fmaf(n, cls_w[d], o0);
            o1 = fmaf(n, cls_w[64 + d], o1);
            o2 = fmaf(n, cls_w[128 + d], o2);
        }
        float* op = out + (size_t)b * 3;
        op[0] = o0; op[1] = o1; op[2] = o2;
    }
}

// ================= fallback main kernel (fp32, LDS staging) =================
__global__ __launch_bounds__(256, 2) void mcaf_main_fb(
    const float* __restrict__ eeg,     const float* __restrict__ eog,
    const float* __restrict__ eeg_inb,
    const float* __restrict__ eeg_ow,  const float* __restrict__ eeg_ob,
    const float* __restrict__ eog_inw, const float* __restrict__ eog_inb,
    const float* __restrict__ eog_ow,  const float* __restrict__ eog_ob,
    const float* __restrict__ eeg_cb,  const float* __restrict__ eog_cb,
    const float* __restrict__ tl_ln1_s, const float* __restrict__ tl_ln1_b,
    const float* __restrict__ tl_ln2_s, const float* __restrict__ tl_ln2_b,
    const float* __restrict__ tl_w1,   const float* __restrict__ tl_b1,
    const float* __restrict__ tl_b2,
    const float* __restrict__ fn_s,    const float* __restrict__ fn_b,
    const float* __restrict__ cls_w,   const float* __restrict__ cls_b,
    const float* __restrict__ ws,      float* __restrict__ out)
{
    __shared__ float smem[4 * 64 * 41];
    const int t    = threadIdx.x;
    const int lane = t & 63;
    const int wid  = t >> 6;
    const int bw   = blockIdx.x * 256 + wid * 64;
    const int b    = bw + lane;
    float* sw = smem + wid * (64 * 41);

    float vbar[62];
    #pragma unroll
    for (int d = 0; d < 62; ++d) vbar[d] = eeg_inb[124 + d];

    for (int chunk = 0; chunk < 8; ++chunk) {
        const int ch0 = chunk * 8;
        for (int j = 0; j < 40; ++j) {
            int idx = j * 64 + lane;
            int r = idx / 40, cc = idx - r * 40;
            int gcol = ch0 * 5 + cc;
            float v = 0.f;
            if (gcol < 310) v = eeg[(bw + r) * 310 + gcol];
            sw[r * 41 + cc] = v;
        }
        __syncthreads();
        const int nch = (62 - ch0 < 8) ? (62 - ch0) : 8;
        for (int el = 0; el < nch; ++el) {
            const int e = ch0 + el;
            const float* xr = sw + lane * 41 + el * 5;
            float p = (xr[0] + xr[1] + xr[2] + xr[3] + xr[4]) * 0.2f;
            const float* wr = ws + WS_WVT + e * 62;
            #pragma unroll
            for (int d = 0; d < 62; ++d) vbar[d] = fmaf(p, wr[d], vbar[d]);
        }
        __syncthreads();
    }

    float h[32];
    #pragma unroll
    for (int o = 0; o < 32; ++o) h[o] = eeg_cb[o];

    for (int chunk = 0; chunk < 8; ++chunk) {
        const int ch0 = chunk * 8;
        for (int j = 0; j < 40; ++j) {
            int idx = j * 64 + lane;
            int r = idx / 40, cc = idx - r * 40;
            int gcol = ch0 * 5 + cc;
            float v = 0.f;
            if (gcol < 310) v = eeg[(bw + r) * 310 + gcol];
            sw[r * 41 + cc] = v;
        }
        __syncthreads();
        const int nch = (62 - ch0 < 8) ? (62 - ch0) : 8;
        for (int el = 0; el < nch; ++el) {
            const int c = ch0 + el;
            const float* owr = eeg_ow + c * 62;
            float oc = eeg_ob[c];
            #pragma unroll
            for (int d = 0; d < 62; ++d) oc = fmaf(owr[d], vbar[d], oc);
            const float* xr = sw + lane * 41 + el * 5;
            float x0 = xr[0], x1 = xr[1], x2 = xr[2], x3 = xr[3], x4 = xr[4];
            const float* cwr = ws + WS_CWT + c * 160;
            #pragma unroll
            for (int o = 0; o < 32; ++o) {
                float tt = x0 * cwr[o * 5 + 0];
                tt = fmaf(x1, cwr[o * 5 + 1], tt);
                tt = fmaf(x2, cwr[o * 5 + 2], tt);
                tt = fmaf(x3, cwr[o * 5 + 3], tt);
                tt = fmaf(x4, cwr[o * 5 + 4], tt);
                h[o] = fmaf(oc, tt, h[o]);
            }
        }
        __syncthreads();
    }

    #pragma unroll
    for (int o = 0; o < 32; ++o) h[o] = h[o] > 0.f ? h[o] : expm1f(h[o]);

    float feat[64];
    #pragma unroll
    for (int f = 0; f < 64; ++f) {
        float acc = ws[WS_B0 + f];
        #pragma unroll
        for (int o = 0; o < 32; ++o)
            acc = fmaf(ws[WS_A_EEG + f * 32 + o], h[o], acc);
        feat[f] = acc;
    }

    for (int j = 0; j < 33; ++j) {
        int idx = j * 64 + lane;
        int r = idx / 33, cc = idx - r * 33;
        sw[r * 34 + cc] = eog[(bw + r) * 33 + cc];
    }
    __syncthreads();
    {
        float Tg[32];
        #pragma unroll
        for (int o = 0; o < 32; ++o) Tg[o] = 0.f;
        float pool = 0.f;
        for (int l2 = 0; l2 < 33; ++l2) {
            float x = sw[lane * 34 + l2];
            pool += x;
            const float* cr = ws + WS_CWOG + l2 * 32;
            #pragma unroll
            for (int o = 0; o < 32; ++o) Tg[o] = fmaf(x, cr[o], Tg[o]);
        }
        pool *= (1.f / 33.f);
        float vb2 = fmaf(pool, eog_inw[2], eog_inb[2]);
        float ob2 = fmaf(vb2, eog_ow[0], eog_ob[0]);
        #pragma unroll
        for (int o = 0; o < 32; ++o) {
            float hh = fmaf(ob2, Tg[o], eog_cb[o]);
            Tg[o] = hh > 0.f ? hh : expm1f(hh);
        }
        #pragma unroll
        for (int f = 0; f < 64; ++f) {
            float acc = feat[f];
            #pragma unroll
            for (int o = 0; o < 32; ++o)
                acc = fmaf(ws[WS_A_EOG + f * 32 + o], Tg[o], acc);
            feat[f] = acc;
        }
    }

    for (int i2 = 0; i2 < 2; ++i2) {
        const float* Wa  = ws + WS_WATT + i2 * 4096;
        const float* ba  = ws + WS_BATT + i2 * 64;
        const float* s1  = tl_ln1_s + i2 * 64;
        const float* g1  = tl_ln1_b + i2 * 64;
        const float* s2  = tl_ln2_s + i2 * 64;
        const float* g2  = tl_ln2_b + i2 * 64;
        const float* w1p = tl_w1 + i2 * 16384;
        const float* bf1 = tl_b1 + i2 * 256;
        const float* w2t = ws + WS_W2T + i2 * 16384;
        const float* bf2 = tl_b2 + i2 * 64;

        float hb[64];
        {
            float m = 0.f;
            #pragma unroll
            for (int d = 0; d < 64; ++d) m += feat[d];
            m *= 0.015625f;
            float vv = 0.f;
            #pragma unroll
            for (int d = 0; d < 64; ++d) { float u = feat[d] - m; vv = fmaf(u, u, vv); }
            vv *= 0.015625f;
            float inv = rsqrtf(vv + 1e-5f);
            #pragma unroll
            for (int d = 0; d < 64; ++d)
                hb[d] = fmaf((feat[d] - m) * inv, s1[d], g1[d]);
        }
        #pragma unroll
        for (int c = 0; c < 64; ++c) {
            float a = ba[c];
            #pragma unroll
            for (int d = 0; d < 64; ++d) a = fmaf(Wa[c * 64 + d], hb[d], a);
            feat[c] += a;
        }
        {
            float m = 0.f;
            #pragma unroll
            for (int d = 0; d < 64; ++d) m += feat[d];
            m *= 0.015625f;
            float vv = 0.f;
            #pragma unroll
            for (int d = 0; d < 64; ++d) { float u = feat[d] - m; vv = fmaf(u, u, vv); }
            vv *= 0.015625f;
            float inv = rsqrtf(vv + 1e-5f);
            #pragma unroll
            for (int d = 0; d < 64; ++d)
                hb[d] = fmaf((feat[d] - m) * inv, s2[d], g2[d]);
        }
        #pragma unroll
        for (int c = 0; c < 64; ++c) feat[c] += bf2[c];
        for (int j = 0; j < 256; ++j) {
            const float* wr = w1p + j * 64;
            float g = bf1[j];
            #pragma unroll
            for (int d = 0; d < 64; ++d) g = fmaf(wr[d], hb[d], g);
            g = 0.5f * g * (1.f + erff(g * 0.70710678118654752f));
            const float* w2r = w2t + j * 64;
            #pragma unroll
            for (int c = 0; c < 64; ++c) feat[c] = fmaf(g, w2r[c], feat[c]);
        }
    }

    {
        float m = 0.f;
        #pragma unroll
        for (int d = 0; d < 64; ++d) m += feat[d];
        m *= 0.015625f;
        float vv = 0.f;
        #pragma unroll
        for (int d = 0; d < 64; ++d) { float u = feat[d] - m; vv = fmaf(u, u, vv); }
        vv *= 0.015625f;
        float inv = rsqrtf(vv + 1e-5f);
        float o0 = cls_b[0], o1 = cls_b[1], o2 = cls_b[2];
        #pragma unroll
        for (int d = 0; d < 64; ++d) {
            float n = fmaf((feat[d] - m) * inv, fn_s[d], fn_b[d]);
            o0 = fmaf(n, cls_w[d], o0);
            o1 = fmaf(n, cls_w[64 + d], o1);
            o2 = fmaf(n, cls_w[128 + d], o2);
        }
        float* op = out + b * 3;
        op[0] = o0; op[1] = o1; op[2] = o2;
    }
}

extern "C" void kernel_launch(void* const* d_in, const int* in_sizes, int n_in,
                              void* d_out, int out_size, void* d_ws, size_t ws_size,
                              hipStream_t stream) {
    const float* eeg      = (const float*)d_in[0];
    const float* eog      = (const float*)d_in[1];
    const float* eeg_inw  = (const float*)d_in[2];
    const float* eeg_inb  = (const float*)d_in[3];
    const float* eeg_ow   = (const float*)d_in[4];
    const float* eeg_ob   = (const float*)d_in[5];
    const float* eog_inw  = (const float*)d_in[6];
    const float* eog_inb  = (const float*)d_in[7];
    const float* eog_ow   = (const float*)d_in[8];
    const float* eog_ob   = (const float*)d_in[9];
    const float* eeg_cw   = (const float*)d_in[10];
    const float* eeg_cb   = (const float*)d_in[11];
    const float* eeg_fw   = (const float*)d_in[12];
    const float* eeg_fb   = (const float*)d_in[13];
    const float* eog_cw   = (const float*)d_in[14];
    const float* eog_cb   = (const float*)d_in[15];
    const float* eog_fw   = (const float*)d_in[16];
    const float* eog_fb   = (const float*)d_in[17];
    const float* fus_w    = (const float*)d_in[18];
    const float* fus_b    = (const float*)d_in[19];
    const float* tl_ln1_s = (const float*)d_in[20];
    const float* tl_ln1_b = (const float*)d_in[21];
    const float* tl_inw   = (const float*)d_in[22];
    const float* tl_inb   = (const float*)d_in[23];
    const float* tl_ow    = (const float*)d_in[24];
    const float* tl_ob    = (const float*)d_in[25];
    const float* tl_ln2_s = (const float*)d_in[26];
    const float* tl_ln2_b = (const float*)d_in[27];
    const float* tl_w1    = (const float*)d_in[28];
    const float* tl_b1    = (const float*)d_in[29];
    const float* tl_w2    = (const float*)d_in[30];
    const float* tl_b2    = (const float*)d_in[31];
    const float* fn_s     = (const float*)d_in[32];
    const float* fn_b     = (const float*)d_in[33];
    const float* cls_w    = (const float*)d_in[34];
    const float* cls_b    = (const float*)d_in[35];
    float* ws  = (float*)d_ws;
    float* out = (float*)d_out;

    hipLaunchKernelGGL(mcaf_pre, dim3(8), dim3(256), 0, stream,
                       eeg_inw, eeg_inb, eeg_ow, eeg_ob, eeg_cw,
                       eeg_fw, eeg_fb, eog_cw, eog_fw, eog_fb,
                       fus_w, fus_b, tl_inw, tl_inb, tl_ow, tl_ob, tl_w1, tl_w2, ws);

    const size_t need = (size_t)WS_TOTALF * 4u;
    if (ws_size >= need) {
        hipLaunchKernelGGL(eeg_tr, dim3((NB / 256) * 8), dim3(256), 0, stream, eeg, ws);
        hipLaunchKernelGGL(eog_tr, dim3(NB / 256), dim3(256), 0, stream, eog, ws);
        hipLaunchKernelGGL(mcaf_front, dim3(NB / 256), dim3(256), 0, stream,
                           eeg_cb, eog_inw, eog_inb, eog_ow, eog_ob, eog_cb, ws);
        hipLaunchKernelGGL(mcaf_trans, dim3(NB / 256), dim3(256), 0, stream,
                           tl_ln1_s, tl_ln1_b, tl_ln2_s, tl_ln2_b,
                           tl_b1, tl_b2, fn_s, fn_b, cls_w, cls_b, ws, out);
    } else {
        hipLaunchKernelGGL(mcaf_main_fb, dim3(NB / 256), dim3(256), 0, stream,
                           eeg, eog, eeg_inb, eeg_ow, eeg_ob,
                           eog_inw, eog_inb, eog_ow, eog_ob,
                           eeg_cb, eog_cb,
                           tl_ln1_s, tl_ln1_b, tl_ln2_s, tl_ln2_b,
                           tl_w1, tl_b1, tl_b2,
                           fn_s, fn_b, cls_w, cls_b, ws, out);
    }
}

// Round 9
// 281.976 us; speedup vs baseline: 3.0794x; 1.4006x over previous
//
#include <hip/hip_runtime.h>
#include <hip/hip_bf16.h>
#include <math.h>

#define NB 131072

typedef __attribute__((ext_vector_type(2))) float f32x2;
typedef __attribute__((ext_vector_type(4))) float f32x4;
typedef __attribute__((ext_vector_type(8))) short bf16x8;

// Wave-local ordering fence for wave-private LDS (DS ops pinned, rest free).
#define SYNC() do { asm volatile("" ::: "memory"); __builtin_amdgcn_sched_barrier(0x7F); } while (0)

// ---- workspace layout (float offsets) ----
#define WS_A_EEG 0          // [64][32] f32 (fallback)
#define WS_A_EOG 2048
#define WS_B0    4096       // [64]
#define WS_WATT  4160       // [2][64][64] f32 (fallback)
#define WS_BATT  12352      // [2][64]
#define WS_WVT   12480      // [62][62] (fallback)
#define WS_M     16324      // [62][62] (fallback)
#define WS_OBB   20168      // [62]
#define WS_CWT   20232      // [62][32][5] (fallback)
#define WS_CWOG  30152      // [33][32]
#define WS_W2T   31208      // [2][256][64] f32 (fallback)
#define WB_WA_F  64000      // bf16 [2][64][64]
#define WB_W1_F  68096      // bf16 [2][256][64]
#define WB_W2_F  84480      // bf16 [2][64][256]
#define WB_MB    100864     // bf16 [64][64]  Maug[c][e]
#define WB_CWL   102912     // bf16 [32][320] CWL[o][l*64+c]
#define WB_ACAT  108032     // bf16 [64][64]  [A_EEG | A_EOG][f][j]
// bf16 channel-PAIR planes: dword at plane (l*31+cp), batch b holds channels
// (2cp, 2cp+1) of timestep l.  155 planes x NB dwords.
#define WB_EEGXB 110080
#define WB_POOLB (WB_EEGXB + 155 * NB)       // bf16 [8][B][8] pooled (e62=1, e63=0)
#define WS_EOGT  (WB_POOLB + 32 * NB)        // f32 [33][B]
#define WS_TOTALF (WS_EOGT + 33 * NB)

// per-wave LDS for fused kernel: 64 rows x 208B (13 x 16B granules; odd stride)
#define ROWB 208
#define WAVE_LDS (64 * ROWB)

__device__ __forceinline__ short f2bf(float x) {
    union { __hip_bfloat16 h; short s; } u;
    u.h = __float2bfloat16(x);
    return u.s;
}
__device__ __forceinline__ float bf2f(unsigned short s) {
    union { unsigned int u; float f; } v;
    v.u = (unsigned int)s << 16;
    return v.f;
}

__global__ __launch_bounds__(256) void mcaf_pre(
    const float* __restrict__ eeg_inw, const float* __restrict__ eeg_inb,
    const float* __restrict__ eeg_ow,  const float* __restrict__ eeg_ob,
    const float* __restrict__ eeg_cw,
    const float* __restrict__ eeg_fw,  const float* __restrict__ eeg_fb,
    const float* __restrict__ eog_cw,  const float* __restrict__ eog_fw,
    const float* __restrict__ eog_fb,
    const float* __restrict__ fus_w,   const float* __restrict__ fus_b,
    const float* __restrict__ tl_inw,  const float* __restrict__ tl_inb,
    const float* __restrict__ tl_ow,   const float* __restrict__ tl_ob,
    const float* __restrict__ tl_w1,   const float* __restrict__ tl_w2,
    float* __restrict__ ws)
{
    const int tid  = blockIdx.x * blockDim.x + threadIdx.x;
    const int nthr = gridDim.x * blockDim.x;
    short* wa_b   = (short*)(ws + WB_WA_F);
    short* w1_b   = (short*)(ws + WB_W1_F);
    short* w2_b   = (short*)(ws + WB_W2_F);
    short* mb_b   = (short*)(ws + WB_MB);
    short* cwl_b  = (short*)(ws + WB_CWL);
    short* acat_b = (short*)(ws + WB_ACAT);

    for (int idx = tid; idx < 2048; idx += nthr) {
        int f = idx >> 5, o = idx & 31;
        float a = 0.f, a2 = 0.f;
        for (int k = 0; k < 64; ++k) {
            a  = fmaf(fus_w[f * 128 + k],      eeg_fw[k * 32 + o], a);
            a2 = fmaf(fus_w[f * 128 + 64 + k], eog_fw[k * 32 + o], a2);
        }
        ws[WS_A_EEG + idx] = a;
        ws[WS_A_EOG + idx] = a2;
    }
    for (int idx = tid; idx < 4096; idx += nthr) {
        int f = idx >> 6, j = idx & 63;
        float a = 0.f;
        if (j < 32) {
            for (int k = 0; k < 64; ++k)
                a = fmaf(fus_w[f * 128 + k], eeg_fw[k * 32 + j], a);
        } else {
            int o = j - 32;
            for (int k = 0; k < 64; ++k)
                a = fmaf(fus_w[f * 128 + 64 + k], eog_fw[k * 32 + o], a);
        }
        acat_b[idx] = f2bf(a);
    }
    for (int f = tid; f < 64; f += nthr) {
        float a = fus_b[f] + (float)(f & 1);
        for (int k = 0; k < 64; ++k) {
            a = fmaf(fus_w[f * 128 + k],      eeg_fb[k], a);
            a = fmaf(fus_w[f * 128 + 64 + k], eog_fb[k], a);
        }
        ws[WS_B0 + f] = a;
    }
    for (int idx = tid; idx < 8192; idx += nthr) {
        int i = idx >> 12, c = (idx >> 6) & 63, d = idx & 63;
        float a = 0.f;
        for (int e = 0; e < 64; ++e)
            a = fmaf(tl_ow[i * 4096 + c * 64 + e],
                     tl_inw[i * 12288 + (128 + e) * 64 + d], a);
        ws[WS_WATT + idx] = a;
        wa_b[idx] = f2bf(a);
    }
    for (int idx = tid; idx < 128; idx += nthr) {
        int i = idx >> 6, c = idx & 63;
        float a = tl_ob[i * 64 + c];
        for (int e = 0; e < 64; ++e)
            a = fmaf(tl_ow[i * 4096 + c * 64 + e], tl_inb[i * 192 + 128 + e], a);
        ws[WS_BATT + idx] = a;
    }
    for (int idx = tid; idx < 32768; idx += nthr) w1_b[idx] = f2bf(tl_w1[idx]);
    for (int idx = tid; idx < 32768; idx += nthr) w2_b[idx] = f2bf(tl_w2[idx]);

    for (int idx = tid; idx < 3844; idx += nthr) {
        int e = idx / 62, d = idx - e * 62;
        ws[WS_WVT + idx] = eeg_inw[(124 + d) * 62 + e];
    }
    for (int idx = tid; idx < 3844; idx += nthr) {
        int c = idx / 62, e = idx - c * 62;
        float a = 0.f;
        for (int d = 0; d < 62; ++d)
            a = fmaf(eeg_ow[c * 62 + d], eeg_inw[(124 + d) * 62 + e], a);
        ws[WS_M + idx] = a;
    }
    for (int c = tid; c < 62; c += nthr) {
        float a = eeg_ob[c];
        for (int d = 0; d < 62; ++d)
            a = fmaf(eeg_ow[c * 62 + d], eeg_inb[124 + d], a);
        ws[WS_OBB + c] = a;
    }
    for (int idx = tid; idx < 4096; idx += nthr) {
        int c = idx >> 6, e = idx & 63;
        float a = 0.f;
        if (c < 62) {
            if (e < 62) {
                for (int d = 0; d < 62; ++d)
                    a = fmaf(eeg_ow[c * 62 + d], eeg_inw[(124 + d) * 62 + e], a);
            } else if (e == 62) {
                a = eeg_ob[c];
                for (int d = 0; d < 62; ++d)
                    a = fmaf(eeg_ow[c * 62 + d], eeg_inb[124 + d], a);
            }
        }
        mb_b[idx] = f2bf(a);
    }
    for (int idx = tid; idx < 10240; idx += nthr) {
        int o = idx / 320, k = idx - o * 320;
        int l = k >> 6, c = k & 63;
        float a = (c < 62 && l < 5) ? eeg_cw[o * 310 + c * 5 + l] : 0.f;
        cwl_b[idx] = f2bf(a);
    }
    for (int idx = tid; idx < 9920; idx += nthr) {
        int c = idx / 160, r = idx - c * 160;
        int o = r / 5, l = r - o * 5;
        ws[WS_CWT + idx] = eeg_cw[o * 310 + c * 5 + l];
    }
    for (int idx = tid; idx < 1056; idx += nthr) {
        int l = idx >> 5, o = idx & 31;
        ws[WS_CWOG + idx] = eog_cw[o * 33 + l];
    }
    for (int idx = tid; idx < 32768; idx += nthr) {
        int i = idx >> 14, r = idx & 16383;
        int j = r >> 6, c = r & 63;
        ws[WS_W2T + idx] = tl_w2[i * 16384 + c * 256 + j];
    }
}

// ---- eeg re-layout: bf16 LDS staging (21KB/block -> 7 blocks/CU), ----------
// ---- packed bf16 channel-pair output + pooled bf16 -------------------------
__global__ __launch_bounds__(256) void eeg_tr(const float* __restrict__ eeg,
                                              float* __restrict__ ws)
{
    __shared__ short smem[4 * 64 * 42];   // 21504 B
    const int lane  = threadIdx.x & 63;
    const int wid   = threadIdx.x >> 6;
    const int chunk = blockIdx.x & 7;
    const int bw    = (blockIdx.x >> 3) * 256 + wid * 64;
    const int b     = bw + lane;
    short* sw = smem + wid * (64 * 42);

    const int ch0 = chunk * 40;
    // stage 64 rows x 40 cols as bf16 (f32x2 loads, 8B-aligned: 1240 % 8 == 0)
    for (int j = 0; j < 20; ++j) {
        int idx = j * 64 + lane;
        int r = idx / 20, cc2 = idx - r * 20;
        int gcol = ch0 + cc2 * 2;
        unsigned int pack = 0;
        if (gcol < 310) {
            f32x2 v = *(const f32x2*)(eeg + (size_t)(bw + r) * 310 + gcol);
            pack = (unsigned int)(unsigned short)f2bf(v[0]) |
                   ((unsigned int)(unsigned short)f2bf(v[1]) << 16);
        }
        *(unsigned int*)(sw + r * 42 + cc2 * 2) = pack;
    }
    SYNC();
    const short* myrow = sw + lane * 42;
    unsigned int* planes = (unsigned int*)(ws + WB_EEGXB);
    // packed channel-pair planes
    #pragma unroll
    for (int pr = 0; pr < 4; ++pr) {
        int c0 = chunk * 8 + pr * 2;
        if (c0 < 62) {
            int cp = c0 >> 1;
            #pragma unroll
            for (int l = 0; l < 5; ++l) {
                unsigned int d = (unsigned int)(unsigned short)myrow[pr * 10 + l] |
                                 ((unsigned int)(unsigned short)myrow[pr * 10 + 5 + l] << 16);
                planes[(size_t)(l * 31 + cp) * NB + b] = d;
            }
        }
    }
    // pooled (f32 accumulate from bf16 values), augmented cols 62->1, 63->0
    bf16x8 pv;
    #pragma unroll
    for (int el = 0; el < 8; ++el) {
        int c = chunk * 8 + el;
        float p;
        if (c < 62) {
            float s = bf2f((unsigned short)myrow[el * 5 + 0]);
            s += bf2f((unsigned short)myrow[el * 5 + 1]);
            s += bf2f((unsigned short)myrow[el * 5 + 2]);
            s += bf2f((unsigned short)myrow[el * 5 + 3]);
            s += bf2f((unsigned short)myrow[el * 5 + 4]);
            p = s * 0.2f;
        } else {
            p = (c == 62) ? 1.0f : 0.f;
        }
        pv[el] = f2bf(p);
    }
    *(bf16x8*)((short*)(ws + WB_POOLB) + ((size_t)chunk * NB + b) * 8) = pv;
}

// ---- eog transpose ----
__global__ __launch_bounds__(256) void eog_tr(const float* __restrict__ eog,
                                              float* __restrict__ ws)
{
    __shared__ float smem[4 * 64 * 34];
    const int lane = threadIdx.x & 63;
    const int wid  = threadIdx.x >> 6;
    const int bw   = blockIdx.x * 256 + wid * 64;
    float* sw = smem + wid * (64 * 34);

    for (int j = 0; j < 33; ++j) {
        int idx = j * 64 + lane;
        int r = idx / 33, cc = idx - r * 33;
        sw[r * 34 + cc] = eog[(size_t)(bw + r) * 33 + cc];
    }
    SYNC();
    #pragma unroll
    for (int cc = 0; cc < 33; ++cc)
        ws[WS_EOGT + (size_t)cc * NB + bw + lane] = sw[lane * 34 + cc];
}

// ============ FUSED: MFMA front-end + transformer + head ====================
__global__ __launch_bounds__(256, 2) void mcaf_fused(
    const float* __restrict__ eeg_cb,
    const float* __restrict__ eog_inw, const float* __restrict__ eog_inb,
    const float* __restrict__ eog_ow,  const float* __restrict__ eog_ob,
    const float* __restrict__ eog_cb,
    const float* __restrict__ tl_ln1_s, const float* __restrict__ tl_ln1_b,
    const float* __restrict__ tl_ln2_s, const float* __restrict__ tl_ln2_b,
    const float* __restrict__ tl_b1,   const float* __restrict__ tl_b2,
    const float* __restrict__ fn_s,    const float* __restrict__ fn_b,
    const float* __restrict__ cls_w,   const float* __restrict__ cls_b,
    const float* __restrict__ ws,      float* __restrict__ out)
{
    __shared__ char smem[4 * WAVE_LDS];
    const int tid  = threadIdx.x;
    const int lane = tid & 63;
    const int wid  = tid >> 6;
    const int b    = blockIdx.x * 256 + tid;
    char* Wv = smem + wid * WAVE_LDS;
    const int g4  = lane >> 4;
    const int r15 = lane & 15;

    const short* MB   = (const short*)(ws + WB_MB);
    const short* CWL  = (const short*)(ws + WB_CWL);
    const short* ACAT = (const short*)(ws + WB_ACAT);
    const short* PB   = (const short*)(ws + WB_POOLB);
    const unsigned int* XP = (const unsigned int*)(ws + WB_EEGXB);

    // ---- phase 1: oc[64] = [pooled,1] @ Maug^T ----
    #pragma unroll
    for (int q = 0; q < 8; ++q) {
        bf16x8 v = *(const bf16x8*)(PB + ((size_t)q * NB + b) * 8);
        *(bf16x8*)(Wv + lane * ROWB + q * 16) = v;
    }
    SYNC();
    bf16x8 Ap[4][2];
    #pragma unroll
    for (int rt = 0; rt < 4; ++rt)
        #pragma unroll
        for (int kt = 0; kt < 2; ++kt)
            Ap[rt][kt] = *(const bf16x8*)(Wv + (rt * 16 + r15) * ROWB + (kt * 4 + g4) * 16);
    SYNC();
    f32x4 accO[4][4];
    #pragma unroll
    for (int rt = 0; rt < 4; ++rt)
        #pragma unroll
        for (int ct = 0; ct < 4; ++ct) accO[rt][ct] = (f32x4){0.f, 0.f, 0.f, 0.f};
    #pragma unroll
    for (int kt = 0; kt < 2; ++kt) {
        bf16x8 bb[4];
        #pragma unroll
        for (int ct = 0; ct < 4; ++ct)
            bb[ct] = *(const bf16x8*)(MB + (ct * 16 + r15) * 64 + kt * 32 + g4 * 8);
        #pragma unroll
        for (int rt = 0; rt < 4; ++rt)
            #pragma unroll
            for (int ct = 0; ct < 4; ++ct)
                accO[rt][ct] = __builtin_amdgcn_mfma_f32_16x16x32_bf16(Ap[rt][kt], bb[ct], accO[rt][ct], 0, 0, 0);
    }
    float oc[64];
    #pragma unroll
    for (int hf = 0; hf < 2; ++hf) {
        SYNC();
        #pragma unroll
        for (int ct2 = 0; ct2 < 2; ++ct2) {
            int ct = hf * 2 + ct2;
            #pragma unroll
            for (int rt = 0; rt < 4; ++rt)
                #pragma unroll
                for (int rg = 0; rg < 4; ++rg) {
                    int row = rt * 16 + g4 * 4 + rg;
                    *(float*)(Wv + row * ROWB + (ct2 * 16 + r15) * 4) = accO[rt][ct][rg];
                }
        }
        SYNC();
        #pragma unroll
        for (int j8 = 0; j8 < 8; ++j8) {
            f32x4 v = *(const f32x4*)(Wv + lane * ROWB + j8 * 16);
            #pragma unroll
            for (int e = 0; e < 4; ++e) oc[hf * 32 + j8 * 4 + e] = v[e];
        }
    }

    // ---- phase 2: h = Y @ CWL^T ; Y built on the fly from packed bf16 x ----
    f32x4 accH[4][2];
    #pragma unroll
    for (int rt = 0; rt < 4; ++rt) {
        accH[rt][0] = (f32x4){0.f, 0.f, 0.f, 0.f};
        accH[rt][1] = (f32x4){0.f, 0.f, 0.f, 0.f};
    }
    for (int l = 0; l < 5; ++l) {
        SYNC();
        #pragma unroll
        for (int jj = 0; jj < 8; ++jj) {
            bf16x8 v;
            #pragma unroll
            for (int q = 0; q < 4; ++q) {
                int cp = jj * 4 + q;
                if (cp < 31) {
                    unsigned int d = XP[(size_t)(l * 31 + cp) * NB + b];
                    v[2 * q]     = f2bf(oc[2 * cp]     * bf2f((unsigned short)(d & 0xffffu)));
                    v[2 * q + 1] = f2bf(oc[2 * cp + 1] * bf2f((unsigned short)(d >> 16)));
                } else {
                    v[2 * q] = 0; v[2 * q + 1] = 0;
                }
            }
            *(bf16x8*)(Wv + lane * ROWB + jj * 16) = v;
        }
        SYNC();
        bf16x8 a[4][2];
        #pragma unroll
        for (int rt = 0; rt < 4; ++rt)
            #pragma unroll
            for (int kt = 0; kt < 2; ++kt)
                a[rt][kt] = *(const bf16x8*)(Wv + (rt * 16 + r15) * ROWB + (kt * 4 + g4) * 16);
        SYNC();
        #pragma unroll
        for (int kt = 0; kt < 2; ++kt) {
            bf16x8 bb[2];
            #pragma unroll
            for (int ct = 0; ct < 2; ++ct)
                bb[ct] = *(const bf16x8*)(CWL + (ct * 16 + r15) * 320 + l * 64 + kt * 32 + g4 * 8);
            #pragma unroll
            for (int rt = 0; rt < 4; ++rt)
                #pragma unroll
                for (int ct = 0; ct < 2; ++ct)
                    accH[rt][ct] = __builtin_amdgcn_mfma_f32_16x16x32_bf16(a[rt][kt], bb[ct], accH[rt][ct], 0, 0, 0);
        }
    }
    float h[32];
    SYNC();
    #pragma unroll
    for (int ct2 = 0; ct2 < 2; ++ct2)
        #pragma unroll
        for (int rt = 0; rt < 4; ++rt)
            #pragma unroll
            for (int rg = 0; rg < 4; ++rg) {
                int row = rt * 16 + g4 * 4 + rg;
                *(float*)(Wv + row * ROWB + (ct2 * 16 + r15) * 4) = accH[rt][ct2][rg];
            }
    SYNC();
    #pragma unroll
    for (int j8 = 0; j8 < 8; ++j8) {
        f32x4 v = *(const f32x4*)(Wv + lane * ROWB + j8 * 16);
        #pragma unroll
        for (int e = 0; e < 4; ++e) h[j8 * 4 + e] = v[e] + eeg_cb[j8 * 4 + e];
    }
    #pragma unroll
    for (int o = 0; o < 32; ++o) h[o] = h[o] > 0.f ? h[o] : expm1f(h[o]);

    // ---- phase 3: EOG per-lane (coalesced eogT) ----
    float Tg[32];
    {
        #pragma unroll
        for (int o = 0; o < 32; ++o) Tg[o] = 0.f;
        float pool = 0.f;
        for (int l2 = 0; l2 < 33; ++l2) {
            float x = ws[WS_EOGT + (size_t)l2 * NB + b];
            pool += x;
            const float* cr = ws + WS_CWOG + l2 * 32;
            #pragma unroll
            for (int o = 0; o < 32; ++o) Tg[o] = fmaf(x, cr[o], Tg[o]);
        }
        pool *= (1.f / 33.f);
        float vb2 = fmaf(pool, eog_inw[2], eog_inb[2]);
        float ob2 = fmaf(vb2, eog_ow[0], eog_ob[0]);
        #pragma unroll
        for (int o = 0; o < 32; ++o) {
            float hh = fmaf(ob2, Tg[o], eog_cb[o]);
            Tg[o] = hh > 0.f ? hh : expm1f(hh);
        }
    }

    // ---- phase 4: feat = [h|Tg] @ ACAT^T + B0 (feat stays in registers) ----
    SYNC();
    #pragma unroll
    for (int jj = 0; jj < 8; ++jj) {
        bf16x8 v;
        #pragma unroll
        for (int e = 0; e < 8; ++e) {
            int j = jj * 8 + e;
            v[e] = f2bf(j < 32 ? h[j] : Tg[j - 32]);
        }
        *(bf16x8*)(Wv + lane * ROWB + jj * 16) = v;
    }
    SYNC();
    bf16x8 Ac[4][2];
    #pragma unroll
    for (int rt = 0; rt < 4; ++rt)
        #pragma unroll
        for (int kt = 0; kt < 2; ++kt)
            Ac[rt][kt] = *(const bf16x8*)(Wv + (rt * 16 + r15) * ROWB + (kt * 4 + g4) * 16);
    SYNC();
    f32x4 accF[4][4];
    #pragma unroll
    for (int rt = 0; rt < 4; ++rt)
        #pragma unroll
        for (int ct = 0; ct < 4; ++ct) accF[rt][ct] = (f32x4){0.f, 0.f, 0.f, 0.f};
    #pragma unroll
    for (int kt = 0; kt < 2; ++kt) {
        bf16x8 bb[4];
        #pragma unroll
        for (int ct = 0; ct < 4; ++ct)
            bb[ct] = *(const bf16x8*)(ACAT + (ct * 16 + r15) * 64 + kt * 32 + g4 * 8);
        #pragma unroll
        for (int rt = 0; rt < 4; ++rt)
            #pragma unroll
            for (int ct = 0; ct < 4; ++ct)
                accF[rt][ct] = __builtin_amdgcn_mfma_f32_16x16x32_bf16(Ac[rt][kt], bb[ct], accF[rt][ct], 0, 0, 0);
    }
    float feat[64];
    #pragma unroll
    for (int hf = 0; hf < 2; ++hf) {
        SYNC();
        #pragma unroll
        for (int ct2 = 0; ct2 < 2; ++ct2) {
            int ct = hf * 2 + ct2;
            #pragma unroll
            for (int rt = 0; rt < 4; ++rt)
                #pragma unroll
                for (int rg = 0; rg < 4; ++rg) {
                    int row = rt * 16 + g4 * 4 + rg;
                    *(float*)(Wv + row * ROWB + (ct2 * 16 + r15) * 4) = accF[rt][ct][rg];
                }
        }
        SYNC();
        #pragma unroll
        for (int j8 = 0; j8 < 8; ++j8) {
            f32x4 v = *(const f32x4*)(Wv + lane * ROWB + j8 * 16);
            #pragma unroll
            for (int e = 0; e < 4; ++e) {
                int d = hf * 32 + j8 * 4 + e;
                feat[d] = v[e] + ws[WS_B0 + d];
            }
        }
    }

    // ---- transformer (2 layers) + head ----
    const short* WAb = (const short*)(ws + WB_WA_F);
    const short* W1b = (const short*)(ws + WB_W1_F);
    const short* W2b = (const short*)(ws + WB_W2_F);

    for (int i2 = 0; i2 < 2; ++i2) {
        const float* ba  = ws + WS_BATT + i2 * 64;
        const float* s1  = tl_ln1_s + i2 * 64;
        const float* gb1 = tl_ln1_b + i2 * 64;
        const float* s2  = tl_ln2_s + i2 * 64;
        const float* gb2 = tl_ln2_b + i2 * 64;
        const float* bf1 = tl_b1 + i2 * 256;
        const float* bf2 = tl_b2 + i2 * 64;

        float hb[64];
        {
            float m = 0.f;
            #pragma unroll
            for (int d = 0; d < 64; ++d) m += feat[d];
            m *= 0.015625f;
            float vv = 0.f;
            #pragma unroll
            for (int d = 0; d < 64; ++d) { float u = feat[d] - m; vv = fmaf(u, u, vv); }
            vv *= 0.015625f;
            float inv = rsqrtf(vv + 1e-5f);
            #pragma unroll
            for (int d = 0; d < 64; ++d)
                hb[d] = fmaf((feat[d] - m) * inv, s1[d], gb1[d]);
        }
        SYNC();
        #pragma unroll
        for (int jj = 0; jj < 8; ++jj) {
            bf16x8 v;
            #pragma unroll
            for (int e = 0; e < 8; ++e) v[e] = f2bf(hb[jj * 8 + e]);
            *(bf16x8*)(Wv + lane * ROWB + jj * 16) = v;
        }
        SYNC();
        bf16x8 Aat[4][2];
        #pragma unroll
        for (int rt = 0; rt < 4; ++rt)
            #pragma unroll
            for (int kt = 0; kt < 2; ++kt)
                Aat[rt][kt] = *(const bf16x8*)(Wv + (rt * 16 + r15) * ROWB + (kt * 4 + g4) * 16);
        SYNC();
        f32x4 acc[4][4];
        #pragma unroll
        for (int rt = 0; rt < 4; ++rt)
            #pragma unroll
            for (int ct = 0; ct < 4; ++ct) acc[rt][ct] = (f32x4){0.f, 0.f, 0.f, 0.f};
        #pragma unroll
        for (int kt = 0; kt < 2; ++kt) {
            bf16x8 bb[4];
            #pragma unroll
            for (int ct = 0; ct < 4; ++ct)
                bb[ct] = *(const bf16x8*)(WAb + i2 * 4096 + (ct * 16 + r15) * 64 + kt * 32 + g4 * 8);
            #pragma unroll
            for (int rt = 0; rt < 4; ++rt)
                #pragma unroll
                for (int ct = 0; ct < 4; ++ct)
                    acc[rt][ct] = __builtin_amdgcn_mfma_f32_16x16x32_bf16(Aat[rt][kt], bb[ct], acc[rt][ct], 0, 0, 0);
        }
        #pragma unroll
        for (int hf = 0; hf < 2; ++hf) {
            SYNC();
            #pragma unroll
            for (int ct2 = 0; ct2 < 2; ++ct2) {
                int ct = hf * 2 + ct2;
                #pragma unroll
                for (int rt = 0; rt < 4; ++rt)
                    #pragma unroll
                    for (int rg = 0; rg < 4; ++rg) {
                        int row = rt * 16 + g4 * 4 + rg;
                        *(float*)(Wv + row * ROWB + (ct2 * 16 + r15) * 4) = acc[rt][ct][rg];
                    }
            }
            SYNC();
            #pragma unroll
            for (int j8 = 0; j8 < 8; ++j8) {
                f32x4 v = *(const f32x4*)(Wv + lane * ROWB + j8 * 16);
                #pragma unroll
                for (int e = 0; e < 4; ++e) {
                    int d = hf * 32 + j8 * 4 + e;
                    feat[d] += v[e] + ba[d];
                }
            }
        }
        {
            float m = 0.f;
            #pragma unroll
            for (int d = 0; d < 64; ++d) m += feat[d];
            m *= 0.015625f;
            float vv = 0.f;
            #pragma unroll
            for (int d = 0; d < 64; ++d) { float u = feat[d] - m; vv = fmaf(u, u, vv); }
            vv *= 0.015625f;
            float inv = rsqrtf(vv + 1e-5f);
            #pragma unroll
            for (int d = 0; d < 64; ++d)
                hb[d] = fmaf((feat[d] - m) * inv, s2[d], gb2[d]);
        }
        SYNC();
        #pragma unroll
        for (int jj = 0; jj < 8; ++jj) {
            bf16x8 v;
            #pragma unroll
            for (int e = 0; e < 8; ++e) v[e] = f2bf(hb[jj * 8 + e]);
            *(bf16x8*)(Wv + lane * ROWB + jj * 16) = v;
        }
        SYNC();
        f32x4 F[4][4];
        #pragma unroll
        for (int rt = 0; rt < 4; ++rt)
            #pragma unroll
            for (int ct = 0; ct < 4; ++ct) F[rt][ct] = (f32x4){0.f, 0.f, 0.f, 0.f};

        for (int ch = 0; ch < 8; ++ch) {
            f32x4 G[4][2];
            #pragma unroll
            for (int rt = 0; rt < 4; ++rt) {
                G[rt][0] = (f32x4){0.f, 0.f, 0.f, 0.f};
                G[rt][1] = (f32x4){0.f, 0.f, 0.f, 0.f};
            }
            #pragma unroll
            for (int kt = 0; kt < 2; ++kt) {
                bf16x8 a1[4];
                #pragma unroll
                for (int rt = 0; rt < 4; ++rt)
                    a1[rt] = *(const bf16x8*)(Wv + (rt * 16 + r15) * ROWB + (kt * 4 + g4) * 16);
                bf16x8 b1[2];
                #pragma unroll
                for (int cc = 0; cc < 2; ++cc)
                    b1[cc] = *(const bf16x8*)(W1b + i2 * 16384 + (ch * 32 + cc * 16 + r15) * 64 + kt * 32 + g4 * 8);
                #pragma unroll
                for (int rt = 0; rt < 4; ++rt)
                    #pragma unroll
                    for (int cc = 0; cc < 2; ++cc)
                        G[rt][cc] = __builtin_amdgcn_mfma_f32_16x16x32_bf16(a1[rt], b1[cc], G[rt][cc], 0, 0, 0);
            }
            SYNC();
            #pragma unroll
            for (int rt = 0; rt < 4; ++rt)
                #pragma unroll
                for (int cc = 0; cc < 2; ++cc) {
                    float bj = bf1[ch * 32 + cc * 16 + r15];
                    #pragma unroll
                    for (int rg = 0; rg < 4; ++rg) {
                        float v = G[rt][cc][rg] + bj;
                        v = 0.5f * v * (1.f + erff(v * 0.70710678118654752f));
                        int row = rt * 16 + g4 * 4 + rg;
                        int col = cc * 16 + r15;
                        *(short*)(Wv + row * ROWB + 128 + ((col >> 3) << 4) + ((col & 7) << 1)) = f2bf(v);
                    }
                }
            SYNC();
            bf16x8 a2[4], b2[4];
            #pragma unroll
            for (int rt = 0; rt < 4; ++rt)
                a2[rt] = *(const bf16x8*)(Wv + (rt * 16 + r15) * ROWB + 128 + g4 * 16);
            #pragma unroll
            for (int ct = 0; ct < 4; ++ct)
                b2[ct] = *(const bf16x8*)(W2b + i2 * 16384 + (ct * 16 + r15) * 256 + ch * 32 + g4 * 8);
            #pragma unroll
            for (int rt = 0; rt < 4; ++rt)
                #pragma unroll
                for (int ct = 0; ct < 4; ++ct)
                    F[rt][ct] = __builtin_amdgcn_mfma_f32_16x16x32_bf16(a2[rt], b2[ct], F[rt][ct], 0, 0, 0);
            SYNC();
        }
        #pragma unroll
        for (int hf = 0; hf < 2; ++hf) {
            SYNC();
            #pragma unroll
            for (int ct2 = 0; ct2 < 2; ++ct2) {
                int ct = hf * 2 + ct2;
                #pragma unroll
                for (int rt = 0; rt < 4; ++rt)
                    #pragma unroll
                    for (int rg = 0; rg < 4; ++rg) {
                        int row = rt * 16 + g4 * 4 + rg;
                        *(float*)(Wv + row * ROWB + (ct2 * 16 + r15) * 4) = F[rt][ct][rg];
                    }
            }
            SYNC();
            #pragma unroll
            for (int j8 = 0; j8 < 8; ++j8) {
                f32x4 v = *(const f32x4*)(Wv + lane * ROWB + j8 * 16);
                #pragma unroll
                for (int e = 0; e < 4; ++e) {
                    int d = hf * 32 + j8 * 4 + e;
                    feat[d] += v[e] + bf2[d];
                }
            }
        }
        SYNC();
    }

    {
        float m = 0.f;
        #pragma unroll
        for (int d = 0; d < 64; ++d) m += feat[d];
        m *= 0.015625f;
        float vv = 0.f;
        #pragma unroll
        for (int d = 0; d < 64; ++d) { float u = feat[d] - m; vv = fmaf(u, u, vv); }
        vv *= 0.015625f;
        float inv = rsqrtf(vv + 1e-5f);
        float o0 = cls_b[0], o1 = cls_b[1], o2 = cls_b[2];
        #pragma unroll
        for (int d = 0; d < 64; ++d) {
            float n = fmaf((feat[d] - m) * inv, fn_s[d], fn_b[d]);
            o0 = fmaf(n, cls_w[d], o0);
            o1 = fmaf(n, cls_w[64 + d], o1);
            o2 = fmaf(n, cls_w[128 + d], o2);
        }
        float* op = out + (size_t)b * 3;
        op[0] = o0; op[1] = o1; op[2] = o2;
    }
}

// ================= fallback main kernel (fp32, LDS staging) =================
__global__ __launch_bounds__(256, 2) void mcaf_main_fb(
    const float* __restrict__ eeg,     const float* __restrict__ eog,
    const float* __restrict__ eeg_inb,
    const float* __restrict__ eeg_ow,  const float* __restrict__ eeg_ob,
    const float* __restrict__ eog_inw, const float* __restrict__ eog_inb,
    const float* __restrict__ eog_ow,  const float* __restrict__ eog_ob,
    const float* __restrict__ eeg_cb,  const float* __restrict__ eog_cb,
    const float* __restrict__ tl_ln1_s, const float* __restrict__ tl_ln1_b,
    const float* __restrict__ tl_ln2_s, const float* __restrict__ tl_ln2_b,
    const float* __restrict__ tl_w1,   const float* __restrict__ tl_b1,
    const float* __restrict__ tl_b2,
    const float* __restrict__ fn_s,    const float* __restrict__ fn_b,
    const float* __restrict__ cls_w,   const float* __restrict__ cls_b,
    const float* __restrict__ ws,      float* __restrict__ out)
{
    __shared__ float smem[4 * 64 * 41];
    const int t    = threadIdx.x;
    const int lane = t & 63;
    const int wid  = t >> 6;
    const int bw   = blockIdx.x * 256 + wid * 64;
    const int b    = bw + lane;
    float* sw = smem + wid * (64 * 41);

    float vbar[62];
    #pragma unroll
    for (int d = 0; d < 62; ++d) vbar[d] = eeg_inb[124 + d];

    for (int chunk = 0; chunk < 8; ++chunk) {
        const int ch0 = chunk * 8;
        for (int j = 0; j < 40; ++j) {
            int idx = j * 64 + lane;
            int r = idx / 40, cc = idx - r * 40;
            int gcol = ch0 * 5 + cc;
            float v = 0.f;
            if (gcol < 310) v = eeg[(bw + r) * 310 + gcol];
            sw[r * 41 + cc] = v;
        }
        __syncthreads();
        const int nch = (62 - ch0 < 8) ? (62 - ch0) : 8;
        for (int el = 0; el < nch; ++el) {
            const int e = ch0 + el;
            const float* xr = sw + lane * 41 + el * 5;
            float p = (xr[0] + xr[1] + xr[2] + xr[3] + xr[4]) * 0.2f;
            const float* wr = ws + WS_WVT + e * 62;
            #pragma unroll
            for (int d = 0; d < 62; ++d) vbar[d] = fmaf(p, wr[d], vbar[d]);
        }
        __syncthreads();
    }

    float h[32];
    #pragma unroll
    for (int o = 0; o < 32; ++o) h[o] = eeg_cb[o];

    for (int chunk = 0; chunk < 8; ++chunk) {
        const int ch0 = chunk * 8;
        for (int j = 0; j < 40; ++j) {
            int idx = j * 64 + lane;
            int r = idx / 40, cc = idx - r * 40;
            int gcol = ch0 * 5 + cc;
            float v = 0.f;
            if (gcol < 310) v = eeg[(bw + r) * 310 + gcol];
            sw[r * 41 + cc] = v;
        }
        __syncthreads();
        const int nch = (62 - ch0 < 8) ? (62 - ch0) : 8;
        for (int el = 0; el < nch; ++el) {
            const int c = ch0 + el;
            const float* owr = eeg_ow + c * 62;
            float oc = eeg_ob[c];
            #pragma unroll
            for (int d = 0; d < 62; ++d) oc = fmaf(owr[d], vbar[d], oc);
            const float* xr = sw + lane * 41 + el * 5;
            float x0 = xr[0], x1 = xr[1], x2 = xr[2], x3 = xr[3], x4 = xr[4];
            const float* cwr = ws + WS_CWT + c * 160;
            #pragma unroll
            for (int o = 0; o < 32; ++o) {
                float tt = x0 * cwr[o * 5 + 0];
                tt = fmaf(x1, cwr[o * 5 + 1], tt);
                tt = fmaf(x2, cwr[o * 5 + 2], tt);
                tt = fmaf(x3, cwr[o * 5 + 3], tt);
                tt = fmaf(x4, cwr[o * 5 + 4], tt);
                h[o] = fmaf(oc, tt, h[o]);
            }
        }
        __syncthreads();
    }

    #pragma unroll
    for (int o = 0; o < 32; ++o) h[o] = h[o] > 0.f ? h[o] : expm1f(h[o]);

    float feat[64];
    #pragma unroll
    for (int f = 0; f < 64; ++f) {
        float acc = ws[WS_B0 + f];
        #pragma unroll
        for (int o = 0; o < 32; ++o)
            acc = fmaf(ws[WS_A_EEG + f * 32 + o], h[o], acc);
        feat[f] = acc;
    }

    for (int j = 0; j < 33; ++j) {
        int idx = j * 64 + lane;
        int r = idx / 33, cc = idx - r * 33;
        sw[r * 34 + cc] = eog[(bw + r) * 33 + cc];
    }
    __syncthreads();
    {
        float Tg[32];
        #pragma unroll
        for (int o = 0; o < 32; ++o) Tg[o] = 0.f;
        float pool = 0.f;
        for (int l2 = 0; l2 < 33; ++l2) {
            float x = sw[lane * 34 + l2];
            pool += x;
            const float* cr = ws + WS_CWOG + l2 * 32;
            #pragma unroll
            for (int o = 0; o < 32; ++o) Tg[o] = fmaf(x, cr[o], Tg[o]);
        }
        pool *= (1.f / 33.f);
        float vb2 = fmaf(pool, eog_inw[2], eog_inb[2]);
        float ob2 = fmaf(vb2, eog_ow[0], eog_ob[0]);
        #pragma unroll
        for (int o = 0; o < 32; ++o) {
            float hh = fmaf(ob2, Tg[o], eog_cb[o]);
            Tg[o] = hh > 0.f ? hh : expm1f(hh);
        }
        #pragma unroll
        for (int f = 0; f < 64; ++f) {
            float acc = feat[f];
            #pragma unroll
            for (int o = 0; o < 32; ++o)
                acc = fmaf(ws[WS_A_EOG + f * 32 + o], Tg[o], acc);
            feat[f] = acc;
        }
    }

    for (int i2 = 0; i2 < 2; ++i2) {
        const float* Wa  = ws + WS_WATT + i2 * 4096;
        const float* ba  = ws + WS_BATT + i2 * 64;
        const float* s1  = tl_ln1_s + i2 * 64;
        const float* g1  = tl_ln1_b + i2 * 64;
        const float* s2  = tl_ln2_s + i2 * 64;
        const float* g2  = tl_ln2_b + i2 * 64;
        const float* w1p = tl_w1 + i2 * 16384;
        const float* bf1 = tl_b1 + i2 * 256;
        const float* w2t = ws + WS_W2T + i2 * 16384;
        const float* bf2 = tl_b2 + i2 * 64;

        float hb[64];
        {
            float m = 0.f;
            #pragma unroll
            for (int d = 0; d < 64; ++d) m += feat[d];
            m *= 0.015625f;
            float vv = 0.f;
            #pragma unroll
            for (int d = 0; d < 64; ++d) { float u = feat[d] - m; vv = fmaf(u, u, vv); }
            vv *= 0.015625f;
            float inv = rsqrtf(vv + 1e-5f);
            #pragma unroll
            for (int d = 0; d < 64; ++d)
                hb[d] = fmaf((feat[d] - m) * inv, s1[d], g1[d]);
        }
        #pragma unroll
        for (int c = 0; c < 64; ++c) {
            float a = ba[c];
            #pragma unroll
            for (int d = 0; d < 64; ++d) a = fmaf(Wa[c * 64 + d], hb[d], a);
            feat[c] += a;
        }
        {
            float m = 0.f;
            #pragma unroll
            for (int d = 0; d < 64; ++d) m += feat[d];
            m *= 0.015625f;
            float vv = 0.f;
            #pragma unroll
            for (int d = 0; d < 64; ++d) { float u = feat[d] - m; vv = fmaf(u, u, vv); }
            vv *= 0.015625f;
            float inv = rsqrtf(vv + 1e-5f);
            #pragma unroll
            for (int d = 0; d < 64; ++d)
                hb[d] = fmaf((feat[d] - m) * inv, s2[d], g2[d]);
        }
        #pragma unroll
        for (int c = 0; c < 64; ++c) feat[c] += bf2[c];
        for (int j = 0; j < 256; ++j) {
            const float* wr = w1p + j * 64;
            float g = bf1[j];
            #pragma unroll
            for (int d = 0; d < 64; ++d) g = fmaf(wr[d], hb[d], g);
            g = 0.5f * g * (1.f + erff(g * 0.70710678118654752f));
            const float* w2r = w2t + j * 64;
            #pragma unroll
            for (int c = 0; c < 64; ++c) feat[c] = fmaf(g, w2r[c], feat[c]);
        }
    }

    {
        float m = 0.f;
        #pragma unroll
        for (int d = 0; d < 64; ++d) m += feat[d];
        m *= 0.015625f;
        float vv = 0.f;
        #pragma unroll
        for (int d = 0; d < 64; ++d) { float u = feat[d] - m; vv = fmaf(u, u, vv); }
        vv *= 0.015625f;
        float inv = rsqrtf(vv + 1e-5f);
        float o0 = cls_b[0], o1 = cls_b[1], o2 = cls_b[2];
        #pragma unroll
        for (int d = 0; d < 64; ++d) {
            float n = fmaf((feat[d] - m) * inv, fn_s[d], fn_b[d]);
            o0 = fmaf(n, cls_w[d], o0);
            o1 = fmaf(n, cls_w[64 + d], o1);
            o2 = fmaf(n, cls_w[128 + d], o2);
        }
        float* op = out + b * 3;
        op[0] = o0; op[1] = o1; op[2] = o2;
    }
}

extern "C" void kernel_launch(void* const* d_in, const int* in_sizes, int n_in,
                              void* d_out, int out_size, void* d_ws, size_t ws_size,
                              hipStream_t stream) {
    const float* eeg      = (const float*)d_in[0];
    const float* eog      = (const float*)d_in[1];
    const float* eeg_inw  = (const float*)d_in[2];
    const float* eeg_inb  = (const float*)d_in[3];
    const float* eeg_ow   = (const float*)d_in[4];
    const float* eeg_ob   = (const float*)d_in[5];
    const float* eog_inw  = (const float*)d_in[6];
    const float* eog_inb  = (const float*)d_in[7];
    const float* eog_ow   = (const float*)d_in[8];
    const float* eog_ob   = (const float*)d_in[9];
    const float* eeg_cw   = (const float*)d_in[10];
    const float* eeg_cb   = (const float*)d_in[11];
    const float* eeg_fw   = (const float*)d_in[12];
    const float* eeg_fb   = (const float*)d_in[13];
    const float* eog_cw   = (const float*)d_in[14];
    const float* eog_cb   = (const float*)d_in[15];
    const float* eog_fw   = (const float*)d_in[16];
    const float* eog_fb   = (const float*)d_in[17];
    const float* fus_w    = (const float*)d_in[18];
    const float* fus_b    = (const float*)d_in[19];
    const float* tl_ln1_s = (const float*)d_in[20];
    const float* tl_ln1_b = (const float*)d_in[21];
    const float* tl_inw   = (const float*)d_in[22];
    const float* tl_inb   = (const float*)d_in[23];
    const float* tl_ow    = (const float*)d_in[24];
    const float* tl_ob    = (const float*)d_in[25];
    const float* tl_ln2_s = (const float*)d_in[26];
    const float* tl_ln2_b = (const float*)d_in[27];
    const float* tl_w1    = (const float*)d_in[28];
    const float* tl_b1    = (const float*)d_in[29];
    const float* tl_w2    = (const float*)d_in[30];
    const float* tl_b2    = (const float*)d_in[31];
    const float* fn_s     = (const float*)d_in[32];
    const float* fn_b     = (const float*)d_in[33];
    const float* cls_w    = (const float*)d_in[34];
    const float* cls_b    = (const float*)d_in[35];
    float* ws  = (float*)d_ws;
    float* out = (float*)d_out;

    hipLaunchKernelGGL(mcaf_pre, dim3(8), dim3(256), 0, stream,
                       eeg_inw, eeg_inb, eeg_ow, eeg_ob, eeg_cw,
                       eeg_fw, eeg_fb, eog_cw, eog_fw, eog_fb,
                       fus_w, fus_b, tl_inw, tl_inb, tl_ow, tl_ob, tl_w1, tl_w2, ws);

    const size_t need = (size_t)WS_TOTALF * 4u;
    if (ws_size >= need) {
        hipLaunchKernelGGL(eeg_tr, dim3((NB / 256) * 8), dim3(256), 0, stream, eeg, ws);
        hipLaunchKernelGGL(eog_tr, dim3(NB / 256), dim3(256), 0, stream, eog, ws);
        hipLaunchKernelGGL(mcaf_fused, dim3(NB / 256), dim3(256), 0, stream,
                           eeg_cb, eog_inw, eog_inb, eog_ow, eog_ob, eog_cb,
                           tl_ln1_s, tl_ln1_b, tl_ln2_s, tl_ln2_b,
                           tl_b1, tl_b2, fn_s, fn_b, cls_w, cls_b, ws, out);
    } else {
        hipLaunchKernelGGL(mcaf_main_fb, dim3(NB / 256), dim3(256), 0, stream,
                           eeg, eog, eeg_inb, eeg_ow, eeg_ob,
                           eog_inw, eog_inb, eog_ow, eog_ob,
                           eeg_cb, eog_cb,
                           tl_ln1_s, tl_ln1_b, tl_ln2_s, tl_ln2_b,
                           tl_w1, tl_b1, tl_b2,
                           fn_s, fn_b, cls_w, cls_b, ws, out);
    }
}

// Round 10
// 242.120 us; speedup vs baseline: 3.5863x; 1.1646x over previous
//
#include <hip/hip_runtime.h>
#include <hip/hip_bf16.h>
#include <math.h>

#define NB 131072

typedef __attribute__((ext_vector_type(2))) float f32x2;
typedef __attribute__((ext_vector_type(4))) float f32x4;
typedef __attribute__((ext_vector_type(8))) short bf16x8;

// Wave-local ordering fence for wave-private LDS (DS ops pinned, rest free).
#define SYNC() do { asm volatile("" ::: "memory"); __builtin_amdgcn_sched_barrier(0x7F); } while (0)

// ---- workspace layout (float offsets) ----
#define WS_A_EEG 0          // [64][32] f32 (fallback)
#define WS_A_EOG 2048
#define WS_B0    4096       // [64]
#define WS_WATT  4160       // [2][64][64] f32 (fallback)
#define WS_BATT  12352      // [2][64]
#define WS_WVT   12480      // [62][62] (fallback)
#define WS_M     16324      // [62][62] (fallback)
#define WS_OBB   20168      // [62]
#define WS_CWT   20232      // [62][32][5] (fallback)
#define WS_CWOG  30152      // [33][32] (fallback)
#define WS_W2T   31208      // [2][256][64] f32 (fallback)
#define WB_WA_F  64000      // bf16 [2][64][64]
#define WB_W1_F  68096      // bf16 [2][256][64]
#define WB_W2_F  84480      // bf16 [2][64][256]
#define WB_MB    100864     // bf16 [64][64]  Maug[c][e]
#define WB_CWL   102912     // bf16 [32][320] CWL[o][l*64+c]
#define WB_ACAT  108032     // bf16 [64][64]  [A_EEG | A_EOG][f][j]
#define WB_CWOG2 110080     // bf16 [32][64]  CWOG2[o][l] (l<33, pad 0)
// bf16 channel-PAIR planes: dword at plane (l*31+cp), batch b holds channels
// (2cp, 2cp+1) of timestep l.  155 planes x NB dwords.
#define WB_EEGXB 111104
#define WB_POOLB (WB_EEGXB + 155 * NB)       // bf16 [8][B][8] pooled (e62=1, e63=0)
#define WB_EOGB  (WB_POOLB + 32 * NB)        // packed bf16 pairs [17][B] dwords
#define WS_TOTALF (WB_EOGB + 17 * NB)

// per-wave LDS for fused kernel: 64 rows x 208B (13 x 16B granules; odd stride)
#define ROWB 208
#define WAVE_LDS (64 * ROWB)

__device__ __forceinline__ short f2bf(float x) {
    union { __hip_bfloat16 h; short s; } u;
    u.h = __float2bfloat16(x);
    return u.s;
}
__device__ __forceinline__ float bf2f(unsigned short s) {
    union { unsigned int u; float f; } v;
    v.u = (unsigned int)s << 16;
    return v.f;
}
// tanh-form gelu: ~11 VALU ops vs ~28 for erff-based. Max dev vs exact ~1e-3.
__device__ __forceinline__ float gelu_fast(float v) {
    float u = v * v;
    float w = v * fmaf(0.044715f, u, 1.0f);
    float x = fminf(w * 2.302118131f, 80.f);        // 2*0.79788456*log2(e); clamp: avoid inf/inf
    float e = __builtin_exp2f(x);
    float t = (e - 1.0f) * __builtin_amdgcn_rcpf(e + 1.0f);
    float hv = 0.5f * v;
    return fmaf(hv, t, hv);
}
// elu negative branch: expm1 via exp2 (predicated-safe; x<=0 -> no overflow)
__device__ __forceinline__ float elu_f(float x) {
    return x > 0.f ? x : (__builtin_exp2f(x * 1.4426950408889634f) - 1.0f);
}

__global__ __launch_bounds__(256) void mcaf_pre(
    const float* __restrict__ eeg_inw, const float* __restrict__ eeg_inb,
    const float* __restrict__ eeg_ow,  const float* __restrict__ eeg_ob,
    const float* __restrict__ eeg_cw,
    const float* __restrict__ eeg_fw,  const float* __restrict__ eeg_fb,
    const float* __restrict__ eog_cw,  const float* __restrict__ eog_fw,
    const float* __restrict__ eog_fb,
    const float* __restrict__ fus_w,   const float* __restrict__ fus_b,
    const float* __restrict__ tl_inw,  const float* __restrict__ tl_inb,
    const float* __restrict__ tl_ow,   const float* __restrict__ tl_ob,
    const float* __restrict__ tl_w1,   const float* __restrict__ tl_w2,
    float* __restrict__ ws)
{
    const int tid  = blockIdx.x * blockDim.x + threadIdx.x;
    const int nthr = gridDim.x * blockDim.x;
    short* wa_b   = (short*)(ws + WB_WA_F);
    short* w1_b   = (short*)(ws + WB_W1_F);
    short* w2_b   = (short*)(ws + WB_W2_F);
    short* mb_b   = (short*)(ws + WB_MB);
    short* cwl_b  = (short*)(ws + WB_CWL);
    short* acat_b = (short*)(ws + WB_ACAT);
    short* cwog2  = (short*)(ws + WB_CWOG2);

    for (int idx = tid; idx < 2048; idx += nthr) {
        int f = idx >> 5, o = idx & 31;
        float a = 0.f, a2 = 0.f;
        for (int k = 0; k < 64; ++k) {
            a  = fmaf(fus_w[f * 128 + k],      eeg_fw[k * 32 + o], a);
            a2 = fmaf(fus_w[f * 128 + 64 + k], eog_fw[k * 32 + o], a2);
        }
        ws[WS_A_EEG + idx] = a;
        ws[WS_A_EOG + idx] = a2;
    }
    for (int idx = tid; idx < 4096; idx += nthr) {
        int f = idx >> 6, j = idx & 63;
        float a = 0.f;
        if (j < 32) {
            for (int k = 0; k < 64; ++k)
                a = fmaf(fus_w[f * 128 + k], eeg_fw[k * 32 + j], a);
        } else {
            int o = j - 32;
            for (int k = 0; k < 64; ++k)
                a = fmaf(fus_w[f * 128 + 64 + k], eog_fw[k * 32 + o], a);
        }
        acat_b[idx] = f2bf(a);
    }
    for (int f = tid; f < 64; f += nthr) {
        float a = fus_b[f] + (float)(f & 1);
        for (int k = 0; k < 64; ++k) {
            a = fmaf(fus_w[f * 128 + k],      eeg_fb[k], a);
            a = fmaf(fus_w[f * 128 + 64 + k], eog_fb[k], a);
        }
        ws[WS_B0 + f] = a;
    }
    for (int idx = tid; idx < 8192; idx += nthr) {
        int i = idx >> 12, c = (idx >> 6) & 63, d = idx & 63;
        float a = 0.f;
        for (int e = 0; e < 64; ++e)
            a = fmaf(tl_ow[i * 4096 + c * 64 + e],
                     tl_inw[i * 12288 + (128 + e) * 64 + d], a);
        ws[WS_WATT + idx] = a;
        wa_b[idx] = f2bf(a);
    }
    for (int idx = tid; idx < 128; idx += nthr) {
        int i = idx >> 6, c = idx & 63;
        float a = tl_ob[i * 64 + c];
        for (int e = 0; e < 64; ++e)
            a = fmaf(tl_ow[i * 4096 + c * 64 + e], tl_inb[i * 192 + 128 + e], a);
        ws[WS_BATT + idx] = a;
    }
    for (int idx = tid; idx < 32768; idx += nthr) w1_b[idx] = f2bf(tl_w1[idx]);
    for (int idx = tid; idx < 32768; idx += nthr) w2_b[idx] = f2bf(tl_w2[idx]);

    for (int idx = tid; idx < 3844; idx += nthr) {
        int e = idx / 62, d = idx - e * 62;
        ws[WS_WVT + idx] = eeg_inw[(124 + d) * 62 + e];
    }
    for (int idx = tid; idx < 3844; idx += nthr) {
        int c = idx / 62, e = idx - c * 62;
        float a = 0.f;
        for (int d = 0; d < 62; ++d)
            a = fmaf(eeg_ow[c * 62 + d], eeg_inw[(124 + d) * 62 + e], a);
        ws[WS_M + idx] = a;
    }
    for (int c = tid; c < 62; c += nthr) {
        float a = eeg_ob[c];
        for (int d = 0; d < 62; ++d)
            a = fmaf(eeg_ow[c * 62 + d], eeg_inb[124 + d], a);
        ws[WS_OBB + c] = a;
    }
    for (int idx = tid; idx < 4096; idx += nthr) {
        int c = idx >> 6, e = idx & 63;
        float a = 0.f;
        if (c < 62) {
            if (e < 62) {
                for (int d = 0; d < 62; ++d)
                    a = fmaf(eeg_ow[c * 62 + d], eeg_inw[(124 + d) * 62 + e], a);
            } else if (e == 62) {
                a = eeg_ob[c];
                for (int d = 0; d < 62; ++d)
                    a = fmaf(eeg_ow[c * 62 + d], eeg_inb[124 + d], a);
            }
        }
        mb_b[idx] = f2bf(a);
    }
    for (int idx = tid; idx < 10240; idx += nthr) {
        int o = idx / 320, k = idx - o * 320;
        int l = k >> 6, c = k & 63;
        float a = (c < 62 && l < 5) ? eeg_cw[o * 310 + c * 5 + l] : 0.f;
        cwl_b[idx] = f2bf(a);
    }
    // CWOG2 bf16 [32][64]
    for (int idx = tid; idx < 2048; idx += nthr) {
        int o = idx >> 6, l = idx & 63;
        cwog2[idx] = f2bf(l < 33 ? eog_cw[o * 33 + l] : 0.f);
    }
    for (int idx = tid; idx < 9920; idx += nthr) {
        int c = idx / 160, r = idx - c * 160;
        int o = r / 5, l = r - o * 5;
        ws[WS_CWT + idx] = eeg_cw[o * 310 + c * 5 + l];
    }
    for (int idx = tid; idx < 1056; idx += nthr) {
        int l = idx >> 5, o = idx & 31;
        ws[WS_CWOG + idx] = eog_cw[o * 33 + l];
    }
    for (int idx = tid; idx < 32768; idx += nthr) {
        int i = idx >> 14, r = idx & 16383;
        int j = r >> 6, c = r & 63;
        ws[WS_W2T + idx] = tl_w2[i * 16384 + c * 256 + j];
    }
}

// ---- eeg re-layout: bf16 LDS staging, packed channel-pair output + pooled --
__global__ __launch_bounds__(256) void eeg_tr(const float* __restrict__ eeg,
                                              float* __restrict__ ws)
{
    __shared__ short smem[4 * 64 * 42];   // 21504 B
    const int lane  = threadIdx.x & 63;
    const int wid   = threadIdx.x >> 6;
    const int chunk = blockIdx.x & 7;
    const int bw    = (blockIdx.x >> 3) * 256 + wid * 64;
    const int b     = bw + lane;
    short* sw = smem + wid * (64 * 42);

    const int ch0 = chunk * 40;
    for (int j = 0; j < 20; ++j) {
        int idx = j * 64 + lane;
        int r = idx / 20, cc2 = idx - r * 20;
        int gcol = ch0 + cc2 * 2;
        unsigned int pack = 0;
        if (gcol < 310) {
            f32x2 v = *(const f32x2*)(eeg + (size_t)(bw + r) * 310 + gcol);
            pack = (unsigned int)(unsigned short)f2bf(v[0]) |
                   ((unsigned int)(unsigned short)f2bf(v[1]) << 16);
        }
        *(unsigned int*)(sw + r * 42 + cc2 * 2) = pack;
    }
    SYNC();
    const short* myrow = sw + lane * 42;
    unsigned int* planes = (unsigned int*)(ws + WB_EEGXB);
    #pragma unroll
    for (int pr = 0; pr < 4; ++pr) {
        int c0 = chunk * 8 + pr * 2;
        if (c0 < 62) {
            int cp = c0 >> 1;
            #pragma unroll
            for (int l = 0; l < 5; ++l) {
                unsigned int d = (unsigned int)(unsigned short)myrow[pr * 10 + l] |
                                 ((unsigned int)(unsigned short)myrow[pr * 10 + 5 + l] << 16);
                planes[(size_t)(l * 31 + cp) * NB + b] = d;
            }
        }
    }
    bf16x8 pv;
    #pragma unroll
    for (int el = 0; el < 8; ++el) {
        int c = chunk * 8 + el;
        float p;
        if (c < 62) {
            float s = bf2f((unsigned short)myrow[el * 5 + 0]);
            s += bf2f((unsigned short)myrow[el * 5 + 1]);
            s += bf2f((unsigned short)myrow[el * 5 + 2]);
            s += bf2f((unsigned short)myrow[el * 5 + 3]);
            s += bf2f((unsigned short)myrow[el * 5 + 4]);
            p = s * 0.2f;
        } else {
            p = (c == 62) ? 1.0f : 0.f;
        }
        pv[el] = f2bf(p);
    }
    *(bf16x8*)((short*)(ws + WB_POOLB) + ((size_t)chunk * NB + b) * 8) = pv;
}

// ---- eog transpose -> packed bf16 pair planes [17][B] dwords ----
__global__ __launch_bounds__(256) void eog_tr(const float* __restrict__ eog,
                                              float* __restrict__ ws)
{
    __shared__ float smem[4 * 64 * 34];
    const int lane = threadIdx.x & 63;
    const int wid  = threadIdx.x >> 6;
    const int bw   = blockIdx.x * 256 + wid * 64;
    float* sw = smem + wid * (64 * 34);

    for (int j = 0; j < 33; ++j) {
        int idx = j * 64 + lane;
        int r = idx / 33, cc = idx - r * 33;
        sw[r * 34 + cc] = eog[(size_t)(bw + r) * 33 + cc];
    }
    SYNC();
    unsigned int* EOGB = (unsigned int*)(ws + WB_EOGB);
    const float* xr = sw + lane * 34;
    #pragma unroll
    for (int cp = 0; cp < 16; ++cp) {
        unsigned int d = (unsigned int)(unsigned short)f2bf(xr[2 * cp]) |
                         ((unsigned int)(unsigned short)f2bf(xr[2 * cp + 1]) << 16);
        EOGB[(size_t)cp * NB + bw + lane] = d;
    }
    EOGB[(size_t)16 * NB + bw + lane] = (unsigned int)(unsigned short)f2bf(xr[32]);
}

// ============ FUSED: MFMA front-end + transformer + head ====================
__global__ __launch_bounds__(256, 2) void mcaf_fused(
    const float* __restrict__ eeg_cb,
    const float* __restrict__ eog_inw, const float* __restrict__ eog_inb,
    const float* __restrict__ eog_ow,  const float* __restrict__ eog_ob,
    const float* __restrict__ eog_cb,
    const float* __restrict__ tl_ln1_s, const float* __restrict__ tl_ln1_b,
    const float* __restrict__ tl_ln2_s, const float* __restrict__ tl_ln2_b,
    const float* __restrict__ tl_b1,   const float* __restrict__ tl_b2,
    const float* __restrict__ fn_s,    const float* __restrict__ fn_b,
    const float* __restrict__ cls_w,   const float* __restrict__ cls_b,
    const float* __restrict__ ws,      float* __restrict__ out)
{
    __shared__ char smem[4 * WAVE_LDS];
    const int tid  = threadIdx.x;
    const int lane = tid & 63;
    const int wid  = tid >> 6;
    const int b    = blockIdx.x * 256 + tid;
    char* Wv = smem + wid * WAVE_LDS;
    const int g4  = lane >> 4;
    const int r15 = lane & 15;

    const short* MB    = (const short*)(ws + WB_MB);
    const short* CWL   = (const short*)(ws + WB_CWL);
    const short* ACAT  = (const short*)(ws + WB_ACAT);
    const short* CWOG2 = (const short*)(ws + WB_CWOG2);
    const short* PB    = (const short*)(ws + WB_POOLB);
    const unsigned int* XP = (const unsigned int*)(ws + WB_EEGXB);

    // ---- phase 1: oc[64] = [pooled,1] @ Maug^T ----
    #pragma unroll
    for (int q = 0; q < 8; ++q) {
        bf16x8 v = *(const bf16x8*)(PB + ((size_t)q * NB + b) * 8);
        *(bf16x8*)(Wv + lane * ROWB + q * 16) = v;
    }
    SYNC();
    bf16x8 Ap[4][2];
    #pragma unroll
    for (int rt = 0; rt < 4; ++rt)
        #pragma unroll
        for (int kt = 0; kt < 2; ++kt)
            Ap[rt][kt] = *(const bf16x8*)(Wv + (rt * 16 + r15) * ROWB + (kt * 4 + g4) * 16);
    SYNC();
    f32x4 accO[4][4];
    #pragma unroll
    for (int rt = 0; rt < 4; ++rt)
        #pragma unroll
        for (int ct = 0; ct < 4; ++ct) accO[rt][ct] = (f32x4){0.f, 0.f, 0.f, 0.f};
    #pragma unroll
    for (int kt = 0; kt < 2; ++kt) {
        bf16x8 bb[4];
        #pragma unroll
        for (int ct = 0; ct < 4; ++ct)
            bb[ct] = *(const bf16x8*)(MB + (ct * 16 + r15) * 64 + kt * 32 + g4 * 8);
        #pragma unroll
        for (int rt = 0; rt < 4; ++rt)
            #pragma unroll
            for (int ct = 0; ct < 4; ++ct)
                accO[rt][ct] = __builtin_amdgcn_mfma_f32_16x16x32_bf16(Ap[rt][kt], bb[ct], accO[rt][ct], 0, 0, 0);
    }
    float oc[64];
    #pragma unroll
    for (int hf = 0; hf < 2; ++hf) {
        SYNC();
        #pragma unroll
        for (int ct2 = 0; ct2 < 2; ++ct2) {
            int ct = hf * 2 + ct2;
            #pragma unroll
            for (int rt = 0; rt < 4; ++rt)
                #pragma unroll
                for (int rg = 0; rg < 4; ++rg) {
                    int row = rt * 16 + g4 * 4 + rg;
                    *(float*)(Wv + row * ROWB + (ct2 * 16 + r15) * 4) = accO[rt][ct][rg];
                }
        }
        SYNC();
        #pragma unroll
        for (int j8 = 0; j8 < 8; ++j8) {
            f32x4 v = *(const f32x4*)(Wv + lane * ROWB + j8 * 16);
            #pragma unroll
            for (int e = 0; e < 4; ++e) oc[hf * 32 + j8 * 4 + e] = v[e];
        }
    }

    // ---- phase 2: h = Y @ CWL^T ; Y built on the fly from packed bf16 x ----
    f32x4 accH[4][2];
    #pragma unroll
    for (int rt = 0; rt < 4; ++rt) {
        accH[rt][0] = (f32x4){0.f, 0.f, 0.f, 0.f};
        accH[rt][1] = (f32x4){0.f, 0.f, 0.f, 0.f};
    }
    for (int l = 0; l < 5; ++l) {
        SYNC();
        #pragma unroll
        for (int jj = 0; jj < 8; ++jj) {
            bf16x8 v;
            #pragma unroll
            for (int q = 0; q < 4; ++q) {
                int cp = jj * 4 + q;
                if (cp < 31) {
                    unsigned int d = XP[(size_t)(l * 31 + cp) * NB + b];
                    v[2 * q]     = f2bf(oc[2 * cp]     * bf2f((unsigned short)(d & 0xffffu)));
                    v[2 * q + 1] = f2bf(oc[2 * cp + 1] * bf2f((unsigned short)(d >> 16)));
                } else {
                    v[2 * q] = 0; v[2 * q + 1] = 0;
                }
            }
            *(bf16x8*)(Wv + lane * ROWB + jj * 16) = v;
        }
        SYNC();
        bf16x8 a[4][2];
        #pragma unroll
        for (int rt = 0; rt < 4; ++rt)
            #pragma unroll
            for (int kt = 0; kt < 2; ++kt)
                a[rt][kt] = *(const bf16x8*)(Wv + (rt * 16 + r15) * ROWB + (kt * 4 + g4) * 16);
        SYNC();
        #pragma unroll
        for (int kt = 0; kt < 2; ++kt) {
            bf16x8 bb[2];
            #pragma unroll
            for (int ct = 0; ct < 2; ++ct)
                bb[ct] = *(const bf16x8*)(CWL + (ct * 16 + r15) * 320 + l * 64 + kt * 32 + g4 * 8);
            #pragma unroll
            for (int rt = 0; rt < 4; ++rt)
                #pragma unroll
                for (int ct = 0; ct < 2; ++ct)
                    accH[rt][ct] = __builtin_amdgcn_mfma_f32_16x16x32_bf16(a[rt][kt], bb[ct], accH[rt][ct], 0, 0, 0);
        }
    }
    float h[32];
    SYNC();
    #pragma unroll
    for (int ct2 = 0; ct2 < 2; ++ct2)
        #pragma unroll
        for (int rt = 0; rt < 4; ++rt)
            #pragma unroll
            for (int rg = 0; rg < 4; ++rg) {
                int row = rt * 16 + g4 * 4 + rg;
                *(float*)(Wv + row * ROWB + (ct2 * 16 + r15) * 4) = accH[rt][ct2][rg];
            }
    SYNC();
    #pragma unroll
    for (int j8 = 0; j8 < 8; ++j8) {
        f32x4 v = *(const f32x4*)(Wv + lane * ROWB + j8 * 16);
        #pragma unroll
        for (int e = 0; e < 4; ++e) h[j8 * 4 + e] = v[e] + eeg_cb[j8 * 4 + e];
    }
    #pragma unroll
    for (int o = 0; o < 32; ++o) h[o] = elu_f(h[o]);

    // ---- phase 3: EOG via MFMA (row = padded eog[33], B = CWOG2) ----
    float Tg[32];
    {
        const unsigned int* EOGB = (const unsigned int*)(ws + WB_EOGB);
        unsigned int ed[17];
        #pragma unroll
        for (int cp = 0; cp < 17; ++cp) ed[cp] = EOGB[(size_t)cp * NB + b];
        float pool = 0.f;
        #pragma unroll
        for (int cp = 0; cp < 16; ++cp) {
            pool += bf2f((unsigned short)(ed[cp] & 0xffffu));
            pool += bf2f((unsigned short)(ed[cp] >> 16));
        }
        pool += bf2f((unsigned short)(ed[16] & 0xffffu));
        SYNC();
        #pragma unroll
        for (int jj = 0; jj < 8; ++jj) {
            union { unsigned int u[4]; bf16x8 v; } pk;
            if (jj < 4) {
                pk.u[0] = ed[4 * jj]; pk.u[1] = ed[4 * jj + 1];
                pk.u[2] = ed[4 * jj + 2]; pk.u[3] = ed[4 * jj + 3];
            } else if (jj == 4) {
                pk.u[0] = ed[16]; pk.u[1] = 0; pk.u[2] = 0; pk.u[3] = 0;
            } else {
                pk.u[0] = 0; pk.u[1] = 0; pk.u[2] = 0; pk.u[3] = 0;
            }
            *(bf16x8*)(Wv + lane * ROWB + jj * 16) = pk.v;
        }
        SYNC();
        bf16x8 a[4][2];
        #pragma unroll
        for (int rt = 0; rt < 4; ++rt)
            #pragma unroll
            for (int kt = 0; kt < 2; ++kt)
                a[rt][kt] = *(const bf16x8*)(Wv + (rt * 16 + r15) * ROWB + (kt * 4 + g4) * 16);
        SYNC();
        f32x4 accE[4][2];
        #pragma unroll
        for (int rt = 0; rt < 4; ++rt) {
            accE[rt][0] = (f32x4){0.f, 0.f, 0.f, 0.f};
            accE[rt][1] = (f32x4){0.f, 0.f, 0.f, 0.f};
        }
        #pragma unroll
        for (int kt = 0; kt < 2; ++kt) {
            bf16x8 bb[2];
            #pragma unroll
            for (int ct = 0; ct < 2; ++ct)
                bb[ct] = *(const bf16x8*)(CWOG2 + (ct * 16 + r15) * 64 + kt * 32 + g4 * 8);
            #pragma unroll
            for (int rt = 0; rt < 4; ++rt)
                #pragma unroll
                for (int ct = 0; ct < 2; ++ct)
                    accE[rt][ct] = __builtin_amdgcn_mfma_f32_16x16x32_bf16(a[rt][kt], bb[ct], accE[rt][ct], 0, 0, 0);
        }
        SYNC();
        #pragma unroll
        for (int ct2 = 0; ct2 < 2; ++ct2)
            #pragma unroll
            for (int rt = 0; rt < 4; ++rt)
                #pragma unroll
                for (int rg = 0; rg < 4; ++rg) {
                    int row = rt * 16 + g4 * 4 + rg;
                    *(float*)(Wv + row * ROWB + (ct2 * 16 + r15) * 4) = accE[rt][ct2][rg];
                }
        SYNC();
        float tp[32];
        #pragma unroll
        for (int j8 = 0; j8 < 8; ++j8) {
            f32x4 v = *(const f32x4*)(Wv + lane * ROWB + j8 * 16);
            #pragma unroll
            for (int e = 0; e < 4; ++e) tp[j8 * 4 + e] = v[e];
        }
        pool *= (1.f / 33.f);
        float vb2 = fmaf(pool, eog_inw[2], eog_inb[2]);
        float ob2 = fmaf(vb2, eog_ow[0], eog_ob[0]);
        #pragma unroll
        for (int o = 0; o < 32; ++o)
            Tg[o] = elu_f(fmaf(ob2, tp[o], eog_cb[o]));
    }

    // ---- phase 4: feat = [h|Tg] @ ACAT^T + B0 (feat stays in registers) ----
    SYNC();
    #pragma unroll
    for (int jj = 0; jj < 8; ++jj) {
        bf16x8 v;
        #pragma unroll
        for (int e = 0; e < 8; ++e) {
            int j = jj * 8 + e;
            v[e] = f2bf(j < 32 ? h[j] : Tg[j - 32]);
        }
        *(bf16x8*)(Wv + lane * ROWB + jj * 16) = v;
    }
    SYNC();
    bf16x8 Ac[4][2];
    #pragma unroll
    for (int rt = 0; rt < 4; ++rt)
        #pragma unroll
        for (int kt = 0; kt < 2; ++kt)
            Ac[rt][kt] = *(const bf16x8*)(Wv + (rt * 16 + r15) * ROWB + (kt * 4 + g4) * 16);
    SYNC();
    f32x4 accF[4][4];
    #pragma unroll
    for (int rt = 0; rt < 4; ++rt)
        #pragma unroll
        for (int ct = 0; ct < 4; ++ct) accF[rt][ct] = (f32x4){0.f, 0.f, 0.f, 0.f};
    #pragma unroll
    for (int kt = 0; kt < 2; ++kt) {
        bf16x8 bb[4];
        #pragma unroll
        for (int ct = 0; ct < 4; ++ct)
            bb[ct] = *(const bf16x8*)(ACAT + (ct * 16 + r15) * 64 + kt * 32 + g4 * 8);
        #pragma unroll
        for (int rt = 0; rt < 4; ++rt)
            #pragma unroll
            for (int ct = 0; ct < 4; ++ct)
                accF[rt][ct] = __builtin_amdgcn_mfma_f32_16x16x32_bf16(Ac[rt][kt], bb[ct], accF[rt][ct], 0, 0, 0);
    }
    float feat[64];
    #pragma unroll
    for (int hf = 0; hf < 2; ++hf) {
        SYNC();
        #pragma unroll
        for (int ct2 = 0; ct2 < 2; ++ct2) {
            int ct = hf * 2 + ct2;
            #pragma unroll
            for (int rt = 0; rt < 4; ++rt)
                #pragma unroll
                for (int rg = 0; rg < 4; ++rg) {
                    int row = rt * 16 + g4 * 4 + rg;
                    *(float*)(Wv + row * ROWB + (ct2 * 16 + r15) * 4) = accF[rt][ct][rg];
                }
        }
        SYNC();
        #pragma unroll
        for (int j8 = 0; j8 < 8; ++j8) {
            f32x4 v = *(const f32x4*)(Wv + lane * ROWB + j8 * 16);
            #pragma unroll
            for (int e = 0; e < 4; ++e) {
                int d = hf * 32 + j8 * 4 + e;
                feat[d] = v[e] + ws[WS_B0 + d];
            }
        }
    }

    // ---- transformer (2 layers) + head ----
    const short* WAb = (const short*)(ws + WB_WA_F);
    const short* W1b = (const short*)(ws + WB_W1_F);
    const short* W2b = (const short*)(ws + WB_W2_F);

    for (int i2 = 0; i2 < 2; ++i2) {
        const float* ba  = ws + WS_BATT + i2 * 64;
        const float* s1  = tl_ln1_s + i2 * 64;
        const float* gb1 = tl_ln1_b + i2 * 64;
        const float* s2  = tl_ln2_s + i2 * 64;
        const float* gb2 = tl_ln2_b + i2 * 64;
        const float* bf1 = tl_b1 + i2 * 256;
        const float* bf2 = tl_b2 + i2 * 64;

        float hb[64];
        {
            float m = 0.f;
            #pragma unroll
            for (int d = 0; d < 64; ++d) m += feat[d];
            m *= 0.015625f;
            float vv = 0.f;
            #pragma unroll
            for (int d = 0; d < 64; ++d) { float u = feat[d] - m; vv = fmaf(u, u, vv); }
            vv *= 0.015625f;
            float inv = rsqrtf(vv + 1e-5f);
            #pragma unroll
            for (int d = 0; d < 64; ++d)
                hb[d] = fmaf((feat[d] - m) * inv, s1[d], gb1[d]);
        }
        SYNC();
        #pragma unroll
        for (int jj = 0; jj < 8; ++jj) {
            bf16x8 v;
            #pragma unroll
            for (int e = 0; e < 8; ++e) v[e] = f2bf(hb[jj * 8 + e]);
            *(bf16x8*)(Wv + lane * ROWB + jj * 16) = v;
        }
        SYNC();
        bf16x8 Aat[4][2];
        #pragma unroll
        for (int rt = 0; rt < 4; ++rt)
            #pragma unroll
            for (int kt = 0; kt < 2; ++kt)
                Aat[rt][kt] = *(const bf16x8*)(Wv + (rt * 16 + r15) * ROWB + (kt * 4 + g4) * 16);
        SYNC();
        f32x4 acc[4][4];
        #pragma unroll
        for (int rt = 0; rt < 4; ++rt)
            #pragma unroll
            for (int ct = 0; ct < 4; ++ct) acc[rt][ct] = (f32x4){0.f, 0.f, 0.f, 0.f};
        #pragma unroll
        for (int kt = 0; kt < 2; ++kt) {
            bf16x8 bb[4];
            #pragma unroll
            for (int ct = 0; ct < 4; ++ct)
                bb[ct] = *(const bf16x8*)(WAb + i2 * 4096 + (ct * 16 + r15) * 64 + kt * 32 + g4 * 8);
            #pragma unroll
            for (int rt = 0; rt < 4; ++rt)
                #pragma unroll
                for (int ct = 0; ct < 4; ++ct)
                    acc[rt][ct] = __builtin_amdgcn_mfma_f32_16x16x32_bf16(Aat[rt][kt], bb[ct], acc[rt][ct], 0, 0, 0);
        }
        #pragma unroll
        for (int hf = 0; hf < 2; ++hf) {
            SYNC();
            #pragma unroll
            for (int ct2 = 0; ct2 < 2; ++ct2) {
                int ct = hf * 2 + ct2;
                #pragma unroll
                for (int rt = 0; rt < 4; ++rt)
                    #pragma unroll
                    for (int rg = 0; rg < 4; ++rg) {
                        int row = rt * 16 + g4 * 4 + rg;
                        *(float*)(Wv + row * ROWB + (ct2 * 16 + r15) * 4) = acc[rt][ct][rg];
                    }
            }
            SYNC();
            #pragma unroll
            for (int j8 = 0; j8 < 8; ++j8) {
                f32x4 v = *(const f32x4*)(Wv + lane * ROWB + j8 * 16);
                #pragma unroll
                for (int e = 0; e < 4; ++e) {
                    int d = hf * 32 + j8 * 4 + e;
                    feat[d] += v[e] + ba[d];
                }
            }
        }
        {
            float m = 0.f;
            #pragma unroll
            for (int d = 0; d < 64; ++d) m += feat[d];
            m *= 0.015625f;
            float vv = 0.f;
            #pragma unroll
            for (int d = 0; d < 64; ++d) { float u = feat[d] - m; vv = fmaf(u, u, vv); }
            vv *= 0.015625f;
            float inv = rsqrtf(vv + 1e-5f);
            #pragma unroll
            for (int d = 0; d < 64; ++d)
                hb[d] = fmaf((feat[d] - m) * inv, s2[d], gb2[d]);
        }
        SYNC();
        #pragma unroll
        for (int jj = 0; jj < 8; ++jj) {
            bf16x8 v;
            #pragma unroll
            for (int e = 0; e < 8; ++e) v[e] = f2bf(hb[jj * 8 + e]);
            *(bf16x8*)(Wv + lane * ROWB + jj * 16) = v;
        }
        SYNC();
        f32x4 F[4][4];
        #pragma unroll
        for (int rt = 0; rt < 4; ++rt)
            #pragma unroll
            for (int ct = 0; ct < 4; ++ct) F[rt][ct] = (f32x4){0.f, 0.f, 0.f, 0.f};

        for (int ch = 0; ch < 8; ++ch) {
            f32x4 G[4][2];
            #pragma unroll
            for (int rt = 0; rt < 4; ++rt) {
                G[rt][0] = (f32x4){0.f, 0.f, 0.f, 0.f};
                G[rt][1] = (f32x4){0.f, 0.f, 0.f, 0.f};
            }
            #pragma unroll
            for (int kt = 0; kt < 2; ++kt) {
                bf16x8 a1[4];
                #pragma unroll
                for (int rt = 0; rt < 4; ++rt)
                    a1[rt] = *(const bf16x8*)(Wv + (rt * 16 + r15) * ROWB + (kt * 4 + g4) * 16);
                bf16x8 b1[2];
                #pragma unroll
                for (int cc = 0; cc < 2; ++cc)
                    b1[cc] = *(const bf16x8*)(W1b + i2 * 16384 + (ch * 32 + cc * 16 + r15) * 64 + kt * 32 + g4 * 8);
                #pragma unroll
                for (int rt = 0; rt < 4; ++rt)
                    #pragma unroll
                    for (int cc = 0; cc < 2; ++cc)
                        G[rt][cc] = __builtin_amdgcn_mfma_f32_16x16x32_bf16(a1[rt], b1[cc], G[rt][cc], 0, 0, 0);
            }
            SYNC();
            #pragma unroll
            for (int rt = 0; rt < 4; ++rt)
                #pragma unroll
                for (int cc = 0; cc < 2; ++cc) {
                    float bj = bf1[ch * 32 + cc * 16 + r15];
                    #pragma unroll
                    for (int rg = 0; rg < 4; ++rg) {
                        float v = gelu_fast(G[rt][cc][rg] + bj);
                        int row = rt * 16 + g4 * 4 + rg;
                        int col = cc * 16 + r15;
                        *(short*)(Wv + row * ROWB + 128 + ((col >> 3) << 4) + ((col & 7) << 1)) = f2bf(v);
                    }
                }
            SYNC();
            bf16x8 a2[4], b2[4];
            #pragma unroll
            for (int rt = 0; rt < 4; ++rt)
                a2[rt] = *(const bf16x8*)(Wv + (rt * 16 + r15) * ROWB + 128 + g4 * 16);
            #pragma unroll
            for (int ct = 0; ct < 4; ++ct)
                b2[ct] = *(const bf16x8*)(W2b + i2 * 16384 + (ct * 16 + r15) * 256 + ch * 32 + g4 * 8);
            #pragma unroll
            for (int rt = 0; rt < 4; ++rt)
                #pragma unroll
                for (int ct = 0; ct < 4; ++ct)
                    F[rt][ct] = __builtin_amdgcn_mfma_f32_16x16x32_bf16(a2[rt], b2[ct], F[rt][ct], 0, 0, 0);
            SYNC();
        }
        #pragma unroll
        for (int hf = 0; hf < 2; ++hf) {
            SYNC();
            #pragma unroll
            for (int ct2 = 0; ct2 < 2; ++ct2) {
                int ct = hf * 2 + ct2;
                #pragma unroll
                for (int rt = 0; rt < 4; ++rt)
                    #pragma unroll
                    for (int rg = 0; rg < 4; ++rg) {
                        int row = rt * 16 + g4 * 4 + rg;
                        *(float*)(Wv + row * ROWB + (ct2 * 16 + r15) * 4) = F[rt][ct][rg];
                    }
            }
            SYNC();
            #pragma unroll
            for (int j8 = 0; j8 < 8; ++j8) {
                f32x4 v = *(const f32x4*)(Wv + lane * ROWB + j8 * 16);
                #pragma unroll
                for (int e = 0; e < 4; ++e) {
                    int d = hf * 32 + j8 * 4 + e;
                    feat[d] += v[e] + bf2[d];
                }
            }
        }
        SYNC();
    }

    {
        float m = 0.f;
        #pragma unroll
        for (int d = 0; d < 64; ++d) m += feat[d];
        m *= 0.015625f;
        float vv = 0.f;
        #pragma unroll
        for (int d = 0; d < 64; ++d) { float u = feat[d] - m; vv = fmaf(u, u, vv); }
        vv *= 0.015625f;
        float inv = rsqrtf(vv + 1e-5f);
        float o0 = cls_b[0], o1 = cls_b[1], o2 = cls_b[2];
        #pragma unroll
        for (int d = 0; d < 64; ++d) {
            float n = fmaf((feat[d] - m) * inv, fn_s[d], fn_b[d]);
            o0 = fmaf(n, cls_w[d], o0);
            o1 = fmaf(n, cls_w[64 + d], o1);
            o2 = fmaf(n, cls_w[128 + d], o2);
        }
        float* op = out + (size_t)b * 3;
        op[0] = o0; op[1] = o1; op[2] = o2;
    }
}

// ================= fallback main kernel (fp32, LDS staging) =================
__global__ __launch_bounds__(256, 2) void mcaf_main_fb(
    const float* __restrict__ eeg,     const float* __restrict__ eog,
    const float* __restrict__ eeg_inb,
    const float* __restrict__ eeg_ow,  const float* __restrict__ eeg_ob,
    const float* __restrict__ eog_inw, const float* __restrict__ eog_inb,
    const float* __restrict__ eog_ow,  const float* __restrict__ eog_ob,
    const float* __restrict__ eeg_cb,  const float* __restrict__ eog_cb,
    const float* __restrict__ tl_ln1_s, const float* __restrict__ tl_ln1_b,
    const float* __restrict__ tl_ln2_s, const float* __restrict__ tl_ln2_b,
    const float* __restrict__ tl_w1,   const float* __restrict__ tl_b1,
    const float* __restrict__ tl_b2,
    const float* __restrict__ fn_s,    const float* __restrict__ fn_b,
    const float* __restrict__ cls_w,   const float* __restrict__ cls_b,
    const float* __restrict__ ws,      float* __restrict__ out)
{
    __shared__ float smem[4 * 64 * 41];
    const int t    = threadIdx.x;
    const int lane = t & 63;
    const int wid  = t >> 6;
    const int bw   = blockIdx.x * 256 + wid * 64;
    const int b    = bw + lane;
    float* sw = smem + wid * (64 * 41);

    float vbar[62];
    #pragma unroll
    for (int d = 0; d < 62; ++d) vbar[d] = eeg_inb[124 + d];

    for (int chunk = 0; chunk < 8; ++chunk) {
        const int ch0 = chunk * 8;
        for (int j = 0; j < 40; ++j) {
            int idx = j * 64 + lane;
            int r = idx / 40, cc = idx - r * 40;
            int gcol = ch0 * 5 + cc;
            float v = 0.f;
            if (gcol < 310) v = eeg[(bw + r) * 310 + gcol];
            sw[r * 41 + cc] = v;
        }
        __syncthreads();
        const int nch = (62 - ch0 < 8) ? (62 - ch0) : 8;
        for (int el = 0; el < nch; ++el) {
            const int e = ch0 + el;
            const float* xr = sw + lane * 41 + el * 5;
            float p = (xr[0] + xr[1] + xr[2] + xr[3] + xr[4]) * 0.2f;
            const float* wr = ws + WS_WVT + e * 62;
            #pragma unroll
            for (int d = 0; d < 62; ++d) vbar[d] = fmaf(p, wr[d], vbar[d]);
        }
        __syncthreads();
    }

    float h[32];
    #pragma unroll
    for (int o = 0; o < 32; ++o) h[o] = eeg_cb[o];

    for (int chunk = 0; chunk < 8; ++chunk) {
        const int ch0 = chunk * 8;
        for (int j = 0; j < 40; ++j) {
            int idx = j * 64 + lane;
            int r = idx / 40, cc = idx - r * 40;
            int gcol = ch0 * 5 + cc;
            float v = 0.f;
            if (gcol < 310) v = eeg[(bw + r) * 310 + gcol];
            sw[r * 41 + cc] = v;
        }
        __syncthreads();
        const int nch = (62 - ch0 < 8) ? (62 - ch0) : 8;
        for (int el = 0; el < nch; ++el) {
            const int c = ch0 + el;
            const float* owr = eeg_ow + c * 62;
            float oc = eeg_ob[c];
            #pragma unroll
            for (int d = 0; d < 62; ++d) oc = fmaf(owr[d], vbar[d], oc);
            const float* xr = sw + lane * 41 + el * 5;
            float x0 = xr[0], x1 = xr[1], x2 = xr[2], x3 = xr[3], x4 = xr[4];
            const float* cwr = ws + WS_CWT + c * 160;
            #pragma unroll
            for (int o = 0; o < 32; ++o) {
                float tt = x0 * cwr[o * 5 + 0];
                tt = fmaf(x1, cwr[o * 5 + 1], tt);
                tt = fmaf(x2, cwr[o * 5 + 2], tt);
                tt = fmaf(x3, cwr[o * 5 + 3], tt);
                tt = fmaf(x4, cwr[o * 5 + 4], tt);
                h[o] = fmaf(oc, tt, h[o]);
            }
        }
        __syncthreads();
    }

    #pragma unroll
    for (int o = 0; o < 32; ++o) h[o] = h[o] > 0.f ? h[o] : expm1f(h[o]);

    float feat[64];
    #pragma unroll
    for (int f = 0; f < 64; ++f) {
        float acc = ws[WS_B0 + f];
        #pragma unroll
        for (int o = 0; o < 32; ++o)
            acc = fmaf(ws[WS_A_EEG + f * 32 + o], h[o], acc);
        feat[f] = acc;
    }

    for (int j = 0; j < 33; ++j) {
        int idx = j * 64 + lane;
        int r = idx / 33, cc = idx - r * 33;
        sw[r * 34 + cc] = eog[(bw + r) * 33 + cc];
    }
    __syncthreads();
    {
        float Tg[32];
        #pragma unroll
        for (int o = 0; o < 32; ++o) Tg[o] = 0.f;
        float pool = 0.f;
        for (int l2 = 0; l2 < 33; ++l2) {
            float x = sw[lane * 34 + l2];
            pool += x;
            const float* cr = ws + WS_CWOG + l2 * 32;
            #pragma unroll
            for (int o = 0; o < 32; ++o) Tg[o] = fmaf(x, cr[o], Tg[o]);
        }
        pool *= (1.f / 33.f);
        float vb2 = fmaf(pool, eog_inw[2], eog_inb[2]);
        float ob2 = fmaf(vb2, eog_ow[0], eog_ob[0]);
        #pragma unroll
        for (int o = 0; o < 32; ++o) {
            float hh = fmaf(ob2, Tg[o], eog_cb[o]);
            Tg[o] = hh > 0.f ? hh : expm1f(hh);
        }
        #pragma unroll
        for (int f = 0; f < 64; ++f) {
            float acc = feat[f];
            #pragma unroll
            for (int o = 0; o < 32; ++o)
                acc = fmaf(ws[WS_A_EOG + f * 32 + o], Tg[o], acc);
            feat[f] = acc;
        }
    }

    for (int i2 = 0; i2 < 2; ++i2) {
        const float* Wa  = ws + WS_WATT + i2 * 4096;
        const float* ba  = ws + WS_BATT + i2 * 64;
        const float* s1  = tl_ln1_s + i2 * 64;
        const float* g1  = tl_ln1_b + i2 * 64;
        const float* s2  = tl_ln2_s + i2 * 64;
        const float* g2  = tl_ln2_b + i2 * 64;
        const float* w1p = tl_w1 + i2 * 16384;
        const float* bf1 = tl_b1 + i2 * 256;
        const float* w2t = ws + WS_W2T + i2 * 16384;
        const float* bf2 = tl_b2 + i2 * 64;

        float hb[64];
        {
            float m = 0.f;
            #pragma unroll
            for (int d = 0; d < 64; ++d) m += feat[d];
            m *= 0.015625f;
            float vv = 0.f;
            #pragma unroll
            for (int d = 0; d < 64; ++d) { float u = feat[d] - m; vv = fmaf(u, u, vv); }
            vv *= 0.015625f;
            float inv = rsqrtf(vv + 1e-5f);
            #pragma unroll
            for (int d = 0; d < 64; ++d)
                hb[d] = fmaf((feat[d] - m) * inv, s1[d], g1[d]);
        }
        #pragma unroll
        for (int c = 0; c < 64; ++c) {
            float a = ba[c];
            #pragma unroll
            for (int d = 0; d < 64; ++d) a = fmaf(Wa[c * 64 + d], hb[d], a);
            feat[c] += a;
        }
        {
            float m = 0.f;
            #pragma unroll
            for (int d = 0; d < 64; ++d) m += feat[d];
            m *= 0.015625f;
            float vv = 0.f;
            #pragma unroll
            for (int d = 0; d < 64; ++d) { float u = feat[d] - m; vv = fmaf(u, u, vv); }
            vv *= 0.015625f;
            float inv = rsqrtf(vv + 1e-5f);
            #pragma unroll
            for (int d = 0; d < 64; ++d)
                hb[d] = fmaf((feat[d] - m) * inv, s2[d], g2[d]);
        }
        #pragma unroll
        for (int c = 0; c < 64; ++c) feat[c] += bf2[c];
        for (int j = 0; j < 256; ++j) {
            const float* wr = w1p + j * 64;
            float g = bf1[j];
            #pragma unroll
            for (int d = 0; d < 64; ++d) g = fmaf(wr[d], hb[d], g);
            g = 0.5f * g * (1.f + erff(g * 0.70710678118654752f));
            const float* w2r = w2t + j * 64;
            #pragma unroll
            for (int c = 0; c < 64; ++c) feat[c] = fmaf(g, w2r[c], feat[c]);
        }
    }

    {
        float m = 0.f;
        #pragma unroll
        for (int d = 0; d < 64; ++d) m += feat[d];
        m *= 0.015625f;
        float vv = 0.f;
        #pragma unroll
        for (int d = 0; d < 64; ++d) { float u = feat[d] - m; vv = fmaf(u, u, vv); }
        vv *= 0.015625f;
        float inv = rsqrtf(vv + 1e-5f);
        float o0 = cls_b[0], o1 = cls_b[1], o2 = cls_b[2];
        #pragma unroll
        for (int d = 0; d < 64; ++d) {
            float n = fmaf((feat[d] - m) * inv, fn_s[d], fn_b[d]);
            o0 = fmaf(n, cls_w[d], o0);
            o1 = fmaf(n, cls_w[64 + d], o1);
            o2 = fmaf(n, cls_w[128 + d], o2);
        }
        float* op = out + b * 3;
        op[0] = o0; op[1] = o1; op[2] = o2;
    }
}

extern "C" void kernel_launch(void* const* d_in, const int* in_sizes, int n_in,
                              void* d_out, int out_size, void* d_ws, size_t ws_size,
                              hipStream_t stream) {
    const float* eeg      = (const float*)d_in[0];
    const float* eog      = (const float*)d_in[1];
    const float* eeg_inw  = (const float*)d_in[2];
    const float* eeg_inb  = (const float*)d_in[3];
    const float* eeg_ow   = (const float*)d_in[4];
    const float* eeg_ob   = (const float*)d_in[5];
    const float* eog_inw  = (const float*)d_in[6];
    const float* eog_inb  = (const float*)d_in[7];
    const float* eog_ow   = (const float*)d_in[8];
    const float* eog_ob   = (const float*)d_in[9];
    const float* eeg_cw   = (const float*)d_in[10];
    const float* eeg_cb   = (const float*)d_in[11];
    const float* eeg_fw   = (const float*)d_in[12];
    const float* eeg_fb   = (const float*)d_in[13];
    const float* eog_cw   = (const float*)d_in[14];
    const float* eog_cb   = (const float*)d_in[15];
    const float* eog_fw   = (const float*)d_in[16];
    const float* eog_fb   = (const float*)d_in[17];
    const float* fus_w    = (const float*)d_in[18];
    const float* fus_b    = (const float*)d_in[19];
    const float* tl_ln1_s = (const float*)d_in[20];
    const float* tl_ln1_b = (const float*)d_in[21];
    const float* tl_inw   = (const float*)d_in[22];
    const float* tl_inb   = (const float*)d_in[23];
    const float* tl_ow    = (const float*)d_in[24];
    const float* tl_ob    = (const float*)d_in[25];
    const float* tl_ln2_s = (const float*)d_in[26];
    const float* tl_ln2_b = (const float*)d_in[27];
    const float* tl_w1    = (const float*)d_in[28];
    const float* tl_b1    = (const float*)d_in[29];
    const float* tl_w2    = (const float*)d_in[30];
    const float* tl_b2    = (const float*)d_in[31];
    const float* fn_s     = (const float*)d_in[32];
    const float* fn_b     = (const float*)d_in[33];
    const float* cls_w    = (const float*)d_in[34];
    const float* cls_b    = (const float*)d_in[35];
    float* ws  = (float*)d_ws;
    float* out = (float*)d_out;

    hipLaunchKernelGGL(mcaf_pre, dim3(8), dim3(256), 0, stream,
                       eeg_inw, eeg_inb, eeg_ow, eeg_ob, eeg_cw,
                       eeg_fw, eeg_fb, eog_cw, eog_fw, eog_fb,
                       fus_w, fus_b, tl_inw, tl_inb, tl_ow, tl_ob, tl_w1, tl_w2, ws);

    const size_t need = (size_t)WS_TOTALF * 4u;
    if (ws_size >= need) {
        hipLaunchKernelGGL(eeg_tr, dim3((NB / 256) * 8), dim3(256), 0, stream, eeg, ws);
        hipLaunchKernelGGL(eog_tr, dim3(NB / 256), dim3(256), 0, stream, eog, ws);
        hipLaunchKernelGGL(mcaf_fused, dim3(NB / 256), dim3(256), 0, stream,
                           eeg_cb, eog_inw, eog_inb, eog_ow, eog_ob, eog_cb,
                           tl_ln1_s, tl_ln1_b, tl_ln2_s, tl_ln2_b,
                           tl_b1, tl_b2, fn_s, fn_b, cls_w, cls_b, ws, out);
    } else {
        hipLaunchKernelGGL(mcaf_main_fb, dim3(NB / 256), dim3(256), 0, stream,
                           eeg, eog, eeg_inb, eeg_ow, eeg_ob,
                           eog_inw, eog_inb, eog_ow, eog_ob,
                           eeg_cb, eog_cb,
                           tl_ln1_s, tl_ln1_b, tl_ln2_s, tl_ln2_b,
                           tl_w1, tl_b1, tl_b2,
                           fn_s, fn_b, cls_w, cls_b, ws, out);
    }
}

// Round 12
// 227.831 us; speedup vs baseline: 3.8112x; 1.0627x over previous
//
#include <hip/hip_runtime.h>
#include <hip/hip_bf16.h>
#include <math.h>

#define NB 131072

typedef __attribute__((ext_vector_type(2))) float f32x2;
typedef __attribute__((ext_vector_type(4))) float f32x4;
typedef __attribute__((ext_vector_type(8))) short bf16x8;
typedef __attribute__((ext_vector_type(4))) short s16x4;

// Wave-local ordering fence for wave-private LDS (DS ops pinned, rest free).
#define SYNC() do { asm volatile("" ::: "memory"); __builtin_amdgcn_sched_barrier(0x7F); } while (0)

// ---- workspace layout (float offsets) ----
#define WS_A_EEG 0          // [64][32] f32 (fallback)
#define WS_A_EOG 2048
#define WS_B0    4096       // [64]
#define WS_WATT  4160       // [2][64][64] f32 (fallback)
#define WS_BATT  12352      // [2][64]
#define WS_WVT   12480      // [62][62] (fallback)
#define WS_M     16324      // [62][62] (fallback)
#define WS_OBB   20168      // [62] (fallback)
#define WS_CWT   20232      // [62][32][5] (fallback)
#define WS_CWOG  30152      // [33][32] (fallback)
#define WS_W2T   31208      // [2][256][64] f32 (fallback)
#define WB_WA_F  64000      // bf16 [2][64][64]
#define WB_W1_F  68096      // bf16 [2][256][64]
#define WB_W2_F  84480      // bf16 [2][64][256]
#define WB_MB    100864     // bf16 [64][64]  Maug[c][e]
#define WB_CWL   102912     // bf16 [32][320] CWL[o][l*64+c]
#define WB_ACAT  108032     // bf16 [64][64]  [A_EEG | A_EOG][f][j]
#define WB_CWOG2 110080     // bf16 [32][64]  CWOG2[o][l] (l<33, pad 0)
#define WB_EEGXB 111104     // packed bf16 pairs: dword plane (l*31+cp) x NB
#define WB_POOLB (WB_EEGXB + 155 * NB)       // bf16 [8][B][8] pooled (e62=1, e63=0)
#define WB_EOGB  (WB_POOLB + 32 * NB)        // packed bf16 pairs [17][B] dwords
#define WS_TOTALF (WB_EOGB + 17 * NB)

// per-wave LDS for fused kernel: 64 rows x 208B (13 x 16B granules; odd stride)
#define ROWB 208
#define WAVE_LDS (64 * ROWB)

__device__ __forceinline__ short f2bf(float x) {
    union { __hip_bfloat16 h; short s; } u;
    u.h = __float2bfloat16(x);
    return u.s;
}
__device__ __forceinline__ float bf2f(unsigned short s) {
    union { unsigned int u; float f; } v;
    v.u = (unsigned int)s << 16;
    return v.f;
}
// tanh-form gelu: ~11 VALU ops vs ~28 for erff-based. Max dev vs exact ~1e-3.
__device__ __forceinline__ float gelu_fast(float v) {
    float u = v * v;
    float w = v * fmaf(0.044715f, u, 1.0f);
    float x = fminf(w * 2.302118131f, 80.f);
    float e = __builtin_exp2f(x);
    float t = (e - 1.0f) * __builtin_amdgcn_rcpf(e + 1.0f);
    float hv = 0.5f * v;
    return fmaf(hv, t, hv);
}
__device__ __forceinline__ float elu_f(float x) {
    return x > 0.f ? x : (__builtin_exp2f(x * 1.4426950408889634f) - 1.0f);
}

__global__ __launch_bounds__(256) void mcaf_pre(
    const float* __restrict__ eeg_inw, const float* __restrict__ eeg_inb,
    const float* __restrict__ eeg_ow,  const float* __restrict__ eeg_ob,
    const float* __restrict__ eeg_cw,
    const float* __restrict__ eeg_fw,  const float* __restrict__ eeg_fb,
    const float* __restrict__ eog_cw,  const float* __restrict__ eog_fw,
    const float* __restrict__ eog_fb,
    const float* __restrict__ fus_w,   const float* __restrict__ fus_b,
    const float* __restrict__ tl_inw,  const float* __restrict__ tl_inb,
    const float* __restrict__ tl_ow,   const float* __restrict__ tl_ob,
    const float* __restrict__ tl_w1,   const float* __restrict__ tl_w2,
    float* __restrict__ ws, int full)
{
    const int tid  = blockIdx.x * blockDim.x + threadIdx.x;
    const int nthr = gridDim.x * blockDim.x;
    short* wa_b   = (short*)(ws + WB_WA_F);
    short* w1_b   = (short*)(ws + WB_W1_F);
    short* w2_b   = (short*)(ws + WB_W2_F);
    short* mb_b   = (short*)(ws + WB_MB);
    short* cwl_b  = (short*)(ws + WB_CWL);
    short* acat_b = (short*)(ws + WB_ACAT);
    short* cwog2  = (short*)(ws + WB_CWOG2);

    for (int idx = tid; idx < 4096; idx += nthr) {
        int f = idx >> 6, j = idx & 63;
        float a = 0.f;
        if (j < 32) {
            for (int k = 0; k < 64; ++k)
                a = fmaf(fus_w[f * 128 + k], eeg_fw[k * 32 + j], a);
        } else {
            int o = j - 32;
            for (int k = 0; k < 64; ++k)
                a = fmaf(fus_w[f * 128 + 64 + k], eog_fw[k * 32 + o], a);
        }
        acat_b[idx] = f2bf(a);
    }
    for (int f = tid; f < 64; f += nthr) {
        float a = fus_b[f] + (float)(f & 1);
        for (int k = 0; k < 64; ++k) {
            a = fmaf(fus_w[f * 128 + k],      eeg_fb[k], a);
            a = fmaf(fus_w[f * 128 + 64 + k], eog_fb[k], a);
        }
        ws[WS_B0 + f] = a;
    }
    for (int idx = tid; idx < 8192; idx += nthr) {
        int i = idx >> 12, c = (idx >> 6) & 63, d = idx & 63;
        float a = 0.f;
        for (int e = 0; e < 64; ++e)
            a = fmaf(tl_ow[i * 4096 + c * 64 + e],
                     tl_inw[i * 12288 + (128 + e) * 64 + d], a);
        if (!full) ws[WS_WATT + idx] = a;
        wa_b[idx] = f2bf(a);
    }
    for (int idx = tid; idx < 128; idx += nthr) {
        int i = idx >> 6, c = idx & 63;
        float a = tl_ob[i * 64 + c];
        for (int e = 0; e < 64; ++e)
            a = fmaf(tl_ow[i * 4096 + c * 64 + e], tl_inb[i * 192 + 128 + e], a);
        ws[WS_BATT + idx] = a;
    }
    for (int idx = tid; idx < 32768; idx += nthr) w1_b[idx] = f2bf(tl_w1[idx]);
    for (int idx = tid; idx < 32768; idx += nthr) w2_b[idx] = f2bf(tl_w2[idx]);

    for (int idx = tid; idx < 4096; idx += nthr) {
        int c = idx >> 6, e = idx & 63;
        float a = 0.f;
        if (c < 62) {
            if (e < 62) {
                for (int d = 0; d < 62; ++d)
                    a = fmaf(eeg_ow[c * 62 + d], eeg_inw[(124 + d) * 62 + e], a);
            } else if (e == 62) {
                a = eeg_ob[c];
                for (int d = 0; d < 62; ++d)
                    a = fmaf(eeg_ow[c * 62 + d], eeg_inb[124 + d], a);
            }
        }
        mb_b[idx] = f2bf(a);
    }
    for (int idx = tid; idx < 10240; idx += nthr) {
        int o = idx / 320, k = idx - o * 320;
        int l = k >> 6, c = k & 63;
        float a = (c < 62 && l < 5) ? eeg_cw[o * 310 + c * 5 + l] : 0.f;
        cwl_b[idx] = f2bf(a);
    }
    for (int idx = tid; idx < 2048; idx += nthr) {
        int o = idx >> 6, l = idx & 63;
        cwog2[idx] = f2bf(l < 33 ? eog_cw[o * 33 + l] : 0.f);
    }

    if (!full) {
        for (int idx = tid; idx < 2048; idx += nthr) {
            int f = idx >> 5, o = idx & 31;
            float a = 0.f, a2 = 0.f;
            for (int k = 0; k < 64; ++k) {
                a  = fmaf(fus_w[f * 128 + k],      eeg_fw[k * 32 + o], a);
                a2 = fmaf(fus_w[f * 128 + 64 + k], eog_fw[k * 32 + o], a2);
            }
            ws[WS_A_EEG + idx] = a;
            ws[WS_A_EOG + idx] = a2;
        }
        for (int idx = tid; idx < 3844; idx += nthr) {
            int e = idx / 62, d = idx - e * 62;
            ws[WS_WVT + idx] = eeg_inw[(124 + d) * 62 + e];
        }
        for (int idx = tid; idx < 3844; idx += nthr) {
            int c = idx / 62, e = idx - c * 62;
            float a = 0.f;
            for (int d = 0; d < 62; ++d)
                a = fmaf(eeg_ow[c * 62 + d], eeg_inw[(124 + d) * 62 + e], a);
            ws[WS_M + idx] = a;
        }
        for (int c = tid; c < 62; c += nthr) {
            float a = eeg_ob[c];
            for (int d = 0; d < 62; ++d)
                a = fmaf(eeg_ow[c * 62 + d], eeg_inb[124 + d], a);
            ws[WS_OBB + c] = a;
        }
        for (int idx = tid; idx < 9920; idx += nthr) {
            int c = idx / 160, r = idx - c * 160;
            int o = r / 5, l = r - o * 5;
            ws[WS_CWT + idx] = eeg_cw[o * 310 + c * 5 + l];
        }
        for (int idx = tid; idx < 1056; idx += nthr) {
            int l = idx >> 5, o = idx & 31;
            ws[WS_CWOG + idx] = eog_cw[o * 33 + l];
        }
        for (int idx = tid; idx < 32768; idx += nthr) {
            int i = idx >> 14, r = idx & 16383;
            int j = r >> 6, c = r & 63;
            ws[WS_W2T + idx] = tl_w2[i * 16384 + c * 256 + j];
        }
    }
}

// ---- eeg re-layout: bf16 LDS staging, packed channel-pair output + pooled --
__global__ __launch_bounds__(256) void eeg_tr(const float* __restrict__ eeg,
                                              float* __restrict__ ws)
{
    __shared__ short smem[4 * 64 * 42];   // 21504 B
    const int lane  = threadIdx.x & 63;
    const int wid   = threadIdx.x >> 6;
    const int chunk = blockIdx.x & 7;
    const int bw    = (blockIdx.x >> 3) * 256 + wid * 64;
    const int b     = bw + lane;
    short* sw = smem + wid * (64 * 42);

    const int ch0 = chunk * 40;
    for (int j = 0; j < 20; ++j) {
        int idx = j * 64 + lane;
        int r = idx / 20, cc2 = idx - r * 20;
        int gcol = ch0 + cc2 * 2;
        unsigned int pack = 0;
        if (gcol < 310) {
            f32x2 v = *(const f32x2*)(eeg + (size_t)(bw + r) * 310 + gcol);
            pack = (unsigned int)(unsigned short)f2bf(v[0]) |
                   ((unsigned int)(unsigned short)f2bf(v[1]) << 16);
        }
        *(unsigned int*)(sw + r * 42 + cc2 * 2) = pack;
    }
    SYNC();
    const short* myrow = sw + lane * 42;
    unsigned int* planes = (unsigned int*)(ws + WB_EEGXB);
    #pragma unroll
    for (int pr = 0; pr < 4; ++pr) {
        int c0 = chunk * 8 + pr * 2;
        if (c0 < 62) {
            int cp = c0 >> 1;
            #pragma unroll
            for (int l = 0; l < 5; ++l) {
                unsigned int d = (unsigned int)(unsigned short)myrow[pr * 10 + l] |
                                 ((unsigned int)(unsigned short)myrow[pr * 10 + 5 + l] << 16);
                planes[(size_t)(l * 31 + cp) * NB + b] = d;
            }
        }
    }
    bf16x8 pv;
    #pragma unroll
    for (int el = 0; el < 8; ++el) {
        int c = chunk * 8 + el;
        float p;
        if (c < 62) {
            float s = bf2f((unsigned short)myrow[el * 5 + 0]);
            s += bf2f((unsigned short)myrow[el * 5 + 1]);
            s += bf2f((unsigned short)myrow[el * 5 + 2]);
            s += bf2f((unsigned short)myrow[el * 5 + 3]);
            s += bf2f((unsigned short)myrow[el * 5 + 4]);
            p = s * 0.2f;
        } else {
            p = (c == 62) ? 1.0f : 0.f;
        }
        pv[el] = f2bf(p);
    }
    *(bf16x8*)((short*)(ws + WB_POOLB) + ((size_t)chunk * NB + b) * 8) = pv;
}

// ---- eog transpose -> packed bf16 pair planes [17][B] dwords ----
__global__ __launch_bounds__(256) void eog_tr(const float* __restrict__ eog,
                                              float* __restrict__ ws)
{
    __shared__ float smem[4 * 64 * 34];
    const int lane = threadIdx.x & 63;
    const int wid  = threadIdx.x >> 6;
    const int bw   = blockIdx.x * 256 + wid * 64;
    float* sw = smem + wid * (64 * 34);

    for (int j = 0; j < 33; ++j) {
        int idx = j * 64 + lane;
        int r = idx / 33, cc = idx - r * 33;
        sw[r * 34 + cc] = eog[(size_t)(bw + r) * 33 + cc];
    }
    SYNC();
    unsigned int* EOGB = (unsigned int*)(ws + WB_EOGB);
    const float* xr = sw + lane * 34;
    #pragma unroll
    for (int cp = 0; cp < 16; ++cp) {
        unsigned int d = (unsigned int)(unsigned short)f2bf(xr[2 * cp]) |
                         ((unsigned int)(unsigned short)f2bf(xr[2 * cp + 1]) << 16);
        EOGB[(size_t)cp * NB + bw + lane] = d;
    }
    EOGB[(size_t)16 * NB + bw + lane] = (unsigned int)(unsigned short)f2bf(xr[32]);
}

// ============ FUSED: MFMA front-end + transformer + head ====================
// All GEMMs use SWAPPED operands mfma(W,X) -> C[c][batch]: each lane holds 4
// CONSECUTIVE output channels (g4*4+rg) for batch row r15 of its tile ->
// relayout is packed b128/b64 writes instead of scalar scatters.
__global__ __launch_bounds__(256, 2) void mcaf_fused(
    const float* __restrict__ eeg_cb,
    const float* __restrict__ eog_inw, const float* __restrict__ eog_inb,
    const float* __restrict__ eog_ow,  const float* __restrict__ eog_ob,
    const float* __restrict__ eog_cb,
    const float* __restrict__ tl_ln1_s, const float* __restrict__ tl_ln1_b,
    const float* __restrict__ tl_ln2_s, const float* __restrict__ tl_ln2_b,
    const float* __restrict__ tl_b1,   const float* __restrict__ tl_b2,
    const float* __restrict__ fn_s,    const float* __restrict__ fn_b,
    const float* __restrict__ cls_w,   const float* __restrict__ cls_b,
    const float* __restrict__ ws,      float* __restrict__ out)
{
    __shared__ char smem[4 * WAVE_LDS];
    const int tid  = threadIdx.x;
    const int lane = tid & 63;
    const int wid  = tid >> 6;
    const int b    = blockIdx.x * 256 + tid;
    char* Wv = smem + wid * WAVE_LDS;
    const int g4  = lane >> 4;
    const int r15 = lane & 15;

    const short* MB    = (const short*)(ws + WB_MB);
    const short* CWL   = (const short*)(ws + WB_CWL);
    const short* ACAT  = (const short*)(ws + WB_ACAT);
    const short* CWOG2 = (const short*)(ws + WB_CWOG2);
    const short* PB    = (const short*)(ws + WB_POOLB);
    const unsigned int* XP = (const unsigned int*)(ws + WB_EEGXB);

    // ---- phase 1: oc[64] = [pooled,1] @ Maug^T (swapped MFMA) ----
    #pragma unroll
    for (int q = 0; q < 8; ++q) {
        bf16x8 v = *(const bf16x8*)(PB + ((size_t)q * NB + b) * 8);
        *(bf16x8*)(Wv + lane * ROWB + q * 16) = v;
    }
    SYNC();
    bf16x8 Ap[4][2];
    #pragma unroll
    for (int rt = 0; rt < 4; ++rt)
        #pragma unroll
        for (int kt = 0; kt < 2; ++kt)
            Ap[rt][kt] = *(const bf16x8*)(Wv + (rt * 16 + r15) * ROWB + (kt * 4 + g4) * 16);
    SYNC();
    f32x4 accO[4][4];   // [ct][rt]
    #pragma unroll
    for (int ct = 0; ct < 4; ++ct)
        #pragma unroll
        for (int rt = 0; rt < 4; ++rt) accO[ct][rt] = (f32x4){0.f, 0.f, 0.f, 0.f};
    __builtin_amdgcn_s_setprio(1);
    #pragma unroll
    for (int kt = 0; kt < 2; ++kt) {
        bf16x8 bb[4];
        #pragma unroll
        for (int ct = 0; ct < 4; ++ct)
            bb[ct] = *(const bf16x8*)(MB + (ct * 16 + r15) * 64 + kt * 32 + g4 * 8);
        #pragma unroll
        for (int ct = 0; ct < 4; ++ct)
            #pragma unroll
            for (int rt = 0; rt < 4; ++rt)
                accO[ct][rt] = __builtin_amdgcn_mfma_f32_16x16x32_bf16(bb[ct], Ap[rt][kt], accO[ct][rt], 0, 0, 0);
    }
    __builtin_amdgcn_s_setprio(0);
    float oc[64];
    #pragma unroll
    for (int hf = 0; hf < 2; ++hf) {
        SYNC();
        #pragma unroll
        for (int ct2 = 0; ct2 < 2; ++ct2)
            #pragma unroll
            for (int rt = 0; rt < 4; ++rt)
                *(f32x4*)(Wv + (rt * 16 + r15) * ROWB + (ct2 * 16 + g4 * 4) * 4) = accO[hf * 2 + ct2][rt];
        SYNC();
        #pragma unroll
        for (int j8 = 0; j8 < 8; ++j8) {
            f32x4 v = *(const f32x4*)(Wv + lane * ROWB + j8 * 16);
            #pragma unroll
            for (int e = 0; e < 4; ++e) oc[hf * 32 + j8 * 4 + e] = v[e];
        }
    }

    // ---- phase 2: h = Y @ CWL^T (swapped) ----
    f32x4 accH[2][4];   // [ct][rt]
    #pragma unroll
    for (int ct = 0; ct < 2; ++ct)
        #pragma unroll
        for (int rt = 0; rt < 4; ++rt) accH[ct][rt] = (f32x4){0.f, 0.f, 0.f, 0.f};
    for (int l = 0; l < 5; ++l) {
        SYNC();
        #pragma unroll
        for (int jj = 0; jj < 8; ++jj) {
            bf16x8 v;
            #pragma unroll
            for (int q = 0; q < 4; ++q) {
                int cp = jj * 4 + q;
                if (cp < 31) {
                    unsigned int d = XP[(size_t)(l * 31 + cp) * NB + b];
                    v[2 * q]     = f2bf(oc[2 * cp]     * bf2f((unsigned short)(d & 0xffffu)));
                    v[2 * q + 1] = f2bf(oc[2 * cp + 1] * bf2f((unsigned short)(d >> 16)));
                } else {
                    v[2 * q] = 0; v[2 * q + 1] = 0;
                }
            }
            *(bf16x8*)(Wv + lane * ROWB + jj * 16) = v;
        }
        SYNC();
        bf16x8 a[4][2];
        #pragma unroll
        for (int rt = 0; rt < 4; ++rt)
            #pragma unroll
            for (int kt = 0; kt < 2; ++kt)
                a[rt][kt] = *(const bf16x8*)(Wv + (rt * 16 + r15) * ROWB + (kt * 4 + g4) * 16);
        SYNC();
        __builtin_amdgcn_s_setprio(1);
        #pragma unroll
        for (int kt = 0; kt < 2; ++kt) {
            bf16x8 bb[2];
            #pragma unroll
            for (int ct = 0; ct < 2; ++ct)
                bb[ct] = *(const bf16x8*)(CWL + (ct * 16 + r15) * 320 + l * 64 + kt * 32 + g4 * 8);
            #pragma unroll
            for (int ct = 0; ct < 2; ++ct)
                #pragma unroll
                for (int rt = 0; rt < 4; ++rt)
                    accH[ct][rt] = __builtin_amdgcn_mfma_f32_16x16x32_bf16(bb[ct], a[rt][kt], accH[ct][rt], 0, 0, 0);
        }
        __builtin_amdgcn_s_setprio(0);
    }
    float h[32];
    SYNC();
    #pragma unroll
    for (int ct2 = 0; ct2 < 2; ++ct2)
        #pragma unroll
        for (int rt = 0; rt < 4; ++rt)
            *(f32x4*)(Wv + (rt * 16 + r15) * ROWB + (ct2 * 16 + g4 * 4) * 4) = accH[ct2][rt];
    SYNC();
    #pragma unroll
    for (int j8 = 0; j8 < 8; ++j8) {
        f32x4 v = *(const f32x4*)(Wv + lane * ROWB + j8 * 16);
        #pragma unroll
        for (int e = 0; e < 4; ++e) h[j8 * 4 + e] = v[e] + eeg_cb[j8 * 4 + e];
    }
    #pragma unroll
    for (int o = 0; o < 32; ++o) h[o] = elu_f(h[o]);

    // ---- phase 3: EOG via MFMA (swapped) ----
    float Tg[32];
    {
        const unsigned int* EOGB = (const unsigned int*)(ws + WB_EOGB);
        unsigned int ed[17];
        #pragma unroll
        for (int cp = 0; cp < 17; ++cp) ed[cp] = EOGB[(size_t)cp * NB + b];
        float pool = 0.f;
        #pragma unroll
        for (int cp = 0; cp < 16; ++cp) {
            pool += bf2f((unsigned short)(ed[cp] & 0xffffu));
            pool += bf2f((unsigned short)(ed[cp] >> 16));
        }
        pool += bf2f((unsigned short)(ed[16] & 0xffffu));
        SYNC();
        #pragma unroll
        for (int jj = 0; jj < 8; ++jj) {
            union { unsigned int u[4]; bf16x8 v; } pk;
            if (jj < 4) {
                pk.u[0] = ed[4 * jj]; pk.u[1] = ed[4 * jj + 1];
                pk.u[2] = ed[4 * jj + 2]; pk.u[3] = ed[4 * jj + 3];
            } else if (jj == 4) {
                pk.u[0] = ed[16]; pk.u[1] = 0; pk.u[2] = 0; pk.u[3] = 0;
            } else {
                pk.u[0] = 0; pk.u[1] = 0; pk.u[2] = 0; pk.u[3] = 0;
            }
            *(bf16x8*)(Wv + lane * ROWB + jj * 16) = pk.v;
        }
        SYNC();
        bf16x8 a[4][2];
        #pragma unroll
        for (int rt = 0; rt < 4; ++rt)
            #pragma unroll
            for (int kt = 0; kt < 2; ++kt)
                a[rt][kt] = *(const bf16x8*)(Wv + (rt * 16 + r15) * ROWB + (kt * 4 + g4) * 16);
        SYNC();
        f32x4 accE[2][4];
        #pragma unroll
        for (int ct = 0; ct < 2; ++ct)
            #pragma unroll
            for (int rt = 0; rt < 4; ++rt) accE[ct][rt] = (f32x4){0.f, 0.f, 0.f, 0.f};
        __builtin_amdgcn_s_setprio(1);
        #pragma unroll
        for (int kt = 0; kt < 2; ++kt) {
            bf16x8 bb[2];
            #pragma unroll
            for (int ct = 0; ct < 2; ++ct)
                bb[ct] = *(const bf16x8*)(CWOG2 + (ct * 16 + r15) * 64 + kt * 32 + g4 * 8);
            #pragma unroll
            for (int ct = 0; ct < 2; ++ct)
                #pragma unroll
                for (int rt = 0; rt < 4; ++rt)
                    accE[ct][rt] = __builtin_amdgcn_mfma_f32_16x16x32_bf16(bb[ct], a[rt][kt], accE[ct][rt], 0, 0, 0);
        }
        __builtin_amdgcn_s_setprio(0);
        SYNC();
        #pragma unroll
        for (int ct2 = 0; ct2 < 2; ++ct2)
            #pragma unroll
            for (int rt = 0; rt < 4; ++rt)
                *(f32x4*)(Wv + (rt * 16 + r15) * ROWB + (ct2 * 16 + g4 * 4) * 4) = accE[ct2][rt];
        SYNC();
        float tp[32];
        #pragma unroll
        for (int j8 = 0; j8 < 8; ++j8) {
            f32x4 v = *(const f32x4*)(Wv + lane * ROWB + j8 * 16);
            #pragma unroll
            for (int e = 0; e < 4; ++e) tp[j8 * 4 + e] = v[e];
        }
        pool *= (1.f / 33.f);
        float vb2 = fmaf(pool, eog_inw[2], eog_inb[2]);
        float ob2 = fmaf(vb2, eog_ow[0], eog_ob[0]);
        #pragma unroll
        for (int o = 0; o < 32; ++o)
            Tg[o] = elu_f(fmaf(ob2, tp[o], eog_cb[o]));
    }

    // ---- phase 4: feat = [h|Tg] @ ACAT^T + B0 (swapped) ----
    SYNC();
    #pragma unroll
    for (int jj = 0; jj < 8; ++jj) {
        bf16x8 v;
        #pragma unroll
        for (int e = 0; e < 8; ++e) {
            int j = jj * 8 + e;
            v[e] = f2bf(j < 32 ? h[j] : Tg[j - 32]);
        }
        *(bf16x8*)(Wv + lane * ROWB + jj * 16) = v;
    }
    SYNC();
    bf16x8 Ac[4][2];
    #pragma unroll
    for (int rt = 0; rt < 4; ++rt)
        #pragma unroll
        for (int kt = 0; kt < 2; ++kt)
            Ac[rt][kt] = *(const bf16x8*)(Wv + (rt * 16 + r15) * ROWB + (kt * 4 + g4) * 16);
    SYNC();
    f32x4 accF[4][4];
    #pragma unroll
    for (int ct = 0; ct < 4; ++ct)
        #pragma unroll
        for (int rt = 0; rt < 4; ++rt) accF[ct][rt] = (f32x4){0.f, 0.f, 0.f, 0.f};
    __builtin_amdgcn_s_setprio(1);
    #pragma unroll
    for (int kt = 0; kt < 2; ++kt) {
        bf16x8 bb[4];
        #pragma unroll
        for (int ct = 0; ct < 4; ++ct)
            bb[ct] = *(const bf16x8*)(ACAT + (ct * 16 + r15) * 64 + kt * 32 + g4 * 8);
        #pragma unroll
        for (int ct = 0; ct < 4; ++ct)
            #pragma unroll
            for (int rt = 0; rt < 4; ++rt)
                accF[ct][rt] = __builtin_amdgcn_mfma_f32_16x16x32_bf16(bb[ct], Ac[rt][kt], accF[ct][rt], 0, 0, 0);
    }
    __builtin_amdgcn_s_setprio(0);
    float feat[64];
    #pragma unroll
    for (int hf = 0; hf < 2; ++hf) {
        SYNC();
        #pragma unroll
        for (int ct2 = 0; ct2 < 2; ++ct2)
            #pragma unroll
            for (int rt = 0; rt < 4; ++rt)
                *(f32x4*)(Wv + (rt * 16 + r15) * ROWB + (ct2 * 16 + g4 * 4) * 4) = accF[hf * 2 + ct2][rt];
        SYNC();
        #pragma unroll
        for (int j8 = 0; j8 < 8; ++j8) {
            f32x4 v = *(const f32x4*)(Wv + lane * ROWB + j8 * 16);
            #pragma unroll
            for (int e = 0; e < 4; ++e) {
                int d = hf * 32 + j8 * 4 + e;
                feat[d] = v[e] + ws[WS_B0 + d];
            }
        }
    }

    // ---- transformer (2 layers) + head ----
    const short* WAb = (const short*)(ws + WB_WA_F);
    const short* W1b = (const short*)(ws + WB_W1_F);
    const short* W2b = (const short*)(ws + WB_W2_F);

    for (int i2 = 0; i2 < 2; ++i2) {
        const float* ba  = ws + WS_BATT + i2 * 64;
        const float* s1  = tl_ln1_s + i2 * 64;
        const float* gb1 = tl_ln1_b + i2 * 64;
        const float* s2  = tl_ln2_s + i2 * 64;
        const float* gb2 = tl_ln2_b + i2 * 64;
        const float* bf1 = tl_b1 + i2 * 256;
        const float* bf2 = tl_b2 + i2 * 64;

        float hb[64];
        {
            float m = 0.f;
            #pragma unroll
            for (int d = 0; d < 64; ++d) m += feat[d];
            m *= 0.015625f;
            float vv = 0.f;
            #pragma unroll
            for (int d = 0; d < 64; ++d) { float u = feat[d] - m; vv = fmaf(u, u, vv); }
            vv *= 0.015625f;
            float inv = rsqrtf(vv + 1e-5f);
            #pragma unroll
            for (int d = 0; d < 64; ++d)
                hb[d] = fmaf((feat[d] - m) * inv, s1[d], gb1[d]);
        }
        SYNC();
        #pragma unroll
        for (int jj = 0; jj < 8; ++jj) {
            bf16x8 v;
            #pragma unroll
            for (int e = 0; e < 8; ++e) v[e] = f2bf(hb[jj * 8 + e]);
            *(bf16x8*)(Wv + lane * ROWB + jj * 16) = v;
        }
        SYNC();
        bf16x8 Aat[4][2];
        #pragma unroll
        for (int rt = 0; rt < 4; ++rt)
            #pragma unroll
            for (int kt = 0; kt < 2; ++kt)
                Aat[rt][kt] = *(const bf16x8*)(Wv + (rt * 16 + r15) * ROWB + (kt * 4 + g4) * 16);
        SYNC();
        f32x4 acc[4][4];
        #pragma unroll
        for (int ct = 0; ct < 4; ++ct)
            #pragma unroll
            for (int rt = 0; rt < 4; ++rt) acc[ct][rt] = (f32x4){0.f, 0.f, 0.f, 0.f};
        __builtin_amdgcn_s_setprio(1);
        #pragma unroll
        for (int kt = 0; kt < 2; ++kt) {
            bf16x8 bb[4];
            #pragma unroll
            for (int ct = 0; ct < 4; ++ct)
                bb[ct] = *(const bf16x8*)(WAb + i2 * 4096 + (ct * 16 + r15) * 64 + kt * 32 + g4 * 8);
            #pragma unroll
            for (int ct = 0; ct < 4; ++ct)
                #pragma unroll
                for (int rt = 0; rt < 4; ++rt)
                    acc[ct][rt] = __builtin_amdgcn_mfma_f32_16x16x32_bf16(bb[ct], Aat[rt][kt], acc[ct][rt], 0, 0, 0);
        }
        __builtin_amdgcn_s_setprio(0);
        #pragma unroll
        for (int hf = 0; hf < 2; ++hf) {
            SYNC();
            #pragma unroll
            for (int ct2 = 0; ct2 < 2; ++ct2)
                #pragma unroll
                for (int rt = 0; rt < 4; ++rt)
                    *(f32x4*)(Wv + (rt * 16 + r15) * ROWB + (ct2 * 16 + g4 * 4) * 4) = acc[hf * 2 + ct2][rt];
            SYNC();
            #pragma unroll
            for (int j8 = 0; j8 < 8; ++j8) {
                f32x4 v = *(const f32x4*)(Wv + lane * ROWB + j8 * 16);
                #pragma unroll
                for (int e = 0; e < 4; ++e) {
                    int d = hf * 32 + j8 * 4 + e;
                    feat[d] += v[e] + ba[d];
                }
            }
        }
        {
            float m = 0.f;
            #pragma unroll
            for (int d = 0; d < 64; ++d) m += feat[d];
            m *= 0.015625f;
            float vv = 0.f;
            #pragma unroll
            for (int d = 0; d < 64; ++d) { float u = feat[d] - m; vv = fmaf(u, u, vv); }
            vv *= 0.015625f;
            float inv = rsqrtf(vv + 1e-5f);
            #pragma unroll
            for (int d = 0; d < 64; ++d)
                hb[d] = fmaf((feat[d] - m) * inv, s2[d], gb2[d]);
        }
        SYNC();
        #pragma unroll
        for (int jj = 0; jj < 8; ++jj) {
            bf16x8 v;
            #pragma unroll
            for (int e = 0; e < 8; ++e) v[e] = f2bf(hb[jj * 8 + e]);
            *(bf16x8*)(Wv + lane * ROWB + jj * 16) = v;
        }
        SYNC();
        f32x4 F[4][4];   // [ct][rt]
        #pragma unroll
        for (int ct = 0; ct < 4; ++ct)
            #pragma unroll
            for (int rt = 0; rt < 4; ++rt) F[ct][rt] = (f32x4){0.f, 0.f, 0.f, 0.f};

        for (int ch = 0; ch < 8; ++ch) {
            f32x4 G[2][4];   // [cc][rt]
            #pragma unroll
            for (int cc = 0; cc < 2; ++cc)
                #pragma unroll
                for (int rt = 0; rt < 4; ++rt) G[cc][rt] = (f32x4){0.f, 0.f, 0.f, 0.f};
            __builtin_amdgcn_s_setprio(1);
            #pragma unroll
            for (int kt = 0; kt < 2; ++kt) {
                bf16x8 a1[4];
                #pragma unroll
                for (int rt = 0; rt < 4; ++rt)
                    a1[rt] = *(const bf16x8*)(Wv + (rt * 16 + r15) * ROWB + (kt * 4 + g4) * 16);
                bf16x8 b1[2];
                #pragma unroll
                for (int cc = 0; cc < 2; ++cc)
                    b1[cc] = *(const bf16x8*)(W1b + i2 * 16384 + (ch * 32 + cc * 16 + r15) * 64 + kt * 32 + g4 * 8);
                #pragma unroll
                for (int cc = 0; cc < 2; ++cc)
                    #pragma unroll
                    for (int rt = 0; rt < 4; ++rt)
                        G[cc][rt] = __builtin_amdgcn_mfma_f32_16x16x32_bf16(b1[cc], a1[rt], G[cc][rt], 0, 0, 0);
            }
            __builtin_amdgcn_s_setprio(0);
            // bias + gelu -> packed b64 write of 4 consecutive j per lane
            f32x4 bjv[2];
            bjv[0] = *(const f32x4*)(bf1 + ch * 32 + g4 * 4);
            bjv[1] = *(const f32x4*)(bf1 + ch * 32 + 16 + g4 * 4);
            SYNC();
            #pragma unroll
            for (int cc = 0; cc < 2; ++cc)
                #pragma unroll
                for (int rt = 0; rt < 4; ++rt) {
                    s16x4 pk;
                    #pragma unroll
                    for (int rg = 0; rg < 4; ++rg)
                        pk[rg] = f2bf(gelu_fast(G[cc][rt][rg] + bjv[cc][rg]));
                    *(s16x4*)(Wv + (rt * 16 + r15) * ROWB + 128 + (cc * 16 + g4 * 4) * 2) = pk;
                }
            SYNC();
            bf16x8 a2[4], b2[4];
            #pragma unroll
            for (int rt = 0; rt < 4; ++rt)
                a2[rt] = *(const bf16x8*)(Wv + (rt * 16 + r15) * ROWB + 128 + g4 * 16);
            #pragma unroll
            for (int ct = 0; ct < 4; ++ct)
                b2[ct] = *(const bf16x8*)(W2b + i2 * 16384 + (ct * 16 + r15) * 256 + ch * 32 + g4 * 8);
            __builtin_amdgcn_s_setprio(1);
            #pragma unroll
            for (int ct = 0; ct < 4; ++ct)
                #pragma unroll
                for (int rt = 0; rt < 4; ++rt)
                    F[ct][rt] = __builtin_amdgcn_mfma_f32_16x16x32_bf16(b2[ct], a2[rt], F[ct][rt], 0, 0, 0);
            __builtin_amdgcn_s_setprio(0);
            SYNC();   // order a2 reads before next chunk's G' writes
        }
        #pragma unroll
        for (int hf = 0; hf < 2; ++hf) {
            SYNC();
            #pragma unroll
            for (int ct2 = 0; ct2 < 2; ++ct2)
                #pragma unroll
                for (int rt = 0; rt < 4; ++rt)
                    *(f32x4*)(Wv + (rt * 16 + r15) * ROWB + (ct2 * 16 + g4 * 4) * 4) = F[hf * 2 + ct2][rt];
            SYNC();
            #pragma unroll
            for (int j8 = 0; j8 < 8; ++j8) {
                f32x4 v = *(const f32x4*)(Wv + lane * ROWB + j8 * 16);
                #pragma unroll
                for (int e = 0; e < 4; ++e) {
                    int d = hf * 32 + j8 * 4 + e;
                    feat[d] += v[e] + bf2[d];
                }
            }
        }
        SYNC();
    }

    {
        float m = 0.f;
        #pragma unroll
        for (int d = 0; d < 64; ++d) m += feat[d];
        m *= 0.015625f;
        float vv = 0.f;
        #pragma unroll
        for (int d = 0; d < 64; ++d) { float u = feat[d] - m; vv = fmaf(u, u, vv); }
        vv *= 0.015625f;
        float inv = rsqrtf(vv + 1e-5f);
        float o0 = cls_b[0], o1 = cls_b[1], o2 = cls_b[2];
        #pragma unroll
        for (int d = 0; d < 64; ++d) {
            float n = fmaf((feat[d] - m) * inv, fn_s[d], fn_b[d]);
            o0 = fmaf(n, cls_w[d], o0);
            o1 = fmaf(n, cls_w[64 + d], o1);
            o2 = fmaf(n, cls_w[128 + d], o2);
        }
        float* op = out + (size_t)b * 3;
        op[0] = o0; op[1] = o1; op[2] = o2;
    }
}

// ================= fallback main kernel (fp32, LDS staging) =================
__global__ __launch_bounds__(256, 2) void mcaf_main_fb(
    const float* __restrict__ eeg,     const float* __restrict__ eog,
    const float* __restrict__ eeg_inb,
    const float* __restrict__ eeg_ow,  const float* __restrict__ eeg_ob,
    const float* __restrict__ eog_inw, const float* __restrict__ eog_inb,
    const float* __restrict__ eog_ow,  const float* __restrict__ eog_ob,
    const float* __restrict__ eeg_cb,  const float* __restrict__ eog_cb,
    const float* __restrict__ tl_ln1_s, const float* __restrict__ tl_ln1_b,
    const float* __restrict__ tl_ln2_s, const float* __restrict__ tl_ln2_b,
    const float* __restrict__ tl_w1,   const float* __restrict__ tl_b1,
    const float* __restrict__ tl_b2,
    const float* __restrict__ fn_s,    const float* __restrict__ fn_b,
    const float* __restrict__ cls_w,   const float* __restrict__ cls_b,
    const float* __restrict__ ws,      float* __restrict__ out)
{
    __shared__ float smem[4 * 64 * 41];
    const int t    = threadIdx.x;
    const int lane = t & 63;
    const int wid  = t >> 6;
    const int bw   = blockIdx.x * 256 + wid * 64;
    const int b    = bw + lane;
    float* sw = smem + wid * (64 * 41);

    float vbar[62];
    #pragma unroll
    for (int d = 0; d < 62; ++d) vbar[d] = eeg_inb[124 + d];

    for (int chunk = 0; chunk < 8; ++chunk) {
        const int ch0 = chunk * 8;
        for (int j = 0; j < 40; ++j) {
            int idx = j * 64 + lane;
            int r = idx / 40, cc = idx - r * 40;
            int gcol = ch0 * 5 + cc;
            float v = 0.f;
            if (gcol < 310) v = eeg[(bw + r) * 310 + gcol];
            sw[r * 41 + cc] = v;
        }
        __syncthreads();
        const int nch = (62 - ch0 < 8) ? (62 - ch0) : 8;
        for (int el = 0; el < nch; ++el) {
            const int e = ch0 + el;
            const float* xr = sw + lane * 41 + el * 5;
            float p = (xr[0] + xr[1] + xr[2] + xr[3] + xr[4]) * 0.2f;
            const float* wr = ws + WS_WVT + e * 62;
            #pragma unroll
            for (int d = 0; d < 62; ++d) vbar[d] = fmaf(p, wr[d], vbar[d]);
        }
        __syncthreads();
    }

    float h[32];
    #pragma unroll
    for (int o = 0; o < 32; ++o) h[o] = eeg_cb[o];

    for (int chunk = 0; chunk < 8; ++chunk) {
        const int ch0 = chunk * 8;
        for (int j = 0; j < 40; ++j) {
            int idx = j * 64 + lane;
            int r = idx / 40, cc = idx - r * 40;
            int gcol = ch0 * 5 + cc;
            float v = 0.f;
            if (gcol < 310) v = eeg[(bw + r) * 310 + gcol];
            sw[r * 41 + cc] = v;
        }
        __syncthreads();
        const int nch = (62 - ch0 < 8) ? (62 - ch0) : 8;
        for (int el = 0; el < nch; ++el) {
            const int c = ch0 + el;
            const float* owr = eeg_ow + c * 62;
            float oc = eeg_ob[c];
            #pragma unroll
            for (int d = 0; d < 62; ++d) oc = fmaf(owr[d], vbar[d], oc);
            const float* xr = sw + lane * 41 + el * 5;
            float x0 = xr[0], x1 = xr[1], x2 = xr[2], x3 = xr[3], x4 = xr[4];
            const float* cwr = ws + WS_CWT + c * 160;
            #pragma unroll
            for (int o = 0; o < 32; ++o) {
                float tt = x0 * cwr[o * 5 + 0];
                tt = fmaf(x1, cwr[o * 5 + 1], tt);
                tt = fmaf(x2, cwr[o * 5 + 2], tt);
                tt = fmaf(x3, cwr[o * 5 + 3], tt);
                tt = fmaf(x4, cwr[o * 5 + 4], tt);
                h[o] = fmaf(oc, tt, h[o]);
            }
        }
        __syncthreads();
    }

    #pragma unroll
    for (int o = 0; o < 32; ++o) h[o] = h[o] > 0.f ? h[o] : expm1f(h[o]);

    float feat[64];
    #pragma unroll
    for (int f = 0; f < 64; ++f) {
        float acc = ws[WS_B0 + f];
        #pragma unroll
        for (int o = 0; o < 32; ++o)
            acc = fmaf(ws[WS_A_EEG + f * 32 + o], h[o], acc);
        feat[f] = acc;
    }

    for (int j = 0; j < 33; ++j) {
        int idx = j * 64 + lane;
        int r = idx / 33, cc = idx - r * 33;
        sw[r * 34 + cc] = eog[(bw + r) * 33 + cc];
    }
    __syncthreads();
    {
        float Tg[32];
        #pragma unroll
        for (int o = 0; o < 32; ++o) Tg[o] = 0.f;
        float pool = 0.f;
        for (int l2 = 0; l2 < 33; ++l2) {
            float x = sw[lane * 34 + l2];
            pool += x;
            const float* cr = ws + WS_CWOG + l2 * 32;
            #pragma unroll
            for (int o = 0; o < 32; ++o) Tg[o] = fmaf(x, cr[o], Tg[o]);
        }
        pool *= (1.f / 33.f);
        float vb2 = fmaf(pool, eog_inw[2], eog_inb[2]);
        float ob2 = fmaf(vb2, eog_ow[0], eog_ob[0]);
        #pragma unroll
        for (int o = 0; o < 32; ++o) {
            float hh = fmaf(ob2, Tg[o], eog_cb[o]);
            Tg[o] = hh > 0.f ? hh : expm1f(hh);
        }
        #pragma unroll
        for (int f = 0; f < 64; ++f) {
            float acc = feat[f];
            #pragma unroll
            for (int o = 0; o < 32; ++o)
                acc = fmaf(ws[WS_A_EOG + f * 32 + o], Tg[o], acc);
            feat[f] = acc;
        }
    }

    for (int i2 = 0; i2 < 2; ++i2) {
        const float* Wa  = ws + WS_WATT + i2 * 4096;
        const float* ba  = ws + WS_BATT + i2 * 64;
        const float* s1  = tl_ln1_s + i2 * 64;
        const float* g1  = tl_ln1_b + i2 * 64;
        const float* s2  = tl_ln2_s + i2 * 64;
        const float* g2  = tl_ln2_b + i2 * 64;
        const float* w1p = tl_w1 + i2 * 16384;
        const float* bf1 = tl_b1 + i2 * 256;
        const float* w2t = ws + WS_W2T + i2 * 16384;
        const float* bf2 = tl_b2 + i2 * 64;

        float hb[64];
        {
            float m = 0.f;
            #pragma unroll
            for (int d = 0; d < 64; ++d) m += feat[d];
            m *= 0.015625f;
            float vv = 0.f;
            #pragma unroll
            for (int d = 0; d < 64; ++d) { float u = feat[d] - m; vv = fmaf(u, u, vv); }
            vv *= 0.015625f;
            float inv = rsqrtf(vv + 1e-5f);
            #pragma unroll
            for (int d = 0; d < 64; ++d)
                hb[d] = fmaf((feat[d] - m) * inv, s1[d], g1[d]);
        }
        #pragma unroll
        for (int c = 0; c < 64; ++c) {
            float a = ba[c];
            #pragma unroll
            for (int d = 0; d < 64; ++d) a = fmaf(Wa[c * 64 + d], hb[d], a);
            feat[c] += a;
        }
        {
            float m = 0.f;
            #pragma unroll
            for (int d = 0; d < 64; ++d) m += feat[d];
            m *= 0.015625f;
            float vv = 0.f;
            #pragma unroll
            for (int d = 0; d < 64; ++d) { float u = feat[d] - m; vv = fmaf(u, u, vv); }
            vv *= 0.015625f;
            float inv = rsqrtf(vv + 1e-5f);
            #pragma unroll
            for (int d = 0; d < 64; ++d)
                hb[d] = fmaf((feat[d] - m) * inv, s2[d], g2[d]);
        }
        #pragma unroll
        for (int c = 0; c < 64; ++c) feat[c] += bf2[c];
        for (int j = 0; j < 256; ++j) {
            const float* wr = w1p + j * 64;
            float g = bf1[j];
            #pragma unroll
            for (int d = 0; d < 64; ++d) g = fmaf(wr[d], hb[d], g);
            g = 0.5f * g * (1.f + erff(g * 0.70710678118654752f));
            const float* w2r = w2t + j * 64;
            #pragma unroll
            for (int c = 0; c < 64; ++c) feat[c] = fmaf(g, w2r[c], feat[c]);
        }
    }

    {
        float m = 0.f;
        #pragma unroll
        for (int d = 0; d < 64; ++d) m += feat[d];
        m *= 0.015625f;
        float vv = 0.f;
        #pragma unroll
        for (int d = 0; d < 64; ++d) { float u = feat[d] - m; vv = fmaf(u, u, vv); }
        vv *= 0.015625f;
        float inv = rsqrtf(vv + 1e-5f);
        float o0 = cls_b[0], o1 = cls_b[1], o2 = cls_b[2];
        #pragma unroll
        for (int d = 0; d < 64; ++d) {
            float n = fmaf((feat[d] - m) * inv, fn_s[d], fn_b[d]);
            o0 = fmaf(n, cls_w[d], o0);
            o1 = fmaf(n, cls_w[64 + d], o1);
            o2 = fmaf(n, cls_w[128 + d], o2);
        }
        float* op = out + b * 3;
        op[0] = o0; op[1] = o1; op[2] = o2;
    }
}

extern "C" void kernel_launch(void* const* d_in, const int* in_sizes, int n_in,
                              void* d_out, int out_size, void* d_ws, size_t ws_size,
                              hipStream_t stream) {
    const float* eeg      = (const float*)d_in[0];
    const float* eog      = (const float*)d_in[1];
    const float* eeg_inw  = (const float*)d_in[2];
    const float* eeg_inb  = (const float*)d_in[3];
    const float* eeg_ow   = (const float*)d_in[4];
    const float* eeg_ob   = (const float*)d_in[5];
    const float* eog_inw  = (const float*)d_in[6];
    const float* eog_inb  = (const float*)d_in[7];
    const float* eog_ow   = (const float*)d_in[8];
    const float* eog_ob   = (const float*)d_in[9];
    const float* eeg_cw   = (const float*)d_in[10];
    const float* eeg_cb   = (const float*)d_in[11];
    const float* eeg_fw   = (const float*)d_in[12];
    const float* eeg_fb   = (const float*)d_in[13];
    const float* eog_cw   = (const float*)d_in[14];
    const float* eog_cb   = (const float*)d_in[15];
    const float* eog_fw   = (const float*)d_in[16];
    const float* eog_fb   = (const float*)d_in[17];
    const float* fus_w    = (const float*)d_in[18];
    const float* fus_b    = (const float*)d_in[19];
    const float* tl_ln1_s = (const float*)d_in[20];
    const float* tl_ln1_b = (const float*)d_in[21];
    const float* tl_inw   = (const float*)d_in[22];
    const float* tl_inb   = (const float*)d_in[23];
    const float* tl_ow    = (const float*)d_in[24];
    const float* tl_ob    = (const float*)d_in[25];
    const float* tl_ln2_s = (const float*)d_in[26];
    const float* tl_ln2_b = (const float*)d_in[27];
    const float* tl_w1    = (const float*)d_in[28];
    const float* tl_b1    = (const float*)d_in[29];
    const float* tl_w2    = (const float*)d_in[30];
    const float* tl_b2    = (const float*)d_in[31];
    const float* fn_s     = (const float*)d_in[32];
    const float* fn_b     = (const float*)d_in[33];
    const float* cls_w    = (const float*)d_in[34];
    const float* cls_b    = (const float*)d_in[35];
    float* ws  = (float*)d_ws;
    float* out = (float*)d_out;

    const size_t need = (size_t)WS_TOTALF * 4u;
    const int full = (ws_size >= need) ? 1 : 0;

    hipLaunchKernelGGL(mcaf_pre, dim3(8), dim3(256), 0, stream,
                       eeg_inw, eeg_inb, eeg_ow, eeg_ob, eeg_cw,
                       eeg_fw, eeg_fb, eog_cw, eog_fw, eog_fb,
                       fus_w, fus_b, tl_inw, tl_inb, tl_ow, tl_ob, tl_w1, tl_w2,
                       ws, full);

    if (full) {
        hipLaunchKernelGGL(eeg_tr, dim3((NB / 256) * 8), dim3(256), 0, stream, eeg, ws);
        hipLaunchKernelGGL(eog_tr, dim3(NB / 256), dim3(256), 0, stream, eog, ws);
        hipLaunchKernelGGL(mcaf_fused, dim3(NB / 256), dim3(256), 0, stream,
                           eeg_cb, eog_inw, eog_inb, eog_ow, eog_ob, eog_cb,
                           tl_ln1_s, tl_ln1_b, tl_ln2_s, tl_ln2_b,
                           tl_b1, tl_b2, fn_s, fn_b, cls_w, cls_b, ws, out);
    } else {
        hipLaunchKernelGGL(mcaf_main_fb, dim3(NB / 256), dim3(256), 0, stream,
                           eeg, eog, eeg_inb, eeg_ow, eeg_ob,
                           eog_inw, eog_inb, eog_ow, eog_ob,
                           eeg_cb, eog_cb,
                           tl_ln1_s, tl_ln1_b, tl_ln2_s, tl_ln2_b,
                           tl_w1, tl_b1, tl_b2,
                           fn_s, fn_b, cls_w, cls_b, ws, out);
    }
}

// Round 13
// 197.098 us; speedup vs baseline: 4.4055x; 1.1559x over previous
//
#include <hip/hip_runtime.h>
#include <hip/hip_bf16.h>
#include <math.h>

#define NB 131072

typedef __attribute__((ext_vector_type(2))) float f32x2;
typedef __attribute__((ext_vector_type(4))) float f32x4;
typedef __attribute__((ext_vector_type(8))) short bf16x8;
typedef __attribute__((ext_vector_type(4))) short s16x4;

// Wave-local ordering fence for wave-private LDS (DS ops pinned, rest free).
#define SYNC() do { asm volatile("" ::: "memory"); __builtin_amdgcn_sched_barrier(0x7F); } while (0)

// ---- workspace layout (float offsets) ----
#define WS_A_EEG 0          // [64][32] f32 (fallback)
#define WS_A_EOG 2048
#define WS_B0    4096       // [64]
#define WS_WATT  4160       // [2][64][64] f32 (fallback)
#define WS_BATT  12352      // [2][64]
#define WS_WVT   12480      // [62][62] (fallback)
#define WS_M     16324      // [62][62] (fallback)
#define WS_OBB   20168      // [62] (fallback)
#define WS_CWT   20232      // [62][32][5] (fallback)
#define WS_CWOG  30152      // [33][32] (fallback)
#define WS_W2T   31208      // [2][256][64] f32 (fallback)
#define WB_WA_F  64000      // bf16 [2][64][64]
#define WB_W1_F  68096      // bf16 [2][256][64]
#define WB_W2_F  84480      // bf16 [2][64][256]
#define WB_MB    100864     // bf16 [64][64]  Maug[c][e]
#define WB_CWL   102912     // bf16 [32][320] CWL[o][l*64+c]
#define WB_ACAT  108032     // bf16 [64][64]  [A_EEG | A_EOG][f][j]
#define WB_CWOG2 110080     // bf16 [32][64]  CWOG2[o][l] (l<33, pad 0)
#define WB_EEGXB 111104     // packed bf16 pairs: dword plane (l*31+cp) x NB
#define WB_POOLB (WB_EEGXB + 155 * NB)       // bf16 [8][B][8] pooled (e62=1, e63=0)
#define WB_EOGB  (WB_POOLB + 32 * NB)        // packed bf16 pairs [17][B] dwords
#define WS_TOTALF (WB_EOGB + 17 * NB)

// per-wave LDS for fused kernel: 64 rows x 208B (13 x 16B granules; odd stride)
#define ROWB 208
#define WAVE_LDS (64 * ROWB)

__device__ __forceinline__ short f2bf(float x) {
    union { __hip_bfloat16 h; short s; } u;
    u.h = __float2bfloat16(x);
    return u.s;
}
__device__ __forceinline__ float bf2f(unsigned short s) {
    union { unsigned int u; float f; } v;
    v.u = (unsigned int)s << 16;
    return v.f;
}
// tanh-form gelu: ~11 VALU ops vs ~28 for erff-based. Max dev vs exact ~1e-3.
__device__ __forceinline__ float gelu_fast(float v) {
    float u = v * v;
    float w = v * fmaf(0.044715f, u, 1.0f);
    float x = fminf(w * 2.302118131f, 80.f);
    float e = __builtin_exp2f(x);
    float t = (e - 1.0f) * __builtin_amdgcn_rcpf(e + 1.0f);
    float hv = 0.5f * v;
    return fmaf(hv, t, hv);
}
__device__ __forceinline__ float elu_f(float x) {
    return x > 0.f ? x : (__builtin_exp2f(x * 1.4426950408889634f) - 1.0f);
}

__global__ __launch_bounds__(256) void mcaf_pre(
    const float* __restrict__ eeg_inw, const float* __restrict__ eeg_inb,
    const float* __restrict__ eeg_ow,  const float* __restrict__ eeg_ob,
    const float* __restrict__ eeg_cw,
    const float* __restrict__ eeg_fw,  const float* __restrict__ eeg_fb,
    const float* __restrict__ eog_cw,  const float* __restrict__ eog_fw,
    const float* __restrict__ eog_fb,
    const float* __restrict__ fus_w,   const float* __restrict__ fus_b,
    const float* __restrict__ tl_inw,  const float* __restrict__ tl_inb,
    const float* __restrict__ tl_ow,   const float* __restrict__ tl_ob,
    const float* __restrict__ tl_w1,   const float* __restrict__ tl_w2,
    float* __restrict__ ws, int full)
{
    const int tid  = blockIdx.x * blockDim.x + threadIdx.x;
    const int nthr = gridDim.x * blockDim.x;
    short* wa_b   = (short*)(ws + WB_WA_F);
    short* w1_b   = (short*)(ws + WB_W1_F);
    short* w2_b   = (short*)(ws + WB_W2_F);
    short* mb_b   = (short*)(ws + WB_MB);
    short* cwl_b  = (short*)(ws + WB_CWL);
    short* acat_b = (short*)(ws + WB_ACAT);
    short* cwog2  = (short*)(ws + WB_CWOG2);

    for (int idx = tid; idx < 4096; idx += nthr) {
        int f = idx >> 6, j = idx & 63;
        float a = 0.f;
        if (j < 32) {
            for (int k = 0; k < 64; ++k)
                a = fmaf(fus_w[f * 128 + k], eeg_fw[k * 32 + j], a);
        } else {
            int o = j - 32;
            for (int k = 0; k < 64; ++k)
                a = fmaf(fus_w[f * 128 + 64 + k], eog_fw[k * 32 + o], a);
        }
        acat_b[idx] = f2bf(a);
    }
    for (int f = tid; f < 64; f += nthr) {
        float a = fus_b[f] + (float)(f & 1);
        for (int k = 0; k < 64; ++k) {
            a = fmaf(fus_w[f * 128 + k],      eeg_fb[k], a);
            a = fmaf(fus_w[f * 128 + 64 + k], eog_fb[k], a);
        }
        ws[WS_B0 + f] = a;
    }
    for (int idx = tid; idx < 8192; idx += nthr) {
        int i = idx >> 12, c = (idx >> 6) & 63, d = idx & 63;
        float a = 0.f;
        for (int e = 0; e < 64; ++e)
            a = fmaf(tl_ow[i * 4096 + c * 64 + e],
                     tl_inw[i * 12288 + (128 + e) * 64 + d], a);
        if (!full) ws[WS_WATT + idx] = a;
        wa_b[idx] = f2bf(a);
    }
    for (int idx = tid; idx < 128; idx += nthr) {
        int i = idx >> 6, c = idx & 63;
        float a = tl_ob[i * 64 + c];
        for (int e = 0; e < 64; ++e)
            a = fmaf(tl_ow[i * 4096 + c * 64 + e], tl_inb[i * 192 + 128 + e], a);
        ws[WS_BATT + idx] = a;
    }
    for (int idx = tid; idx < 32768; idx += nthr) w1_b[idx] = f2bf(tl_w1[idx]);
    for (int idx = tid; idx < 32768; idx += nthr) w2_b[idx] = f2bf(tl_w2[idx]);

    for (int idx = tid; idx < 4096; idx += nthr) {
        int c = idx >> 6, e = idx & 63;
        float a = 0.f;
        if (c < 62) {
            if (e < 62) {
                for (int d = 0; d < 62; ++d)
                    a = fmaf(eeg_ow[c * 62 + d], eeg_inw[(124 + d) * 62 + e], a);
            } else if (e == 62) {
                a = eeg_ob[c];
                for (int d = 0; d < 62; ++d)
                    a = fmaf(eeg_ow[c * 62 + d], eeg_inb[124 + d], a);
            }
        }
        mb_b[idx] = f2bf(a);
    }
    for (int idx = tid; idx < 10240; idx += nthr) {
        int o = idx / 320, k = idx - o * 320;
        int l = k >> 6, c = k & 63;
        float a = (c < 62 && l < 5) ? eeg_cw[o * 310 + c * 5 + l] : 0.f;
        cwl_b[idx] = f2bf(a);
    }
    for (int idx = tid; idx < 2048; idx += nthr) {
        int o = idx >> 6, l = idx & 63;
        cwog2[idx] = f2bf(l < 33 ? eog_cw[o * 33 + l] : 0.f);
    }

    if (!full) {
        for (int idx = tid; idx < 2048; idx += nthr) {
            int f = idx >> 5, o = idx & 31;
            float a = 0.f, a2 = 0.f;
            for (int k = 0; k < 64; ++k) {
                a  = fmaf(fus_w[f * 128 + k],      eeg_fw[k * 32 + o], a);
                a2 = fmaf(fus_w[f * 128 + 64 + k], eog_fw[k * 32 + o], a2);
            }
            ws[WS_A_EEG + idx] = a;
            ws[WS_A_EOG + idx] = a2;
        }
        for (int idx = tid; idx < 3844; idx += nthr) {
            int e = idx / 62, d = idx - e * 62;
            ws[WS_WVT + idx] = eeg_inw[(124 + d) * 62 + e];
        }
        for (int idx = tid; idx < 3844; idx += nthr) {
            int c = idx / 62, e = idx - c * 62;
            float a = 0.f;
            for (int d = 0; d < 62; ++d)
                a = fmaf(eeg_ow[c * 62 + d], eeg_inw[(124 + d) * 62 + e], a);
            ws[WS_M + idx] = a;
        }
        for (int c = tid; c < 62; c += nthr) {
            float a = eeg_ob[c];
            for (int d = 0; d < 62; ++d)
                a = fmaf(eeg_ow[c * 62 + d], eeg_inb[124 + d], a);
            ws[WS_OBB + c] = a;
        }
        for (int idx = tid; idx < 9920; idx += nthr) {
            int c = idx / 160, r = idx - c * 160;
            int o = r / 5, l = r - o * 5;
            ws[WS_CWT + idx] = eeg_cw[o * 310 + c * 5 + l];
        }
        for (int idx = tid; idx < 1056; idx += nthr) {
            int l = idx >> 5, o = idx & 31;
            ws[WS_CWOG + idx] = eog_cw[o * 33 + l];
        }
        for (int idx = tid; idx < 32768; idx += nthr) {
            int i = idx >> 14, r = idx & 16383;
            int j = r >> 6, c = r & 63;
            ws[WS_W2T + idx] = tl_w2[i * 16384 + c * 256 + j];
        }
    }
}

// ---- combined re-layout: blocks [0, NB/256*8) do eeg chunks; blocks
// ---- [NB/256*8, +NB/256) do the eog transpose. One launch total.
__global__ __launch_bounds__(256) void mcaf_tr(const float* __restrict__ eeg,
                                               const float* __restrict__ eog,
                                               float* __restrict__ ws)
{
    __shared__ short smem[4 * 64 * 42];   // 21504 B (eeg path); eog path reuses as float[64*34] per wave region
    const int lane = threadIdx.x & 63;
    const int wid  = threadIdx.x >> 6;
    const int nEeg = (NB / 256) * 8;

    if ((int)blockIdx.x < nEeg) {
        const int chunk = blockIdx.x & 7;
        const int bw    = ((int)blockIdx.x >> 3) * 256 + wid * 64;
        const int b     = bw + lane;
        short* sw = smem + wid * (64 * 42);

        const int ch0 = chunk * 40;
        for (int j = 0; j < 20; ++j) {
            int idx = j * 64 + lane;
            int r = idx / 20, cc2 = idx - r * 20;
            int gcol = ch0 + cc2 * 2;
            unsigned int pack = 0;
            if (gcol < 310) {
                f32x2 v = *(const f32x2*)(eeg + (size_t)(bw + r) * 310 + gcol);
                pack = (unsigned int)(unsigned short)f2bf(v[0]) |
                       ((unsigned int)(unsigned short)f2bf(v[1]) << 16);
            }
            *(unsigned int*)(sw + r * 42 + cc2 * 2) = pack;
        }
        SYNC();
        const short* myrow = sw + lane * 42;
        unsigned int* planes = (unsigned int*)(ws + WB_EEGXB);
        #pragma unroll
        for (int pr = 0; pr < 4; ++pr) {
            int c0 = chunk * 8 + pr * 2;
            if (c0 < 62) {
                int cp = c0 >> 1;
                #pragma unroll
                for (int l = 0; l < 5; ++l) {
                    unsigned int d = (unsigned int)(unsigned short)myrow[pr * 10 + l] |
                                     ((unsigned int)(unsigned short)myrow[pr * 10 + 5 + l] << 16);
                    planes[(size_t)(l * 31 + cp) * NB + b] = d;
                }
            }
        }
        bf16x8 pv;
        #pragma unroll
        for (int el = 0; el < 8; ++el) {
            int c = chunk * 8 + el;
            float p;
            if (c < 62) {
                float s = bf2f((unsigned short)myrow[el * 5 + 0]);
                s += bf2f((unsigned short)myrow[el * 5 + 1]);
                s += bf2f((unsigned short)myrow[el * 5 + 2]);
                s += bf2f((unsigned short)myrow[el * 5 + 3]);
                s += bf2f((unsigned short)myrow[el * 5 + 4]);
                p = s * 0.2f;
            } else {
                p = (c == 62) ? 1.0f : 0.f;
            }
            pv[el] = f2bf(p);
        }
        *(bf16x8*)((short*)(ws + WB_POOLB) + ((size_t)chunk * NB + b) * 8) = pv;
    } else {
        const int bid = (int)blockIdx.x - nEeg;
        const int bw  = bid * 256 + wid * 64;
        float* swf = (float*)smem + wid * (64 * 34);   // 8704B/wave < 10752B region

        for (int j = 0; j < 33; ++j) {
            int idx = j * 64 + lane;
            int r = idx / 33, cc = idx - r * 33;
            swf[r * 34 + cc] = eog[(size_t)(bw + r) * 33 + cc];
        }
        SYNC();
        unsigned int* EOGB = (unsigned int*)(ws + WB_EOGB);
        const float* xr = swf + lane * 34;
        #pragma unroll
        for (int cp = 0; cp < 16; ++cp) {
            unsigned int d = (unsigned int)(unsigned short)f2bf(xr[2 * cp]) |
                             ((unsigned int)(unsigned short)f2bf(xr[2 * cp + 1]) << 16);
            EOGB[(size_t)cp * NB + bw + lane] = d;
        }
        EOGB[(size_t)16 * NB + bw + lane] = (unsigned int)(unsigned short)f2bf(xr[32]);
    }
}

// ============ FUSED: MFMA front-end + transformer + head ====================
// All GEMMs use SWAPPED operands mfma(W,X) -> C[c][batch]: each lane holds 4
// CONSECUTIVE output channels for batch row r15 of its tile -> packed relayout.
__global__ __launch_bounds__(256, 2) void mcaf_fused(
    const float* __restrict__ eeg_cb,
    const float* __restrict__ eog_inw, const float* __restrict__ eog_inb,
    const float* __restrict__ eog_ow,  const float* __restrict__ eog_ob,
    const float* __restrict__ eog_cb,
    const float* __restrict__ tl_ln1_s, const float* __restrict__ tl_ln1_b,
    const float* __restrict__ tl_ln2_s, const float* __restrict__ tl_ln2_b,
    const float* __restrict__ tl_b1,   const float* __restrict__ tl_b2,
    const float* __restrict__ fn_s,    const float* __restrict__ fn_b,
    const float* __restrict__ cls_w,   const float* __restrict__ cls_b,
    const float* __restrict__ ws,      float* __restrict__ out)
{
    __shared__ char smem[4 * WAVE_LDS];
    const int tid  = threadIdx.x;
    const int lane = tid & 63;
    const int wid  = tid >> 6;
    const int b    = blockIdx.x * 256 + tid;
    char* Wv = smem + wid * WAVE_LDS;
    const int g4  = lane >> 4;
    const int r15 = lane & 15;

    const short* MB    = (const short*)(ws + WB_MB);
    const short* CWL   = (const short*)(ws + WB_CWL);
    const short* ACAT  = (const short*)(ws + WB_ACAT);
    const short* CWOG2 = (const short*)(ws + WB_CWOG2);
    const short* PB    = (const short*)(ws + WB_POOLB);
    const unsigned int* XP = (const unsigned int*)(ws + WB_EEGXB);

    // ---- phase 1: oc[64] = [pooled,1] @ Maug^T (swapped MFMA) ----
    #pragma unroll
    for (int q = 0; q < 8; ++q) {
        bf16x8 v = *(const bf16x8*)(PB + ((size_t)q * NB + b) * 8);
        *(bf16x8*)(Wv + lane * ROWB + q * 16) = v;
    }
    SYNC();
    bf16x8 Ap[4][2];
    #pragma unroll
    for (int rt = 0; rt < 4; ++rt)
        #pragma unroll
        for (int kt = 0; kt < 2; ++kt)
            Ap[rt][kt] = *(const bf16x8*)(Wv + (rt * 16 + r15) * ROWB + (kt * 4 + g4) * 16);
    SYNC();
    f32x4 accO[4][4];   // [ct][rt]
    #pragma unroll
    for (int ct = 0; ct < 4; ++ct)
        #pragma unroll
        for (int rt = 0; rt < 4; ++rt) accO[ct][rt] = (f32x4){0.f, 0.f, 0.f, 0.f};
    __builtin_amdgcn_s_setprio(1);
    #pragma unroll
    for (int kt = 0; kt < 2; ++kt) {
        bf16x8 bb[4];
        #pragma unroll
        for (int ct = 0; ct < 4; ++ct)
            bb[ct] = *(const bf16x8*)(MB + (ct * 16 + r15) * 64 + kt * 32 + g4 * 8);
        #pragma unroll
        for (int ct = 0; ct < 4; ++ct)
            #pragma unroll
            for (int rt = 0; rt < 4; ++rt)
                accO[ct][rt] = __builtin_amdgcn_mfma_f32_16x16x32_bf16(bb[ct], Ap[rt][kt], accO[ct][rt], 0, 0, 0);
    }
    __builtin_amdgcn_s_setprio(0);
    float oc[64];
    #pragma unroll
    for (int hf = 0; hf < 2; ++hf) {
        SYNC();
        #pragma unroll
        for (int ct2 = 0; ct2 < 2; ++ct2)
            #pragma unroll
            for (int rt = 0; rt < 4; ++rt)
                *(f32x4*)(Wv + (rt * 16 + r15) * ROWB + (ct2 * 16 + g4 * 4) * 4) = accO[hf * 2 + ct2][rt];
        SYNC();
        #pragma unroll
        for (int j8 = 0; j8 < 8; ++j8) {
            f32x4 v = *(const f32x4*)(Wv + lane * ROWB + j8 * 16);
            #pragma unroll
            for (int e = 0; e < 4; ++e) oc[hf * 32 + j8 * 4 + e] = v[e];
        }
    }

    // ---- phase 2: h = Y @ CWL^T (swapped) ----
    f32x4 accH[2][4];   // [ct][rt]
    #pragma unroll
    for (int ct = 0; ct < 2; ++ct)
        #pragma unroll
        for (int rt = 0; rt < 4; ++rt) accH[ct][rt] = (f32x4){0.f, 0.f, 0.f, 0.f};
    for (int l = 0; l < 5; ++l) {
        SYNC();
        #pragma unroll
        for (int jj = 0; jj < 8; ++jj) {
            bf16x8 v;
            #pragma unroll
            for (int q = 0; q < 4; ++q) {
                int cp = jj * 4 + q;
                if (cp < 31) {
                    unsigned int d = XP[(size_t)(l * 31 + cp) * NB + b];
                    v[2 * q]     = f2bf(oc[2 * cp]     * bf2f((unsigned short)(d & 0xffffu)));
                    v[2 * q + 1] = f2bf(oc[2 * cp + 1] * bf2f((unsigned short)(d >> 16)));
                } else {
                    v[2 * q] = 0; v[2 * q + 1] = 0;
                }
            }
            *(bf16x8*)(Wv + lane * ROWB + jj * 16) = v;
        }
        SYNC();
        bf16x8 a[4][2];
        #pragma unroll
        for (int rt = 0; rt < 4; ++rt)
            #pragma unroll
            for (int kt = 0; kt < 2; ++kt)
                a[rt][kt] = *(const bf16x8*)(Wv + (rt * 16 + r15) * ROWB + (kt * 4 + g4) * 16);
        SYNC();
        __builtin_amdgcn_s_setprio(1);
        #pragma unroll
        for (int kt = 0; kt < 2; ++kt) {
            bf16x8 bb[2];
            #pragma unroll
            for (int ct = 0; ct < 2; ++ct)
                bb[ct] = *(const bf16x8*)(CWL + (ct * 16 + r15) * 320 + l * 64 + kt * 32 + g4 * 8);
            #pragma unroll
            for (int ct = 0; ct < 2; ++ct)
                #pragma unroll
                for (int rt = 0; rt < 4; ++rt)
                    accH[ct][rt] = __builtin_amdgcn_mfma_f32_16x16x32_bf16(bb[ct], a[rt][kt], accH[ct][rt], 0, 0, 0);
        }
        __builtin_amdgcn_s_setprio(0);
    }
    float h[32];
    SYNC();
    #pragma unroll
    for (int ct2 = 0; ct2 < 2; ++ct2)
        #pragma unroll
        for (int rt = 0; rt < 4; ++rt)
            *(f32x4*)(Wv + (rt * 16 + r15) * ROWB + (ct2 * 16 + g4 * 4) * 4) = accH[ct2][rt];
    SYNC();
    #pragma unroll
    for (int j8 = 0; j8 < 8; ++j8) {
        f32x4 v = *(const f32x4*)(Wv + lane * ROWB + j8 * 16);
        #pragma unroll
        for (int e = 0; e < 4; ++e) h[j8 * 4 + e] = v[e] + eeg_cb[j8 * 4 + e];
    }
    #pragma unroll
    for (int o = 0; o < 32; ++o) h[o] = elu_f(h[o]);

    // ---- phase 3: EOG via MFMA (swapped) ----
    float Tg[32];
    {
        const unsigned int* EOGB = (const unsigned int*)(ws + WB_EOGB);
        unsigned int ed[17];
        #pragma unroll
        for (int cp = 0; cp < 17; ++cp) ed[cp] = EOGB[(size_t)cp * NB + b];
        float pool = 0.f;
        #pragma unroll
        for (int cp = 0; cp < 16; ++cp) {
            pool += bf2f((unsigned short)(ed[cp] & 0xffffu));
            pool += bf2f((unsigned short)(ed[cp] >> 16));
        }
        pool += bf2f((unsigned short)(ed[16] & 0xffffu));
        SYNC();
        #pragma unroll
        for (int jj = 0; jj < 8; ++jj) {
            union { unsigned int u[4]; bf16x8 v; } pk;
            if (jj < 4) {
                pk.u[0] = ed[4 * jj]; pk.u[1] = ed[4 * jj + 1];
                pk.u[2] = ed[4 * jj + 2]; pk.u[3] = ed[4 * jj + 3];
            } else if (jj == 4) {
                pk.u[0] = ed[16]; pk.u[1] = 0; pk.u[2] = 0; pk.u[3] = 0;
            } else {
                pk.u[0] = 0; pk.u[1] = 0; pk.u[2] = 0; pk.u[3] = 0;
            }
            *(bf16x8*)(Wv + lane * ROWB + jj * 16) = pk.v;
        }
        SYNC();
        bf16x8 a[4][2];
        #pragma unroll
        for (int rt = 0; rt < 4; ++rt)
            #pragma unroll
            for (int kt = 0; kt < 2; ++kt)
                a[rt][kt] = *(const bf16x8*)(Wv + (rt * 16 + r15) * ROWB + (kt * 4 + g4) * 16);
        SYNC();
        f32x4 accE[2][4];
        #pragma unroll
        for (int ct = 0; ct < 2; ++ct)
            #pragma unroll
            for (int rt = 0; rt < 4; ++rt) accE[ct][rt] = (f32x4){0.f, 0.f, 0.f, 0.f};
        __builtin_amdgcn_s_setprio(1);
        #pragma unroll
        for (int kt = 0; kt < 2; ++kt) {
            bf16x8 bb[2];
            #pragma unroll
            for (int ct = 0; ct < 2; ++ct)
                bb[ct] = *(const bf16x8*)(CWOG2 + (ct * 16 + r15) * 64 + kt * 32 + g4 * 8);
            #pragma unroll
            for (int ct = 0; ct < 2; ++ct)
                #pragma unroll
                for (int rt = 0; rt < 4; ++rt)
                    accE[ct][rt] = __builtin_amdgcn_mfma_f32_16x16x32_bf16(bb[ct], a[rt][kt], accE[ct][rt], 0, 0, 0);
        }
        __builtin_amdgcn_s_setprio(0);
        SYNC();
        #pragma unroll
        for (int ct2 = 0; ct2 < 2; ++ct2)
            #pragma unroll
            for (int rt = 0; rt < 4; ++rt)
                *(f32x4*)(Wv + (rt * 16 + r15) * ROWB + (ct2 * 16 + g4 * 4) * 4) = accE[ct2][rt];
        SYNC();
        float tp[32];
        #pragma unroll
        for (int j8 = 0; j8 < 8; ++j8) {
            f32x4 v = *(const f32x4*)(Wv + lane * ROWB + j8 * 16);
            #pragma unroll
            for (int e = 0; e < 4; ++e) tp[j8 * 4 + e] = v[e];
        }
        pool *= (1.f / 33.f);
        float vb2 = fmaf(pool, eog_inw[2], eog_inb[2]);
        float ob2 = fmaf(vb2, eog_ow[0], eog_ob[0]);
        #pragma unroll
        for (int o = 0; o < 32; ++o)
            Tg[o] = elu_f(fmaf(ob2, tp[o], eog_cb[o]));
    }

    // ---- phase 4: feat = [h|Tg] @ ACAT^T + B0 (swapped) ----
    SYNC();
    #pragma unroll
    for (int jj = 0; jj < 8; ++jj) {
        bf16x8 v;
        #pragma unroll
        for (int e = 0; e < 8; ++e) {
            int j = jj * 8 + e;
            v[e] = f2bf(j < 32 ? h[j] : Tg[j - 32]);
        }
        *(bf16x8*)(Wv + lane * ROWB + jj * 16) = v;
    }
    SYNC();
    bf16x8 Ac[4][2];
    #pragma unroll
    for (int rt = 0; rt < 4; ++rt)
        #pragma unroll
        for (int kt = 0; kt < 2; ++kt)
            Ac[rt][kt] = *(const bf16x8*)(Wv + (rt * 16 + r15) * ROWB + (kt * 4 + g4) * 16);
    SYNC();
    f32x4 accF[4][4];
    #pragma unroll
    for (int ct = 0; ct < 4; ++ct)
        #pragma unroll
        for (int rt = 0; rt < 4; ++rt) accF[ct][rt] = (f32x4){0.f, 0.f, 0.f, 0.f};
    __builtin_amdgcn_s_setprio(1);
    #pragma unroll
    for (int kt = 0; kt < 2; ++kt) {
        bf16x8 bb[4];
        #pragma unroll
        for (int ct = 0; ct < 4; ++ct)
            bb[ct] = *(const bf16x8*)(ACAT + (ct * 16 + r15) * 64 + kt * 32 + g4 * 8);
        #pragma unroll
        for (int ct = 0; ct < 4; ++ct)
            #pragma unroll
            for (int rt = 0; rt < 4; ++rt)
                accF[ct][rt] = __builtin_amdgcn_mfma_f32_16x16x32_bf16(bb[ct], Ac[rt][kt], accF[ct][rt], 0, 0, 0);
    }
    __builtin_amdgcn_s_setprio(0);
    float feat[64];
    #pragma unroll
    for (int hf = 0; hf < 2; ++hf) {
        SYNC();
        #pragma unroll
        for (int ct2 = 0; ct2 < 2; ++ct2)
            #pragma unroll
            for (int rt = 0; rt < 4; ++rt)
                *(f32x4*)(Wv + (rt * 16 + r15) * ROWB + (ct2 * 16 + g4 * 4) * 4) = accF[hf * 2 + ct2][rt];
        SYNC();
        #pragma unroll
        for (int j8 = 0; j8 < 8; ++j8) {
            f32x4 v = *(const f32x4*)(Wv + lane * ROWB + j8 * 16);
            #pragma unroll
            for (int e = 0; e < 4; ++e) {
                int d = hf * 32 + j8 * 4 + e;
                feat[d] = v[e] + ws[WS_B0 + d];
            }
        }
    }

    // ---- transformer (2 layers) + head ----
    const short* WAb = (const short*)(ws + WB_WA_F);
    const short* W1b = (const short*)(ws + WB_W1_F);
    const short* W2b = (const short*)(ws + WB_W2_F);

    for (int i2 = 0; i2 < 2; ++i2) {
        const float* ba  = ws + WS_BATT + i2 * 64;
        const float* s1  = tl_ln1_s + i2 * 64;
        const float* gb1 = tl_ln1_b + i2 * 64;
        const float* s2  = tl_ln2_s + i2 * 64;
        const float* gb2 = tl_ln2_b + i2 * 64;
        const float* bf1 = tl_b1 + i2 * 256;
        const float* bf2 = tl_b2 + i2 * 64;

        float hb[64];
        {
            float m = 0.f;
            #pragma unroll
            for (int d = 0; d < 64; ++d) m += feat[d];
            m *= 0.015625f;
            float vv = 0.f;
            #pragma unroll
            for (int d = 0; d < 64; ++d) { float u = feat[d] - m; vv = fmaf(u, u, vv); }
            vv *= 0.015625f;
            float inv = rsqrtf(vv + 1e-5f);
            #pragma unroll
            for (int d = 0; d < 64; ++d)
                hb[d] = fmaf((feat[d] - m) * inv, s1[d], gb1[d]);
        }
        SYNC();
        #pragma unroll
        for (int jj = 0; jj < 8; ++jj) {
            bf16x8 v;
            #pragma unroll
            for (int e = 0; e < 8; ++e) v[e] = f2bf(hb[jj * 8 + e]);
            *(bf16x8*)(Wv + lane * ROWB + jj * 16) = v;
        }
        SYNC();
        bf16x8 Aat[4][2];
        #pragma unroll
        for (int rt = 0; rt < 4; ++rt)
            #pragma unroll
            for (int kt = 0; kt < 2; ++kt)
                Aat[rt][kt] = *(const bf16x8*)(Wv + (rt * 16 + r15) * ROWB + (kt * 4 + g4) * 16);
        SYNC();
        f32x4 acc[4][4];
        #pragma unroll
        for (int ct = 0; ct < 4; ++ct)
            #pragma unroll
            for (int rt = 0; rt < 4; ++rt) acc[ct][rt] = (f32x4){0.f, 0.f, 0.f, 0.f};
        __builtin_amdgcn_s_setprio(1);
        #pragma unroll
        for (int kt = 0; kt < 2; ++kt) {
            bf16x8 bb[4];
            #pragma unroll
            for (int ct = 0; ct < 4; ++ct)
                bb[ct] = *(const bf16x8*)(WAb + i2 * 4096 + (ct * 16 + r15) * 64 + kt * 32 + g4 * 8);
            #pragma unroll
            for (int ct = 0; ct < 4; ++ct)
                #pragma unroll
                for (int rt = 0; rt < 4; ++rt)
                    acc[ct][rt] = __builtin_amdgcn_mfma_f32_16x16x32_bf16(bb[ct], Aat[rt][kt], acc[ct][rt], 0, 0, 0);
        }
        __builtin_amdgcn_s_setprio(0);
        #pragma unroll
        for (int hf = 0; hf < 2; ++hf) {
            SYNC();
            #pragma unroll
            for (int ct2 = 0; ct2 < 2; ++ct2)
                #pragma unroll
                for (int rt = 0; rt < 4; ++rt)
                    *(f32x4*)(Wv + (rt * 16 + r15) * ROWB + (ct2 * 16 + g4 * 4) * 4) = acc[hf * 2 + ct2][rt];
            SYNC();
            #pragma unroll
            for (int j8 = 0; j8 < 8; ++j8) {
                f32x4 v = *(const f32x4*)(Wv + lane * ROWB + j8 * 16);
                #pragma unroll
                for (int e = 0; e < 4; ++e) {
                    int d = hf * 32 + j8 * 4 + e;
                    feat[d] += v[e] + ba[d];
                }
            }
        }
        {
            float m = 0.f;
            #pragma unroll
            for (int d = 0; d < 64; ++d) m += feat[d];
            m *= 0.015625f;
            float vv = 0.f;
            #pragma unroll
            for (int d = 0; d < 64; ++d) { float u = feat[d] - m; vv = fmaf(u, u, vv); }
            vv *= 0.015625f;
            float inv = rsqrtf(vv + 1e-5f);
            #pragma unroll
            for (int d = 0; d < 64; ++d)
                hb[d] = fmaf((feat[d] - m) * inv, s2[d], gb2[d]);
        }
        SYNC();
        #pragma unroll
        for (int jj = 0; jj < 8; ++jj) {
            bf16x8 v;
            #pragma unroll
            for (int e = 0; e < 8; ++e) v[e] = f2bf(hb[jj * 8 + e]);
            *(bf16x8*)(Wv + lane * ROWB + jj * 16) = v;
        }
        SYNC();
        f32x4 F[4][4];   // [ct][rt]
        #pragma unroll
        for (int ct = 0; ct < 4; ++ct)
            #pragma unroll
            for (int rt = 0; rt < 4; ++rt) F[ct][rt] = (f32x4){0.f, 0.f, 0.f, 0.f};

        for (int ch = 0; ch < 8; ++ch) {
            f32x4 G[2][4];   // [cc][rt]
            #pragma unroll
            for (int cc = 0; cc < 2; ++cc)
                #pragma unroll
                for (int rt = 0; rt < 4; ++rt) G[cc][rt] = (f32x4){0.f, 0.f, 0.f, 0.f};
            __builtin_amdgcn_s_setprio(1);
            #pragma unroll
            for (int kt = 0; kt < 2; ++kt) {
                bf16x8 a1[4];
                #pragma unroll
                for (int rt = 0; rt < 4; ++rt)
                    a1[rt] = *(const bf16x8*)(Wv + (rt * 16 + r15) * ROWB + (kt * 4 + g4) * 16);
                bf16x8 b1[2];
                #pragma unroll
                for (int cc = 0; cc < 2; ++cc)
                    b1[cc] = *(const bf16x8*)(W1b + i2 * 16384 + (ch * 32 + cc * 16 + r15) * 64 + kt * 32 + g4 * 8);
                #pragma unroll
                for (int cc = 0; cc < 2; ++cc)
                    #pragma unroll
                    for (int rt = 0; rt < 4; ++rt)
                        G[cc][rt] = __builtin_amdgcn_mfma_f32_16x16x32_bf16(b1[cc], a1[rt], G[cc][rt], 0, 0, 0);
            }
            __builtin_amdgcn_s_setprio(0);
            // bias + gelu -> packed b64 write of 4 consecutive j per lane
            f32x4 bjv[2];
            bjv[0] = *(const f32x4*)(bf1 + ch * 32 + g4 * 4);
            bjv[1] = *(const f32x4*)(bf1 + ch * 32 + 16 + g4 * 4);
            SYNC();
            #pragma unroll
            for (int cc = 0; cc < 2; ++cc)
                #pragma unroll
                for (int rt = 0; rt < 4; ++rt) {
                    s16x4 pk;
                    #pragma unroll
                    for (int rg = 0; rg < 4; ++rg)
                        pk[rg] = f2bf(gelu_fast(G[cc][rt][rg] + bjv[cc][rg]));
                    *(s16x4*)(Wv + (rt * 16 + r15) * ROWB + 128 + (cc * 16 + g4 * 4) * 2) = pk;
                }
            SYNC();
            bf16x8 a2[4], b2[4];
            #pragma unroll
            for (int rt = 0; rt < 4; ++rt)
                a2[rt] = *(const bf16x8*)(Wv + (rt * 16 + r15) * ROWB + 128 + g4 * 16);
            #pragma unroll
            for (int ct = 0; ct < 4; ++ct)
                b2[ct] = *(const bf16x8*)(W2b + i2 * 16384 + (ct * 16 + r15) * 256 + ch * 32 + g4 * 8);
            __builtin_amdgcn_s_setprio(1);
            #pragma unroll
            for (int ct = 0; ct < 4; ++ct)
                #pragma unroll
                for (int rt = 0; rt < 4; ++rt)
                    F[ct][rt] = __builtin_amdgcn_mfma_f32_16x16x32_bf16(b2[ct], a2[rt], F[ct][rt], 0, 0, 0);
            __builtin_amdgcn_s_setprio(0);
            SYNC();   // order a2 reads before next chunk's G' writes
        }
        #pragma unroll
        for (int hf = 0; hf < 2; ++hf) {
            SYNC();
            #pragma unroll
            for (int ct2 = 0; ct2 < 2; ++ct2)
                #pragma unroll
                for (int rt = 0; rt < 4; ++rt)
                    *(f32x4*)(Wv + (rt * 16 + r15) * ROWB + (ct2 * 16 + g4 * 4) * 4) = F[hf * 2 + ct2][rt];
            SYNC();
            #pragma unroll
            for (int j8 = 0; j8 < 8; ++j8) {
                f32x4 v = *(const f32x4*)(Wv + lane * ROWB + j8 * 16);
                #pragma unroll
                for (int e = 0; e < 4; ++e) {
                    int d = hf * 32 + j8 * 4 + e;
                    feat[d] += v[e] + bf2[d];
                }
            }
        }
        SYNC();
    }

    {
        float m = 0.f;
        #pragma unroll
        for (int d = 0; d < 64; ++d) m += feat[d];
        m *= 0.015625f;
        float vv = 0.f;
        #pragma unroll
        for (int d = 0; d < 64; ++d) { float u = feat[d] - m; vv = fmaf(u, u, vv); }
        vv *= 0.015625f;
        float inv = rsqrtf(vv + 1e-5f);
        float o0 = cls_b[0], o1 = cls_b[1], o2 = cls_b[2];
        #pragma unroll
        for (int d = 0; d < 64; ++d) {
            float n = fmaf((feat[d] - m) * inv, fn_s[d], fn_b[d]);
            o0 = fmaf(n, cls_w[d], o0);
            o1 = fmaf(n, cls_w[64 + d], o1);
            o2 = fmaf(n, cls_w[128 + d], o2);
        }
        float* op = out + (size_t)b * 3;
        op[0] = o0; op[1] = o1; op[2] = o2;
    }
}

// ================= fallback main kernel (fp32, LDS staging) =================
__global__ __launch_bounds__(256, 2) void mcaf_main_fb(
    const float* __restrict__ eeg,     const float* __restrict__ eog,
    const float* __restrict__ eeg_inb,
    const float* __restrict__ eeg_ow,  const float* __restrict__ eeg_ob,
    const float* __restrict__ eog_inw, const float* __restrict__ eog_inb,
    const float* __restrict__ eog_ow,  const float* __restrict__ eog_ob,
    const float* __restrict__ eeg_cb,  const float* __restrict__ eog_cb,
    const float* __restrict__ tl_ln1_s, const float* __restrict__ tl_ln1_b,
    const float* __restrict__ tl_ln2_s, const float* __restrict__ tl_ln2_b,
    const float* __restrict__ tl_w1,   const float* __restrict__ tl_b1,
    const float* __restrict__ tl_b2,
    const float* __restrict__ fn_s,    const float* __restrict__ fn_b,
    const float* __restrict__ cls_w,   const float* __restrict__ cls_b,
    const float* __restrict__ ws,      float* __restrict__ out)
{
    __shared__ float smem[4 * 64 * 41];
    const int t    = threadIdx.x;
    const int lane = t & 63;
    const int wid  = t >> 6;
    const int bw   = blockIdx.x * 256 + wid * 64;
    const int b    = bw + lane;
    float* sw = smem + wid * (64 * 41);

    float vbar[62];
    #pragma unroll
    for (int d = 0; d < 62; ++d) vbar[d] = eeg_inb[124 + d];

    for (int chunk = 0; chunk < 8; ++chunk) {
        const int ch0 = chunk * 8;
        for (int j = 0; j < 40; ++j) {
            int idx = j * 64 + lane;
            int r = idx / 40, cc = idx - r * 40;
            int gcol = ch0 * 5 + cc;
            float v = 0.f;
            if (gcol < 310) v = eeg[(bw + r) * 310 + gcol];
            sw[r * 41 + cc] = v;
        }
        __syncthreads();
        const int nch = (62 - ch0 < 8) ? (62 - ch0) : 8;
        for (int el = 0; el < nch; ++el) {
            const int e = ch0 + el;
            const float* xr = sw + lane * 41 + el * 5;
            float p = (xr[0] + xr[1] + xr[2] + xr[3] + xr[4]) * 0.2f;
            const float* wr = ws + WS_WVT + e * 62;
            #pragma unroll
            for (int d = 0; d < 62; ++d) vbar[d] = fmaf(p, wr[d], vbar[d]);
        }
        __syncthreads();
    }

    float h[32];
    #pragma unroll
    for (int o = 0; o < 32; ++o) h[o] = eeg_cb[o];

    for (int chunk = 0; chunk < 8; ++chunk) {
        const int ch0 = chunk * 8;
        for (int j = 0; j < 40; ++j) {
            int idx = j * 64 + lane;
            int r = idx / 40, cc = idx - r * 40;
            int gcol = ch0 * 5 + cc;
            float v = 0.f;
            if (gcol < 310) v = eeg[(bw + r) * 310 + gcol];
            sw[r * 41 + cc] = v;
        }
        __syncthreads();
        const int nch = (62 - ch0 < 8) ? (62 - ch0) : 8;
        for (int el = 0; el < nch; ++el) {
            const int c = ch0 + el;
            const float* owr = eeg_ow + c * 62;
            float oc = eeg_ob[c];
            #pragma unroll
            for (int d = 0; d < 62; ++d) oc = fmaf(owr[d], vbar[d], oc);
            const float* xr = sw + lane * 41 + el * 5;
            float x0 = xr[0], x1 = xr[1], x2 = xr[2], x3 = xr[3], x4 = xr[4];
            const float* cwr = ws + WS_CWT + c * 160;
            #pragma unroll
            for (int o = 0; o < 32; ++o) {
                float tt = x0 * cwr[o * 5 + 0];
                tt = fmaf(x1, cwr[o * 5 + 1], tt);
                tt = fmaf(x2, cwr[o * 5 + 2], tt);
                tt = fmaf(x3, cwr[o * 5 + 3], tt);
                tt = fmaf(x4, cwr[o * 5 + 4], tt);
                h[o] = fmaf(oc, tt, h[o]);
            }
        }
        __syncthreads();
    }

    #pragma unroll
    for (int o = 0; o < 32; ++o) h[o] = h[o] > 0.f ? h[o] : expm1f(h[o]);

    float feat[64];
    #pragma unroll
    for (int f = 0; f < 64; ++f) {
        float acc = ws[WS_B0 + f];
        #pragma unroll
        for (int o = 0; o < 32; ++o)
            acc = fmaf(ws[WS_A_EEG + f * 32 + o], h[o], acc);
        feat[f] = acc;
    }

    for (int j = 0; j < 33; ++j) {
        int idx = j * 64 + lane;
        int r = idx / 33, cc = idx - r * 33;
        sw[r * 34 + cc] = eog[(bw + r) * 33 + cc];
    }
    __syncthreads();
    {
        float Tg[32];
        #pragma unroll
        for (int o = 0; o < 32; ++o) Tg[o] = 0.f;
        float pool = 0.f;
        for (int l2 = 0; l2 < 33; ++l2) {
            float x = sw[lane * 34 + l2];
            pool += x;
            const float* cr = ws + WS_CWOG + l2 * 32;
            #pragma unroll
            for (int o = 0; o < 32; ++o) Tg[o] = fmaf(x, cr[o], Tg[o]);
        }
        pool *= (1.f / 33.f);
        float vb2 = fmaf(pool, eog_inw[2], eog_inb[2]);
        float ob2 = fmaf(vb2, eog_ow[0], eog_ob[0]);
        #pragma unroll
        for (int o = 0; o < 32; ++o) {
            float hh = fmaf(ob2, Tg[o], eog_cb[o]);
            Tg[o] = hh > 0.f ? hh : expm1f(hh);
        }
        #pragma unroll
        for (int f = 0; f < 64; ++f) {
            float acc = feat[f];
            #pragma unroll
            for (int o = 0; o < 32; ++o)
                acc = fmaf(ws[WS_A_EOG + f * 32 + o], Tg[o], acc);
            feat[f] = acc;
        }
    }

    for (int i2 = 0; i2 < 2; ++i2) {
        const float* Wa  = ws + WS_WATT + i2 * 4096;
        const float* ba  = ws + WS_BATT + i2 * 64;
        const float* s1  = tl_ln1_s + i2 * 64;
        const float* g1  = tl_ln1_b + i2 * 64;
        const float* s2  = tl_ln2_s + i2 * 64;
        const float* g2  = tl_ln2_b + i2 * 64;
        const float* w1p = tl_w1 + i2 * 16384;
        const float* bf1 = tl_b1 + i2 * 256;
        const float* w2t = ws + WS_W2T + i2 * 16384;
        const float* bf2 = tl_b2 + i2 * 64;

        float hb[64];
        {
            float m = 0.f;
            #pragma unroll
            for (int d = 0; d < 64; ++d) m += feat[d];
            m *= 0.015625f;
            float vv = 0.f;
            #pragma unroll
            for (int d = 0; d < 64; ++d) { float u = feat[d] - m; vv = fmaf(u, u, vv); }
            vv *= 0.015625f;
            float inv = rsqrtf(vv + 1e-5f);
            #pragma unroll
            for (int d = 0; d < 64; ++d)
                hb[d] = fmaf((feat[d] - m) * inv, s1[d], g1[d]);
        }
        #pragma unroll
        for (int c = 0; c < 64; ++c) {
            float a = ba[c];
            #pragma unroll
            for (int d = 0; d < 64; ++d) a = fmaf(Wa[c * 64 + d], hb[d], a);
            feat[c] += a;
        }
        {
            float m = 0.f;
            #pragma unroll
            for (int d = 0; d < 64; ++d) m += feat[d];
            m *= 0.015625f;
            float vv = 0.f;
            #pragma unroll
            for (int d = 0; d < 64; ++d) { float u = feat[d] - m; vv = fmaf(u, u, vv); }
            vv *= 0.015625f;
            float inv = rsqrtf(vv + 1e-5f);
            #pragma unroll
            for (int d = 0; d < 64; ++d)
                hb[d] = fmaf((feat[d] - m) * inv, s2[d], g2[d]);
        }
        #pragma unroll
        for (int c = 0; c < 64; ++c) feat[c] += bf2[c];
        for (int j = 0; j < 256; ++j) {
            const float* wr = w1p + j * 64;
            float g = bf1[j];
            #pragma unroll
            for (int d = 0; d < 64; ++d) g = fmaf(wr[d], hb[d], g);
            g = 0.5f * g * (1.f + erff(g * 0.70710678118654752f));
            const float* w2r = w2t + j * 64;
            #pragma unroll
            for (int c = 0; c < 64; ++c) feat[c] = fmaf(g, w2r[c], feat[c]);
        }
    }

    {
        float m = 0.f;
        #pragma unroll
        for (int d = 0; d < 64; ++d) m += feat[d];
        m *= 0.015625f;
        float vv = 0.f;
        #pragma unroll
        for (int d = 0; d < 64; ++d) { float u = feat[d] - m; vv = fmaf(u, u, vv); }
        vv *= 0.015625f;
        float inv = rsqrtf(vv + 1e-5f);
        float o0 = cls_b[0], o1 = cls_b[1], o2 = cls_b[2];
        #pragma unroll
        for (int d = 0; d < 64; ++d) {
            float n = fmaf((feat[d] - m) * inv, fn_s[d], fn_b[d]);
            o0 = fmaf(n, cls_w[d], o0);
            o1 = fmaf(n, cls_w[64 + d], o1);
            o2 = fmaf(n, cls_w[128 + d], o2);
        }
        float* op = out + b * 3;
        op[0] = o0; op[1] = o1; op[2] = o2;
    }
}

extern "C" void kernel_launch(void* const* d_in, const int* in_sizes, int n_in,
                              void* d_out, int out_size, void* d_ws, size_t ws_size,
                              hipStream_t stream) {
    const float* eeg      = (const float*)d_in[0];
    const float* eog      = (const float*)d_in[1];
    const float* eeg_inw  = (const float*)d_in[2];
    const float* eeg_inb  = (const float*)d_in[3];
    const float* eeg_ow   = (const float*)d_in[4];
    const float* eeg_ob   = (const float*)d_in[5];
    const float* eog_inw  = (const float*)d_in[6];
    const float* eog_inb  = (const float*)d_in[7];
    const float* eog_ow   = (const float*)d_in[8];
    const float* eog_ob   = (const float*)d_in[9];
    const float* eeg_cw   = (const float*)d_in[10];
    const float* eeg_cb   = (const float*)d_in[11];
    const float* eeg_fw   = (const float*)d_in[12];
    const float* eeg_fb   = (const float*)d_in[13];
    const float* eog_cw   = (const float*)d_in[14];
    const float* eog_cb   = (const float*)d_in[15];
    const float* eog_fw   = (const float*)d_in[16];
    const float* eog_fb   = (const float*)d_in[17];
    const float* fus_w    = (const float*)d_in[18];
    const float* fus_b    = (const float*)d_in[19];
    const float* tl_ln1_s = (const float*)d_in[20];
    const float* tl_ln1_b = (const float*)d_in[21];
    const float* tl_inw   = (const float*)d_in[22];
    const float* tl_inb   = (const float*)d_in[23];
    const float* tl_ow    = (const float*)d_in[24];
    const float* tl_ob    = (const float*)d_in[25];
    const float* tl_ln2_s = (const float*)d_in[26];
    const float* tl_ln2_b = (const float*)d_in[27];
    const float* tl_w1    = (const float*)d_in[28];
    const float* tl_b1    = (const float*)d_in[29];
    const float* tl_w2    = (const float*)d_in[30];
    const float* tl_b2    = (const float*)d_in[31];
    const float* fn_s     = (const float*)d_in[32];
    const float* fn_b     = (const float*)d_in[33];
    const float* cls_w    = (const float*)d_in[34];
    const float* cls_b    = (const float*)d_in[35];
    float* ws  = (float*)d_ws;
    float* out = (float*)d_out;

    const size_t need = (size_t)WS_TOTALF * 4u;
    const int full = (ws_size >= need) ? 1 : 0;

    hipLaunchKernelGGL(mcaf_pre, dim3(64), dim3(256), 0, stream,
                       eeg_inw, eeg_inb, eeg_ow, eeg_ob, eeg_cw,
                       eeg_fw, eeg_fb, eog_cw, eog_fw, eog_fb,
                       fus_w, fus_b, tl_inw, tl_inb, tl_ow, tl_ob, tl_w1, tl_w2,
                       ws, full);

    if (full) {
        hipLaunchKernelGGL(mcaf_tr, dim3((NB / 256) * 8 + NB / 256), dim3(256), 0, stream,
                           eeg, eog, ws);
        hipLaunchKernelGGL(mcaf_fused, dim3(NB / 256), dim3(256), 0, stream,
                           eeg_cb, eog_inw, eog_inb, eog_ow, eog_ob, eog_cb,
                           tl_ln1_s, tl_ln1_b, tl_ln2_s, tl_ln2_b,
                           tl_b1, tl_b2, fn_s, fn_b, cls_w, cls_b, ws, out);
    } else {
        hipLaunchKernelGGL(mcaf_main_fb, dim3(NB / 256), dim3(256), 0, stream,
                           eeg, eog, eeg_inb, eeg_ow, eeg_ob,
                           eog_inw, eog_inb, eog_ow, eog_ob,
                           eeg_cb, eog_cb,
                           tl_ln1_s, tl_ln1_b, tl_ln2_s, tl_ln2_b,
                           tl_w1, tl_b1, tl_b2,
                           fn_s, fn_b, cls_w, cls_b, ws, out);
    }
}

// Round 14
// 167.150 us; speedup vs baseline: 5.1948x; 1.1792x over previous
//
#include <hip/hip_runtime.h>
#include <hip/hip_bf16.h>
#include <math.h>

#define NB 131072

typedef __attribute__((ext_vector_type(2))) float f32x2;
typedef __attribute__((ext_vector_type(4))) float f32x4;
typedef __attribute__((ext_vector_type(8))) short bf16x8;
typedef __attribute__((ext_vector_type(4))) short s16x4;

// Wave-local ordering fence for wave-private LDS (DS ops pinned, rest free).
#define SYNC() do { asm volatile("" ::: "memory"); __builtin_amdgcn_sched_barrier(0x7F); } while (0)

// ---- workspace layout (float offsets) ----
#define WS_A_EEG 0          // [64][32] f32 (fallback)
#define WS_A_EOG 2048
#define WS_B0    4096       // [64]
#define WS_WATT  4160       // [2][64][64] f32 (fallback)
#define WS_BATT  12352      // [2][64]
#define WS_WVT   12480      // [62][62] (fallback)
#define WS_M     16324      // [62][62] (fallback)
#define WS_OBB   20168      // [62] (fallback)
#define WS_CWT   20232      // [62][32][5] (fallback)
#define WS_CWOG  30152      // [33][32] (fallback)
#define WS_W2T   31208      // [2][256][64] f32 (fallback)
#define WB_WA_F  64000      // bf16 [2][64][64]
#define WB_W1_F  68096      // bf16 [2][256][64]
#define WB_W2_F  84480      // bf16 [2][64][256]
#define WB_MB    100864     // bf16 [64][64]  Maug[c][e]
#define WB_CWL   102912     // bf16 [32][320] CWL[o][l*64+c]
#define WB_ACAT  108032     // bf16 [64][64]  [A_EEG | A_EOG][f][j]
#define WB_CWOG2 110080     // bf16 [32][64]  CWOG2[o][l] (l<33, pad 0)
#define WB_EEGXB 111104     // packed bf16 pairs: dword plane (l*31+cp) x NB
#define WB_POOLB (WB_EEGXB + 155 * NB)       // bf16 [8][B][8] pooled (e62=1, e63=0)
#define WB_EOGB  (WB_POOLB + 32 * NB)        // packed bf16 pairs [17][B] dwords
#define WS_TOTALF (WB_EOGB + 17 * NB)

// per-wave LDS for fused kernel: 64 rows x 208B (13 x 16B granules; odd stride)
#define ROWB 208
#define WAVE_LDS (64 * ROWB)

__device__ __forceinline__ short f2bf(float x) {
    union { __hip_bfloat16 h; short s; } u;
    u.h = __float2bfloat16(x);
    return u.s;
}
__device__ __forceinline__ float bf2f(unsigned short s) {
    union { unsigned int u; float f; } v;
    v.u = (unsigned int)s << 16;
    return v.f;
}
// tanh-form gelu: ~11 VALU ops vs ~28 for erff-based. Max dev vs exact ~1e-3.
__device__ __forceinline__ float gelu_fast(float v) {
    float u = v * v;
    float w = v * fmaf(0.044715f, u, 1.0f);
    float x = fminf(w * 2.302118131f, 80.f);
    float e = __builtin_exp2f(x);
    float t = (e - 1.0f) * __builtin_amdgcn_rcpf(e + 1.0f);
    float hv = 0.5f * v;
    return fmaf(hv, t, hv);
}
__device__ __forceinline__ float elu_f(float x) {
    return x > 0.f ? x : (__builtin_exp2f(x * 1.4426950408889634f) - 1.0f);
}

// ---- table-building work, shared by merged prep kernel (full path) and
// ---- standalone pre kernel (fallback path) ----
__device__ void pre_body(
    const float* __restrict__ eeg_inw, const float* __restrict__ eeg_inb,
    const float* __restrict__ eeg_ow,  const float* __restrict__ eeg_ob,
    const float* __restrict__ eeg_cw,
    const float* __restrict__ eeg_fw,  const float* __restrict__ eeg_fb,
    const float* __restrict__ eog_cw,  const float* __restrict__ eog_fw,
    const float* __restrict__ eog_fb,
    const float* __restrict__ fus_w,   const float* __restrict__ fus_b,
    const float* __restrict__ tl_inw,  const float* __restrict__ tl_inb,
    const float* __restrict__ tl_ow,   const float* __restrict__ tl_ob,
    const float* __restrict__ tl_w1,   const float* __restrict__ tl_w2,
    float* __restrict__ ws, int full, int tid, int nthr)
{
    short* wa_b   = (short*)(ws + WB_WA_F);
    short* w1_b   = (short*)(ws + WB_W1_F);
    short* w2_b   = (short*)(ws + WB_W2_F);
    short* mb_b   = (short*)(ws + WB_MB);
    short* cwl_b  = (short*)(ws + WB_CWL);
    short* acat_b = (short*)(ws + WB_ACAT);
    short* cwog2  = (short*)(ws + WB_CWOG2);

    for (int idx = tid; idx < 4096; idx += nthr) {
        int f = idx >> 6, j = idx & 63;
        float a = 0.f;
        if (j < 32) {
            for (int k = 0; k < 64; ++k)
                a = fmaf(fus_w[f * 128 + k], eeg_fw[k * 32 + j], a);
        } else {
            int o = j - 32;
            for (int k = 0; k < 64; ++k)
                a = fmaf(fus_w[f * 128 + 64 + k], eog_fw[k * 32 + o], a);
        }
        acat_b[idx] = f2bf(a);
    }
    for (int f = tid; f < 64; f += nthr) {
        float a = fus_b[f] + (float)(f & 1);
        for (int k = 0; k < 64; ++k) {
            a = fmaf(fus_w[f * 128 + k],      eeg_fb[k], a);
            a = fmaf(fus_w[f * 128 + 64 + k], eog_fb[k], a);
        }
        ws[WS_B0 + f] = a;
    }
    for (int idx = tid; idx < 8192; idx += nthr) {
        int i = idx >> 12, c = (idx >> 6) & 63, d = idx & 63;
        float a = 0.f;
        for (int e = 0; e < 64; ++e)
            a = fmaf(tl_ow[i * 4096 + c * 64 + e],
                     tl_inw[i * 12288 + (128 + e) * 64 + d], a);
        if (!full) ws[WS_WATT + idx] = a;
        wa_b[idx] = f2bf(a);
    }
    for (int idx = tid; idx < 128; idx += nthr) {
        int i = idx >> 6, c = idx & 63;
        float a = tl_ob[i * 64 + c];
        for (int e = 0; e < 64; ++e)
            a = fmaf(tl_ow[i * 4096 + c * 64 + e], tl_inb[i * 192 + 128 + e], a);
        ws[WS_BATT + idx] = a;
    }
    for (int idx = tid; idx < 32768; idx += nthr) w1_b[idx] = f2bf(tl_w1[idx]);
    for (int idx = tid; idx < 32768; idx += nthr) w2_b[idx] = f2bf(tl_w2[idx]);

    for (int idx = tid; idx < 4096; idx += nthr) {
        int c = idx >> 6, e = idx & 63;
        float a = 0.f;
        if (c < 62) {
            if (e < 62) {
                for (int d = 0; d < 62; ++d)
                    a = fmaf(eeg_ow[c * 62 + d], eeg_inw[(124 + d) * 62 + e], a);
            } else if (e == 62) {
                a = eeg_ob[c];
                for (int d = 0; d < 62; ++d)
                    a = fmaf(eeg_ow[c * 62 + d], eeg_inb[124 + d], a);
            }
        }
        mb_b[idx] = f2bf(a);
    }
    for (int idx = tid; idx < 10240; idx += nthr) {
        int o = idx / 320, k = idx - o * 320;
        int l = k >> 6, c = k & 63;
        float a = (c < 62 && l < 5) ? eeg_cw[o * 310 + c * 5 + l] : 0.f;
        cwl_b[idx] = f2bf(a);
    }
    for (int idx = tid; idx < 2048; idx += nthr) {
        int o = idx >> 6, l = idx & 63;
        cwog2[idx] = f2bf(l < 33 ? eog_cw[o * 33 + l] : 0.f);
    }

    if (!full) {
        for (int idx = tid; idx < 2048; idx += nthr) {
            int f = idx >> 5, o = idx & 31;
            float a = 0.f, a2 = 0.f;
            for (int k = 0; k < 64; ++k) {
                a  = fmaf(fus_w[f * 128 + k],      eeg_fw[k * 32 + o], a);
                a2 = fmaf(fus_w[f * 128 + 64 + k], eog_fw[k * 32 + o], a2);
            }
            ws[WS_A_EEG + idx] = a;
            ws[WS_A_EOG + idx] = a2;
        }
        for (int idx = tid; idx < 3844; idx += nthr) {
            int e = idx / 62, d = idx - e * 62;
            ws[WS_WVT + idx] = eeg_inw[(124 + d) * 62 + e];
        }
        for (int idx = tid; idx < 3844; idx += nthr) {
            int c = idx / 62, e = idx - c * 62;
            float a = 0.f;
            for (int d = 0; d < 62; ++d)
                a = fmaf(eeg_ow[c * 62 + d], eeg_inw[(124 + d) * 62 + e], a);
            ws[WS_M + idx] = a;
        }
        for (int c = tid; c < 62; c += nthr) {
            float a = eeg_ob[c];
            for (int d = 0; d < 62; ++d)
                a = fmaf(eeg_ow[c * 62 + d], eeg_inb[124 + d], a);
            ws[WS_OBB + c] = a;
        }
        for (int idx = tid; idx < 9920; idx += nthr) {
            int c = idx / 160, r = idx - c * 160;
            int o = r / 5, l = r - o * 5;
            ws[WS_CWT + idx] = eeg_cw[o * 310 + c * 5 + l];
        }
        for (int idx = tid; idx < 1056; idx += nthr) {
            int l = idx >> 5, o = idx & 31;
            ws[WS_CWOG + idx] = eog_cw[o * 33 + l];
        }
        for (int idx = tid; idx < 32768; idx += nthr) {
            int i = idx >> 14, r = idx & 16383;
            int j = r >> 6, c = r & 63;
            ws[WS_W2T + idx] = tl_w2[i * 16384 + c * 256 + j];
        }
    }
}

// standalone pre (fallback path only)
__global__ __launch_bounds__(256) void mcaf_pre(
    const float* __restrict__ eeg_inw, const float* __restrict__ eeg_inb,
    const float* __restrict__ eeg_ow,  const float* __restrict__ eeg_ob,
    const float* __restrict__ eeg_cw,
    const float* __restrict__ eeg_fw,  const float* __restrict__ eeg_fb,
    const float* __restrict__ eog_cw,  const float* __restrict__ eog_fw,
    const float* __restrict__ eog_fb,
    const float* __restrict__ fus_w,   const float* __restrict__ fus_b,
    const float* __restrict__ tl_inw,  const float* __restrict__ tl_inb,
    const float* __restrict__ tl_ow,   const float* __restrict__ tl_ob,
    const float* __restrict__ tl_w1,   const float* __restrict__ tl_w2,
    float* __restrict__ ws, int full)
{
    pre_body(eeg_inw, eeg_inb, eeg_ow, eeg_ob, eeg_cw, eeg_fw, eeg_fb,
             eog_cw, eog_fw, eog_fb, fus_w, fus_b, tl_inw, tl_inb,
             tl_ow, tl_ob, tl_w1, tl_w2, ws, full,
             blockIdx.x * blockDim.x + threadIdx.x, gridDim.x * blockDim.x);
}

// ---- merged prep: blocks [0,64) tables; [64, 64+NB/256*8) eeg; rest eog ----
#define PREP_PRE   64
#define PREP_EEG   ((NB / 256) * 8)
#define PREP_EOG   (NB / 256)
__global__ __launch_bounds__(256) void mcaf_prep(
    const float* __restrict__ eeg,     const float* __restrict__ eog,
    const float* __restrict__ eeg_inw, const float* __restrict__ eeg_inb,
    const float* __restrict__ eeg_ow,  const float* __restrict__ eeg_ob,
    const float* __restrict__ eeg_cw,
    const float* __restrict__ eeg_fw,  const float* __restrict__ eeg_fb,
    const float* __restrict__ eog_cw,  const float* __restrict__ eog_fw,
    const float* __restrict__ eog_fb,
    const float* __restrict__ fus_w,   const float* __restrict__ fus_b,
    const float* __restrict__ tl_inw,  const float* __restrict__ tl_inb,
    const float* __restrict__ tl_ow,   const float* __restrict__ tl_ob,
    const float* __restrict__ tl_w1,   const float* __restrict__ tl_w2,
    float* __restrict__ ws)
{
    __shared__ short smem[4 * 64 * 42];   // eeg path; eog path reuses region
    const int lane = threadIdx.x & 63;
    const int wid  = threadIdx.x >> 6;

    if ((int)blockIdx.x < PREP_PRE) {
        pre_body(eeg_inw, eeg_inb, eeg_ow, eeg_ob, eeg_cw, eeg_fw, eeg_fb,
                 eog_cw, eog_fw, eog_fb, fus_w, fus_b, tl_inw, tl_inb,
                 tl_ow, tl_ob, tl_w1, tl_w2, ws, 1,
                 blockIdx.x * 256 + threadIdx.x, PREP_PRE * 256);
        return;
    }
    if ((int)blockIdx.x < PREP_PRE + PREP_EEG) {
        const int bid   = (int)blockIdx.x - PREP_PRE;
        const int chunk = bid & 7;
        const int bw    = (bid >> 3) * 256 + wid * 64;
        const int b     = bw + lane;
        short* sw = smem + wid * (64 * 42);

        const int ch0 = chunk * 40;
        for (int j = 0; j < 20; ++j) {
            int idx = j * 64 + lane;
            int r = idx / 20, cc2 = idx - r * 20;
            int gcol = ch0 + cc2 * 2;
            unsigned int pack = 0;
            if (gcol < 310) {
                f32x2 v = *(const f32x2*)(eeg + (size_t)(bw + r) * 310 + gcol);
                pack = (unsigned int)(unsigned short)f2bf(v[0]) |
                       ((unsigned int)(unsigned short)f2bf(v[1]) << 16);
            }
            *(unsigned int*)(sw + r * 42 + cc2 * 2) = pack;
        }
        SYNC();
        const short* myrow = sw + lane * 42;
        unsigned int* planes = (unsigned int*)(ws + WB_EEGXB);
        #pragma unroll
        for (int pr = 0; pr < 4; ++pr) {
            int c0 = chunk * 8 + pr * 2;
            if (c0 < 62) {
                int cp = c0 >> 1;
                #pragma unroll
                for (int l = 0; l < 5; ++l) {
                    unsigned int d = (unsigned int)(unsigned short)myrow[pr * 10 + l] |
                                     ((unsigned int)(unsigned short)myrow[pr * 10 + 5 + l] << 16);
                    planes[(size_t)(l * 31 + cp) * NB + b] = d;
                }
            }
        }
        bf16x8 pv;
        #pragma unroll
        for (int el = 0; el < 8; ++el) {
            int c = chunk * 8 + el;
            float p;
            if (c < 62) {
                float s = bf2f((unsigned short)myrow[el * 5 + 0]);
                s += bf2f((unsigned short)myrow[el * 5 + 1]);
                s += bf2f((unsigned short)myrow[el * 5 + 2]);
                s += bf2f((unsigned short)myrow[el * 5 + 3]);
                s += bf2f((unsigned short)myrow[el * 5 + 4]);
                p = s * 0.2f;
            } else {
                p = (c == 62) ? 1.0f : 0.f;
            }
            pv[el] = f2bf(p);
        }
        *(bf16x8*)((short*)(ws + WB_POOLB) + ((size_t)chunk * NB + b) * 8) = pv;
    } else {
        const int bid = (int)blockIdx.x - PREP_PRE - PREP_EEG;
        const int bw  = bid * 256 + wid * 64;
        float* swf = (float*)smem + wid * (64 * 34);

        for (int j = 0; j < 33; ++j) {
            int idx = j * 64 + lane;
            int r = idx / 33, cc = idx - r * 33;
            swf[r * 34 + cc] = eog[(size_t)(bw + r) * 33 + cc];
        }
        SYNC();
        unsigned int* EOGB = (unsigned int*)(ws + WB_EOGB);
        const float* xr = swf + lane * 34;
        #pragma unroll
        for (int cp = 0; cp < 16; ++cp) {
            unsigned int d = (unsigned int)(unsigned short)f2bf(xr[2 * cp]) |
                             ((unsigned int)(unsigned short)f2bf(xr[2 * cp + 1]) << 16);
            EOGB[(size_t)cp * NB + bw + lane] = d;
        }
        EOGB[(size_t)16 * NB + bw + lane] = (unsigned int)(unsigned short)f2bf(xr[32]);
    }
}

// ============ FUSED: MFMA front-end + transformer + head ====================
__global__ __launch_bounds__(256, 2) void mcaf_fused(
    const float* __restrict__ eeg_cb,
    const float* __restrict__ eog_inw, const float* __restrict__ eog_inb,
    const float* __restrict__ eog_ow,  const float* __restrict__ eog_ob,
    const float* __restrict__ eog_cb,
    const float* __restrict__ tl_ln1_s, const float* __restrict__ tl_ln1_b,
    const float* __restrict__ tl_ln2_s, const float* __restrict__ tl_ln2_b,
    const float* __restrict__ tl_b1,   const float* __restrict__ tl_b2,
    const float* __restrict__ fn_s,    const float* __restrict__ fn_b,
    const float* __restrict__ cls_w,   const float* __restrict__ cls_b,
    const float* __restrict__ ws,      float* __restrict__ out)
{
    __shared__ char smem[4 * WAVE_LDS];
    const int tid  = threadIdx.x;
    const int lane = tid & 63;
    const int wid  = tid >> 6;
    const int b    = blockIdx.x * 256 + tid;
    char* Wv = smem + wid * WAVE_LDS;
    const int g4  = lane >> 4;
    const int r15 = lane & 15;

    const short* MB    = (const short*)(ws + WB_MB);
    const short* CWL   = (const short*)(ws + WB_CWL);
    const short* ACAT  = (const short*)(ws + WB_ACAT);
    const short* CWOG2 = (const short*)(ws + WB_CWOG2);
    const short* PB    = (const short*)(ws + WB_POOLB);
    const unsigned int* XP = (const unsigned int*)(ws + WB_EEGXB);

    // early-issue EOG row loads (consumed in phase 3; hides HBM latency)
    unsigned int ed[17];
    {
        const unsigned int* EOGB = (const unsigned int*)(ws + WB_EOGB);
        #pragma unroll
        for (int cp = 0; cp < 17; ++cp) ed[cp] = EOGB[(size_t)cp * NB + b];
    }

    // ---- phase 1: oc[64] = [pooled,1] @ Maug^T (swapped MFMA) ----
    #pragma unroll
    for (int q = 0; q < 8; ++q) {
        bf16x8 v = *(const bf16x8*)(PB + ((size_t)q * NB + b) * 8);
        *(bf16x8*)(Wv + lane * ROWB + q * 16) = v;
    }
    SYNC();
    bf16x8 Ap[4][2];
    #pragma unroll
    for (int rt = 0; rt < 4; ++rt)
        #pragma unroll
        for (int kt = 0; kt < 2; ++kt)
            Ap[rt][kt] = *(const bf16x8*)(Wv + (rt * 16 + r15) * ROWB + (kt * 4 + g4) * 16);
    SYNC();
    f32x4 accO[4][4];   // [ct][rt]
    #pragma unroll
    for (int ct = 0; ct < 4; ++ct)
        #pragma unroll
        for (int rt = 0; rt < 4; ++rt) accO[ct][rt] = (f32x4){0.f, 0.f, 0.f, 0.f};
    __builtin_amdgcn_s_setprio(1);
    #pragma unroll
    for (int kt = 0; kt < 2; ++kt) {
        bf16x8 bb[4];
        #pragma unroll
        for (int ct = 0; ct < 4; ++ct)
            bb[ct] = *(const bf16x8*)(MB + (ct * 16 + r15) * 64 + kt * 32 + g4 * 8);
        #pragma unroll
        for (int ct = 0; ct < 4; ++ct)
            #pragma unroll
            for (int rt = 0; rt < 4; ++rt)
                accO[ct][rt] = __builtin_amdgcn_mfma_f32_16x16x32_bf16(bb[ct], Ap[rt][kt], accO[ct][rt], 0, 0, 0);
    }
    __builtin_amdgcn_s_setprio(0);
    float oc[64];
    #pragma unroll
    for (int hf = 0; hf < 2; ++hf) {
        SYNC();
        #pragma unroll
        for (int ct2 = 0; ct2 < 2; ++ct2)
            #pragma unroll
            for (int rt = 0; rt < 4; ++rt)
                *(f32x4*)(Wv + (rt * 16 + r15) * ROWB + (ct2 * 16 + g4 * 4) * 4) = accO[hf * 2 + ct2][rt];
        SYNC();
        #pragma unroll
        for (int j8 = 0; j8 < 8; ++j8) {
            f32x4 v = *(const f32x4*)(Wv + lane * ROWB + j8 * 16);
            #pragma unroll
            for (int e = 0; e < 4; ++e) oc[hf * 32 + j8 * 4 + e] = v[e];
        }
    }

    // ---- phase 2: h = Y @ CWL^T (swapped), XP prefetched one l ahead ----
    f32x4 accH[2][4];   // [ct][rt]
    #pragma unroll
    for (int ct = 0; ct < 2; ++ct)
        #pragma unroll
        for (int rt = 0; rt < 4; ++rt) accH[ct][rt] = (f32x4){0.f, 0.f, 0.f, 0.f};
    unsigned int xp[31], xpn[31];
    #pragma unroll
    for (int cp = 0; cp < 31; ++cp) xp[cp] = XP[(size_t)cp * NB + b];
    for (int l = 0; l < 5; ++l) {
        if (l < 4) {
            #pragma unroll
            for (int cp = 0; cp < 31; ++cp)
                xpn[cp] = XP[(size_t)((l + 1) * 31 + cp) * NB + b];
        }
        SYNC();
        #pragma unroll
        for (int jj = 0; jj < 8; ++jj) {
            bf16x8 v;
            #pragma unroll
            for (int q = 0; q < 4; ++q) {
                int cp = jj * 4 + q;
                if (cp < 31) {
                    unsigned int d = xp[cp];
                    v[2 * q]     = f2bf(oc[2 * cp]     * bf2f((unsigned short)(d & 0xffffu)));
                    v[2 * q + 1] = f2bf(oc[2 * cp + 1] * bf2f((unsigned short)(d >> 16)));
                } else {
                    v[2 * q] = 0; v[2 * q + 1] = 0;
                }
            }
            *(bf16x8*)(Wv + lane * ROWB + jj * 16) = v;
        }
        SYNC();
        bf16x8 a[4][2];
        #pragma unroll
        for (int rt = 0; rt < 4; ++rt)
            #pragma unroll
            for (int kt = 0; kt < 2; ++kt)
                a[rt][kt] = *(const bf16x8*)(Wv + (rt * 16 + r15) * ROWB + (kt * 4 + g4) * 16);
        SYNC();
        __builtin_amdgcn_s_setprio(1);
        #pragma unroll
        for (int kt = 0; kt < 2; ++kt) {
            bf16x8 bb[2];
            #pragma unroll
            for (int ct = 0; ct < 2; ++ct)
                bb[ct] = *(const bf16x8*)(CWL + (ct * 16 + r15) * 320 + l * 64 + kt * 32 + g4 * 8);
            #pragma unroll
            for (int ct = 0; ct < 2; ++ct)
                #pragma unroll
                for (int rt = 0; rt < 4; ++rt)
                    accH[ct][rt] = __builtin_amdgcn_mfma_f32_16x16x32_bf16(bb[ct], a[rt][kt], accH[ct][rt], 0, 0, 0);
        }
        __builtin_amdgcn_s_setprio(0);
        #pragma unroll
        for (int cp = 0; cp < 31; ++cp) xp[cp] = xpn[cp];
    }
    float h[32];
    SYNC();
    #pragma unroll
    for (int ct2 = 0; ct2 < 2; ++ct2)
        #pragma unroll
        for (int rt = 0; rt < 4; ++rt)
            *(f32x4*)(Wv + (rt * 16 + r15) * ROWB + (ct2 * 16 + g4 * 4) * 4) = accH[ct2][rt];
    SYNC();
    #pragma unroll
    for (int j8 = 0; j8 < 8; ++j8) {
        f32x4 v = *(const f32x4*)(Wv + lane * ROWB + j8 * 16);
        #pragma unroll
        for (int e = 0; e < 4; ++e) h[j8 * 4 + e] = v[e] + eeg_cb[j8 * 4 + e];
    }
    #pragma unroll
    for (int o = 0; o < 32; ++o) h[o] = elu_f(h[o]);

    // ---- phase 3: EOG via MFMA (swapped; ed[] loaded at entry) ----
    float Tg[32];
    {
        float pool = 0.f;
        #pragma unroll
        for (int cp = 0; cp < 16; ++cp) {
            pool += bf2f((unsigned short)(ed[cp] & 0xffffu));
            pool += bf2f((unsigned short)(ed[cp] >> 16));
        }
        pool += bf2f((unsigned short)(ed[16] & 0xffffu));
        SYNC();
        #pragma unroll
        for (int jj = 0; jj < 8; ++jj) {
            union { unsigned int u[4]; bf16x8 v; } pk;
            if (jj < 4) {
                pk.u[0] = ed[4 * jj]; pk.u[1] = ed[4 * jj + 1];
                pk.u[2] = ed[4 * jj + 2]; pk.u[3] = ed[4 * jj + 3];
            } else if (jj == 4) {
                pk.u[0] = ed[16]; pk.u[1] = 0; pk.u[2] = 0; pk.u[3] = 0;
            } else {
                pk.u[0] = 0; pk.u[1] = 0; pk.u[2] = 0; pk.u[3] = 0;
            }
            *(bf16x8*)(Wv + lane * ROWB + jj * 16) = pk.v;
        }
        SYNC();
        bf16x8 a[4][2];
        #pragma unroll
        for (int rt = 0; rt < 4; ++rt)
            #pragma unroll
            for (int kt = 0; kt < 2; ++kt)
                a[rt][kt] = *(const bf16x8*)(Wv + (rt * 16 + r15) * ROWB + (kt * 4 + g4) * 16);
        SYNC();
        f32x4 accE[2][4];
        #pragma unroll
        for (int ct = 0; ct < 2; ++ct)
            #pragma unroll
            for (int rt = 0; rt < 4; ++rt) accE[ct][rt] = (f32x4){0.f, 0.f, 0.f, 0.f};
        __builtin_amdgcn_s_setprio(1);
        #pragma unroll
        for (int kt = 0; kt < 2; ++kt) {
            bf16x8 bb[2];
            #pragma unroll
            for (int ct = 0; ct < 2; ++ct)
                bb[ct] = *(const bf16x8*)(CWOG2 + (ct * 16 + r15) * 64 + kt * 32 + g4 * 8);
            #pragma unroll
            for (int ct = 0; ct < 2; ++ct)
                #pragma unroll
                for (int rt = 0; rt < 4; ++rt)
                    accE[ct][rt] = __builtin_amdgcn_mfma_f32_16x16x32_bf16(bb[ct], a[rt][kt], accE[ct][rt], 0, 0, 0);
        }
        __builtin_amdgcn_s_setprio(0);
        SYNC();
        #pragma unroll
        for (int ct2 = 0; ct2 < 2; ++ct2)
            #pragma unroll
            for (int rt = 0; rt < 4; ++rt)
                *(f32x4*)(Wv + (rt * 16 + r15) * ROWB + (ct2 * 16 + g4 * 4) * 4) = accE[ct2][rt];
        SYNC();
        float tp[32];
        #pragma unroll
        for (int j8 = 0; j8 < 8; ++j8) {
            f32x4 v = *(const f32x4*)(Wv + lane * ROWB + j8 * 16);
            #pragma unroll
            for (int e = 0; e < 4; ++e) tp[j8 * 4 + e] = v[e];
        }
        pool *= (1.f / 33.f);
        float vb2 = fmaf(pool, eog_inw[2], eog_inb[2]);
        float ob2 = fmaf(vb2, eog_ow[0], eog_ob[0]);
        #pragma unroll
        for (int o = 0; o < 32; ++o)
            Tg[o] = elu_f(fmaf(ob2, tp[o], eog_cb[o]));
    }

    // ---- phase 4: feat = [h|Tg] @ ACAT^T + B0 (swapped) ----
    SYNC();
    #pragma unroll
    for (int jj = 0; jj < 8; ++jj) {
        bf16x8 v;
        #pragma unroll
        for (int e = 0; e < 8; ++e) {
            int j = jj * 8 + e;
            v[e] = f2bf(j < 32 ? h[j] : Tg[j - 32]);
        }
        *(bf16x8*)(Wv + lane * ROWB + jj * 16) = v;
    }
    SYNC();
    bf16x8 Ac[4][2];
    #pragma unroll
    for (int rt = 0; rt < 4; ++rt)
        #pragma unroll
        for (int kt = 0; kt < 2; ++kt)
            Ac[rt][kt] = *(const bf16x8*)(Wv + (rt * 16 + r15) * ROWB + (kt * 4 + g4) * 16);
    SYNC();
    f32x4 accF[4][4];
    #pragma unroll
    for (int ct = 0; ct < 4; ++ct)
        #pragma unroll
        for (int rt = 0; rt < 4; ++rt) accF[ct][rt] = (f32x4){0.f, 0.f, 0.f, 0.f};
    __builtin_amdgcn_s_setprio(1);
    #pragma unroll
    for (int kt = 0; kt < 2; ++kt) {
        bf16x8 bb[4];
        #pragma unroll
        for (int ct = 0; ct < 4; ++ct)
            bb[ct] = *(const bf16x8*)(ACAT + (ct * 16 + r15) * 64 + kt * 32 + g4 * 8);
        #pragma unroll
        for (int ct = 0; ct < 4; ++ct)
            #pragma unroll
            for (int rt = 0; rt < 4; ++rt)
                accF[ct][rt] = __builtin_amdgcn_mfma_f32_16x16x32_bf16(bb[ct], Ac[rt][kt], accF[ct][rt], 0, 0, 0);
    }
    __builtin_amdgcn_s_setprio(0);
    float feat[64];
    #pragma unroll
    for (int hf = 0; hf < 2; ++hf) {
        SYNC();
        #pragma unroll
        for (int ct2 = 0; ct2 < 2; ++ct2)
            #pragma unroll
            for (int rt = 0; rt < 4; ++rt)
                *(f32x4*)(Wv + (rt * 16 + r15) * ROWB + (ct2 * 16 + g4 * 4) * 4) = accF[hf * 2 + ct2][rt];
        SYNC();
        #pragma unroll
        for (int j8 = 0; j8 < 8; ++j8) {
            f32x4 v = *(const f32x4*)(Wv + lane * ROWB + j8 * 16);
            #pragma unroll
            for (int e = 0; e < 4; ++e) {
                int d = hf * 32 + j8 * 4 + e;
                feat[d] = v[e] + ws[WS_B0 + d];
            }
        }
    }

    // ---- transformer (2 layers) + head ----
    const short* WAb = (const short*)(ws + WB_WA_F);
    const short* W1b = (const short*)(ws + WB_W1_F);
    const short* W2b = (const short*)(ws + WB_W2_F);

    for (int i2 = 0; i2 < 2; ++i2) {
        const float* ba  = ws + WS_BATT + i2 * 64;
        const float* s1  = tl_ln1_s + i2 * 64;
        const float* gb1 = tl_ln1_b + i2 * 64;
        const float* s2  = tl_ln2_s + i2 * 64;
        const float* gb2 = tl_ln2_b + i2 * 64;
        const float* bf1 = tl_b1 + i2 * 256;
        const float* bf2 = tl_b2 + i2 * 64;

        float hb[64];
        {
            float m = 0.f;
            #pragma unroll
            for (int d = 0; d < 64; ++d) m += feat[d];
            m *= 0.015625f;
            float vv = 0.f;
            #pragma unroll
            for (int d = 0; d < 64; ++d) { float u = feat[d] - m; vv = fmaf(u, u, vv); }
            vv *= 0.015625f;
            float inv = rsqrtf(vv + 1e-5f);
            #pragma unroll
            for (int d = 0; d < 64; ++d)
                hb[d] = fmaf((feat[d] - m) * inv, s1[d], gb1[d]);
        }
        SYNC();
        #pragma unroll
        for (int jj = 0; jj < 8; ++jj) {
            bf16x8 v;
            #pragma unroll
            for (int e = 0; e < 8; ++e) v[e] = f2bf(hb[jj * 8 + e]);
            *(bf16x8*)(Wv + lane * ROWB + jj * 16) = v;
        }
        SYNC();
        bf16x8 Aat[4][2];
        #pragma unroll
        for (int rt = 0; rt < 4; ++rt)
            #pragma unroll
            for (int kt = 0; kt < 2; ++kt)
                Aat[rt][kt] = *(const bf16x8*)(Wv + (rt * 16 + r15) * ROWB + (kt * 4 + g4) * 16);
        SYNC();
        f32x4 acc[4][4];
        #pragma unroll
        for (int ct = 0; ct < 4; ++ct)
            #pragma unroll
            for (int rt = 0; rt < 4; ++rt) acc[ct][rt] = (f32x4){0.f, 0.f, 0.f, 0.f};
        __builtin_amdgcn_s_setprio(1);
        #pragma unroll
        for (int kt = 0; kt < 2; ++kt) {
            bf16x8 bb[4];
            #pragma unroll
            for (int ct = 0; ct < 4; ++ct)
                bb[ct] = *(const bf16x8*)(WAb + i2 * 4096 + (ct * 16 + r15) * 64 + kt * 32 + g4 * 8);
            #pragma unroll
            for (int ct = 0; ct < 4; ++ct)
                #pragma unroll
                for (int rt = 0; rt < 4; ++rt)
                    acc[ct][rt] = __builtin_amdgcn_mfma_f32_16x16x32_bf16(bb[ct], Aat[rt][kt], acc[ct][rt], 0, 0, 0);
        }
        __builtin_amdgcn_s_setprio(0);
        #pragma unroll
        for (int hf = 0; hf < 2; ++hf) {
            SYNC();
            #pragma unroll
            for (int ct2 = 0; ct2 < 2; ++ct2)
                #pragma unroll
                for (int rt = 0; rt < 4; ++rt)
                    *(f32x4*)(Wv + (rt * 16 + r15) * ROWB + (ct2 * 16 + g4 * 4) * 4) = acc[hf * 2 + ct2][rt];
            SYNC();
            #pragma unroll
            for (int j8 = 0; j8 < 8; ++j8) {
                f32x4 v = *(const f32x4*)(Wv + lane * ROWB + j8 * 16);
                #pragma unroll
                for (int e = 0; e < 4; ++e) {
                    int d = hf * 32 + j8 * 4 + e;
                    feat[d] += v[e] + ba[d];
                }
            }
        }
        {
            float m = 0.f;
            #pragma unroll
            for (int d = 0; d < 64; ++d) m += feat[d];
            m *= 0.015625f;
            float vv = 0.f;
            #pragma unroll
            for (int d = 0; d < 64; ++d) { float u = feat[d] - m; vv = fmaf(u, u, vv); }
            vv *= 0.015625f;
            float inv = rsqrtf(vv + 1e-5f);
            #pragma unroll
            for (int d = 0; d < 64; ++d)
                hb[d] = fmaf((feat[d] - m) * inv, s2[d], gb2[d]);
        }
        SYNC();
        #pragma unroll
        for (int jj = 0; jj < 8; ++jj) {
            bf16x8 v;
            #pragma unroll
            for (int e = 0; e < 8; ++e) v[e] = f2bf(hb[jj * 8 + e]);
            *(bf16x8*)(Wv + lane * ROWB + jj * 16) = v;
        }
        SYNC();
        f32x4 F[4][4];   // [ct][rt]
        #pragma unroll
        for (int ct = 0; ct < 4; ++ct)
            #pragma unroll
            for (int rt = 0; rt < 4; ++rt) F[ct][rt] = (f32x4){0.f, 0.f, 0.f, 0.f};

        for (int ch = 0; ch < 8; ++ch) {
            f32x4 G[2][4];   // [cc][rt]
            #pragma unroll
            for (int cc = 0; cc < 2; ++cc)
                #pragma unroll
                for (int rt = 0; rt < 4; ++rt) G[cc][rt] = (f32x4){0.f, 0.f, 0.f, 0.f};
            __builtin_amdgcn_s_setprio(1);
            #pragma unroll
            for (int kt = 0; kt < 2; ++kt) {
                bf16x8 a1[4];
                #pragma unroll
                for (int rt = 0; rt < 4; ++rt)
                    a1[rt] = *(const bf16x8*)(Wv + (rt * 16 + r15) * ROWB + (kt * 4 + g4) * 16);
                bf16x8 b1[2];
                #pragma unroll
                for (int cc = 0; cc < 2; ++cc)
                    b1[cc] = *(const bf16x8*)(W1b + i2 * 16384 + (ch * 32 + cc * 16 + r15) * 64 + kt * 32 + g4 * 8);
                #pragma unroll
                for (int cc = 0; cc < 2; ++cc)
                    #pragma unroll
                    for (int rt = 0; rt < 4; ++rt)
                        G[cc][rt] = __builtin_amdgcn_mfma_f32_16x16x32_bf16(b1[cc], a1[rt], G[cc][rt], 0, 0, 0);
            }
            __builtin_amdgcn_s_setprio(0);
            f32x4 bjv[2];
            bjv[0] = *(const f32x4*)(bf1 + ch * 32 + g4 * 4);
            bjv[1] = *(const f32x4*)(bf1 + ch * 32 + 16 + g4 * 4);
            SYNC();
            #pragma unroll
            for (int cc = 0; cc < 2; ++cc)
                #pragma unroll
                for (int rt = 0; rt < 4; ++rt) {
                    s16x4 pk;
                    #pragma unroll
                    for (int rg = 0; rg < 4; ++rg)
                        pk[rg] = f2bf(gelu_fast(G[cc][rt][rg] + bjv[cc][rg]));
                    *(s16x4*)(Wv + (rt * 16 + r15) * ROWB + 128 + (cc * 16 + g4 * 4) * 2) = pk;
                }
            SYNC();
            bf16x8 a2[4], b2[4];
            #pragma unroll
            for (int rt = 0; rt < 4; ++rt)
                a2[rt] = *(const bf16x8*)(Wv + (rt * 16 + r15) * ROWB + 128 + g4 * 16);
            #pragma unroll
            for (int ct = 0; ct < 4; ++ct)
                b2[ct] = *(const bf16x8*)(W2b + i2 * 16384 + (ct * 16 + r15) * 256 + ch * 32 + g4 * 8);
            __builtin_amdgcn_s_setprio(1);
            #pragma unroll
            for (int ct = 0; ct < 4; ++ct)
                #pragma unroll
                for (int rt = 0; rt < 4; ++rt)
                    F[ct][rt] = __builtin_amdgcn_mfma_f32_16x16x32_bf16(b2[ct], a2[rt], F[ct][rt], 0, 0, 0);
            __builtin_amdgcn_s_setprio(0);
            SYNC();
        }
        #pragma unroll
        for (int hf = 0; hf < 2; ++hf) {
            SYNC();
            #pragma unroll
            for (int ct2 = 0; ct2 < 2; ++ct2)
                #pragma unroll
                for (int rt = 0; rt < 4; ++rt)
                    *(f32x4*)(Wv + (rt * 16 + r15) * ROWB + (ct2 * 16 + g4 * 4) * 4) = F[hf * 2 + ct2][rt];
            SYNC();
            #pragma unroll
            for (int j8 = 0; j8 < 8; ++j8) {
                f32x4 v = *(const f32x4*)(Wv + lane * ROWB + j8 * 16);
                #pragma unroll
                for (int e = 0; e < 4; ++e) {
                    int d = hf * 32 + j8 * 4 + e;
                    feat[d] += v[e] + bf2[d];
                }
            }
        }
        SYNC();
    }

    {
        float m = 0.f;
        #pragma unroll
        for (int d = 0; d < 64; ++d) m += feat[d];
        m *= 0.015625f;
        float vv = 0.f;
        #pragma unroll
        for (int d = 0; d < 64; ++d) { float u = feat[d] - m; vv = fmaf(u, u, vv); }
        vv *= 0.015625f;
        float inv = rsqrtf(vv + 1e-5f);
        float o0 = cls_b[0], o1 = cls_b[1], o2 = cls_b[2];
        #pragma unroll
        for (int d = 0; d < 64; ++d) {
            float n = fmaf((feat[d] - m) * inv, fn_s[d], fn_b[d]);
            o0 = fmaf(n, cls_w[d], o0);
            o1 = fmaf(n, cls_w[64 + d], o1);
            o2 = fmaf(n, cls_w[128 + d], o2);
        }
        float* op = out + (size_t)b * 3;
        op[0] = o0; op[1] = o1; op[2] = o2;
    }
}

// ================= fallback main kernel (fp32, LDS staging) =================
__global__ __launch_bounds__(256, 2) void mcaf_main_fb(
    const float* __restrict__ eeg,     const float* __restrict__ eog,
    const float* __restrict__ eeg_inb,
    const float* __restrict__ eeg_ow,  const float* __restrict__ eeg_ob,
    const float* __restrict__ eog_inw, const float* __restrict__ eog_inb,
    const float* __restrict__ eog_ow,  const float* __restrict__ eog_ob,
    const float* __restrict__ eeg_cb,  const float* __restrict__ eog_cb,
    const float* __restrict__ tl_ln1_s, const float* __restrict__ tl_ln1_b,
    const float* __restrict__ tl_ln2_s, const float* __restrict__ tl_ln2_b,
    const float* __restrict__ tl_w1,   const float* __restrict__ tl_b1,
    const float* __restrict__ tl_b2,
    const float* __restrict__ fn_s,    const float* __restrict__ fn_b,
    const float* __restrict__ cls_w,   const float* __restrict__ cls_b,
    const float* __restrict__ ws,      float* __restrict__ out)
{
    __shared__ float smem[4 * 64 * 41];
    const int t    = threadIdx.x;
    const int lane = t & 63;
    const int wid  = t >> 6;
    const int bw   = blockIdx.x * 256 + wid * 64;
    const int b    = bw + lane;
    float* sw = smem + wid * (64 * 41);

    float vbar[62];
    #pragma unroll
    for (int d = 0; d < 62; ++d) vbar[d] = eeg_inb[124 + d];

    for (int chunk = 0; chunk < 8; ++chunk) {
        const int ch0 = chunk * 8;
        for (int j = 0; j < 40; ++j) {
            int idx = j * 64 + lane;
            int r = idx / 40, cc = idx - r * 40;
            int gcol = ch0 * 5 + cc;
            float v = 0.f;
            if (gcol < 310) v = eeg[(bw + r) * 310 + gcol];
            sw[r * 41 + cc] = v;
        }
        __syncthreads();
        const int nch = (62 - ch0 < 8) ? (62 - ch0) : 8;
        for (int el = 0; el < nch; ++el) {
            const int e = ch0 + el;
            const float* xr = sw + lane * 41 + el * 5;
            float p = (xr[0] + xr[1] + xr[2] + xr[3] + xr[4]) * 0.2f;
            const float* wr = ws + WS_WVT + e * 62;
            #pragma unroll
            for (int d = 0; d < 62; ++d) vbar[d] = fmaf(p, wr[d], vbar[d]);
        }
        __syncthreads();
    }

    float h[32];
    #pragma unroll
    for (int o = 0; o < 32; ++o) h[o] = eeg_cb[o];

    for (int chunk = 0; chunk < 8; ++chunk) {
        const int ch0 = chunk * 8;
        for (int j = 0; j < 40; ++j) {
            int idx = j * 64 + lane;
            int r = idx / 40, cc = idx - r * 40;
            int gcol = ch0 * 5 + cc;
            float v = 0.f;
            if (gcol < 310) v = eeg[(bw + r) * 310 + gcol];
            sw[r * 41 + cc] = v;
        }
        __syncthreads();
        const int nch = (62 - ch0 < 8) ? (62 - ch0) : 8;
        for (int el = 0; el < nch; ++el) {
            const int c = ch0 + el;
            const float* owr = eeg_ow + c * 62;
            float oc = eeg_ob[c];
            #pragma unroll
            for (int d = 0; d < 62; ++d) oc = fmaf(owr[d], vbar[d], oc);
            const float* xr = sw + lane * 41 + el * 5;
            float x0 = xr[0], x1 = xr[1], x2 = xr[2], x3 = xr[3], x4 = xr[4];
            const float* cwr = ws + WS_CWT + c * 160;
            #pragma unroll
            for (int o = 0; o < 32; ++o) {
                float tt = x0 * cwr[o * 5 + 0];
                tt = fmaf(x1, cwr[o * 5 + 1], tt);
                tt = fmaf(x2, cwr[o * 5 + 2], tt);
                tt = fmaf(x3, cwr[o * 5 + 3], tt);
                tt = fmaf(x4, cwr[o * 5 + 4], tt);
                h[o] = fmaf(oc, tt, h[o]);
            }
        }
        __syncthreads();
    }

    #pragma unroll
    for (int o = 0; o < 32; ++o) h[o] = h[o] > 0.f ? h[o] : expm1f(h[o]);

    float feat[64];
    #pragma unroll
    for (int f = 0; f < 64; ++f) {
        float acc = ws[WS_B0 + f];
        #pragma unroll
        for (int o = 0; o < 32; ++o)
            acc = fmaf(ws[WS_A_EEG + f * 32 + o], h[o], acc);
        feat[f] = acc;
    }

    for (int j = 0; j < 33; ++j) {
        int idx = j * 64 + lane;
        int r = idx / 33, cc = idx - r * 33;
        sw[r * 34 + cc] = eog[(bw + r) * 33 + cc];
    }
    __syncthreads();
    {
        float Tg[32];
        #pragma unroll
        for (int o = 0; o < 32; ++o) Tg[o] = 0.f;
        float pool = 0.f;
        for (int l2 = 0; l2 < 33; ++l2) {
            float x = sw[lane * 34 + l2];
            pool += x;
            const float* cr = ws + WS_CWOG + l2 * 32;
            #pragma unroll
            for (int o = 0; o < 32; ++o) Tg[o] = fmaf(x, cr[o], Tg[o]);
        }
        pool *= (1.f / 33.f);
        float vb2 = fmaf(pool, eog_inw[2], eog_inb[2]);
        float ob2 = fmaf(vb2, eog_ow[0], eog_ob[0]);
        #pragma unroll
        for (int o = 0; o < 32; ++o) {
            float hh = fmaf(ob2, Tg[o], eog_cb[o]);
            Tg[o] = hh > 0.f ? hh : expm1f(hh);
        }
        #pragma unroll
        for (int f = 0; f < 64; ++f) {
            float acc = feat[f];
            #pragma unroll
            for (int o = 0; o < 32; ++o)
                acc = fmaf(ws[WS_A_EOG + f * 32 + o], Tg[o], acc);
            feat[f] = acc;
        }
    }

    for (int i2 = 0; i2 < 2; ++i2) {
        const float* Wa  = ws + WS_WATT + i2 * 4096;
        const float* ba  = ws + WS_BATT + i2 * 64;
        const float* s1  = tl_ln1_s + i2 * 64;
        const float* g1  = tl_ln1_b + i2 * 64;
        const float* s2  = tl_ln2_s + i2 * 64;
        const float* g2  = tl_ln2_b + i2 * 64;
        const float* w1p = tl_w1 + i2 * 16384;
        const float* bf1 = tl_b1 + i2 * 256;
        const float* w2t = ws + WS_W2T + i2 * 16384;
        const float* bf2 = tl_b2 + i2 * 64;

        float hb[64];
        {
            float m = 0.f;
            #pragma unroll
            for (int d = 0; d < 64; ++d) m += feat[d];
            m *= 0.015625f;
            float vv = 0.f;
            #pragma unroll
            for (int d = 0; d < 64; ++d) { float u = feat[d] - m; vv = fmaf(u, u, vv); }
            vv *= 0.015625f;
            float inv = rsqrtf(vv + 1e-5f);
            #pragma unroll
            for (int d = 0; d < 64; ++d)
                hb[d] = fmaf((feat[d] - m) * inv, s1[d], g1[d]);
        }
        #pragma unroll
        for (int c = 0; c < 64; ++c) {
            float a = ba[c];
            #pragma unroll
            for (int d = 0; d < 64; ++d) a = fmaf(Wa[c * 64 + d], hb[d], a);
            feat[c] += a;
        }
        {
            float m = 0.f;
            #pragma unroll
            for (int d = 0; d < 64; ++d) m += feat[d];
            m *= 0.015625f;
            float vv = 0.f;
            #pragma unroll
            for (int d = 0; d < 64; ++d) { float u = feat[d] - m; vv = fmaf(u, u, vv); }
            vv *= 0.015625f;
            float inv = rsqrtf(vv + 1e-5f);
            #pragma unroll
            for (int d = 0; d < 64; ++d)
                hb[d] = fmaf((feat[d] - m) * inv, s2[d], g2[d]);
        }
        #pragma unroll
        for (int c = 0; c < 64; ++c) feat[c] += bf2[c];
        for (int j = 0; j < 256; ++j) {
            const float* wr = w1p + j * 64;
            float g = bf1[j];
            #pragma unroll
            for (int d = 0; d < 64; ++d) g = fmaf(wr[d], hb[d], g);
            g = 0.5f * g * (1.f + erff(g * 0.70710678118654752f));
            const float* w2r = w2t + j * 64;
            #pragma unroll
            for (int c = 0; c < 64; ++c) feat[c] = fmaf(g, w2r[c], feat[c]);
        }
    }

    {
        float m = 0.f;
        #pragma unroll
        for (int d = 0; d < 64; ++d) m += feat[d];
        m *= 0.015625f;
        float vv = 0.f;
        #pragma unroll
        for (int d = 0; d < 64; ++d) { float u = feat[d] - m; vv = fmaf(u, u, vv); }
        vv *= 0.015625f;
        float inv = rsqrtf(vv + 1e-5f);
        float o0 = cls_b[0], o1 = cls_b[1], o2 = cls_b[2];
        #pragma unroll
        for (int d = 0; d < 64; ++d) {
            float n = fmaf((feat[d] - m) * inv, fn_s[d], fn_b[d]);
            o0 = fmaf(n, cls_w[d], o0);
            o1 = fmaf(n, cls_w[64 + d], o1);
            o2 = fmaf(n, cls_w[128 + d], o2);
        }
        float* op = out + b * 3;
        op[0] = o0; op[1] = o1; op[2] = o2;
    }
}

extern "C" void kernel_launch(void* const* d_in, const int* in_sizes, int n_in,
                              void* d_out, int out_size, void* d_ws, size_t ws_size,
                              hipStream_t stream) {
    const float* eeg      = (const float*)d_in[0];
    const float* eog      = (const float*)d_in[1];
    const float* eeg_inw  = (const float*)d_in[2];
    const float* eeg_inb  = (const float*)d_in[3];
    const float* eeg_ow   = (const float*)d_in[4];
    const float* eeg_ob   = (const float*)d_in[5];
    const float* eog_inw  = (const float*)d_in[6];
    const float* eog_inb  = (const float*)d_in[7];
    const float* eog_ow   = (const float*)d_in[8];
    const float* eog_ob   = (const float*)d_in[9];
    const float* eeg_cw   = (const float*)d_in[10];
    const float* eeg_cb   = (const float*)d_in[11];
    const float* eeg_fw   = (const float*)d_in[12];
    const float* eeg_fb   = (const float*)d_in[13];
    const float* eog_cw   = (const float*)d_in[14];
    const float* eog_cb   = (const float*)d_in[15];
    const float* eog_fw   = (const float*)d_in[16];
    const float* eog_fb   = (const float*)d_in[17];
    const float* fus_w    = (const float*)d_in[18];
    const float* fus_b    = (const float*)d_in[19];
    const float* tl_ln1_s = (const float*)d_in[20];
    const float* tl_ln1_b = (const float*)d_in[21];
    const float* tl_inw   = (const float*)d_in[22];
    const float* tl_inb   = (const float*)d_in[23];
    const float* tl_ow    = (const float*)d_in[24];
    const float* tl_ob    = (const float*)d_in[25];
    const float* tl_ln2_s = (const float*)d_in[26];
    const float* tl_ln2_b = (const float*)d_in[27];
    const float* tl_w1    = (const float*)d_in[28];
    const float* tl_b1    = (const float*)d_in[29];
    const float* tl_w2    = (const float*)d_in[30];
    const float* tl_b2    = (const float*)d_in[31];
    const float* fn_s     = (const float*)d_in[32];
    const float* fn_b     = (const float*)d_in[33];
    const float* cls_w    = (const float*)d_in[34];
    const float* cls_b    = (const float*)d_in[35];
    float* ws  = (float*)d_ws;
    float* out = (float*)d_out;

    const size_t need = (size_t)WS_TOTALF * 4u;
    const int full = (ws_size >= need) ? 1 : 0;

    if (full) {
        hipLaunchKernelGGL(mcaf_prep, dim3(PREP_PRE + PREP_EEG + PREP_EOG), dim3(256), 0, stream,
                           eeg, eog,
                           eeg_inw, eeg_inb, eeg_ow, eeg_ob, eeg_cw,
                           eeg_fw, eeg_fb, eog_cw, eog_fw, eog_fb,
                           fus_w, fus_b, tl_inw, tl_inb, tl_ow, tl_ob, tl_w1, tl_w2, ws);
        hipLaunchKernelGGL(mcaf_fused, dim3(NB / 256), dim3(256), 0, stream,
                           eeg_cb, eog_inw, eog_inb, eog_ow, eog_ob, eog_cb,
                           tl_ln1_s, tl_ln1_b, tl_ln2_s, tl_ln2_b,
                           tl_b1, tl_b2, fn_s, fn_b, cls_w, cls_b, ws, out);
    } else {
        hipLaunchKernelGGL(mcaf_pre, dim3(64), dim3(256), 0, stream,
                           eeg_inw, eeg_inb, eeg_ow, eeg_ob, eeg_cw,
                           eeg_fw, eeg_fb, eog_cw, eog_fw, eog_fb,
                           fus_w, fus_b, tl_inw, tl_inb, tl_ow, tl_ob, tl_w1, tl_w2,
                           ws, 0);
        hipLaunchKernelGGL(mcaf_main_fb, dim3(NB / 256), dim3(256), 0, stream,
                           eeg, eog, eeg_inb, eeg_ow, eeg_ob,
                           eog_inw, eog_inb, eog_ow, eog_ob,
                           eeg_cb, eog_cb,
                           tl_ln1_s, tl_ln1_b, tl_ln2_s, tl_ln2_b,
                           tl_w1, tl_b1, tl_b2,
                           fn_s, fn_b, cls_w, cls_b, ws, out);
    }
}